// Round 7
// baseline (1447.029 us; speedup 1.0000x reference)
//
#include <hip/hip_runtime.h>
#include <hip/hip_bf16.h>
#include <math.h>

#define SEQ 1024
#define DIM 4096
#define NH 32
#define HD 128
#define NKVH 8
#define FF 14336
#define LR 16

typedef __attribute__((ext_vector_type(8))) short bf16x8;
typedef __attribute__((ext_vector_type(4))) float f32x4;
typedef __attribute__((ext_vector_type(4))) ushort ushort4v;

__device__ __forceinline__ ushort f2bf(float f) {
  union { float f; unsigned u; } v; v.f = f;
  unsigned r = (v.u + 0x7FFFu + ((v.u >> 16) & 1u)) >> 16;
  return (ushort)r;
}
__device__ __forceinline__ float bf2f(ushort h) {
  union { unsigned u; float f; } v; v.u = ((unsigned)h) << 16;
  return v.f;
}

__device__ __forceinline__ void gload_lds16(const void* g, void* l) {
  __builtin_amdgcn_global_load_lds(
      (const __attribute__((address_space(1))) void*)g,
      (__attribute__((address_space(3))) void*)l, 16, 0, 0);
}

// ---------------- RMSNorm: f32 in -> bf16 out ----------------
__global__ __launch_bounds__(256) void rmsnorm_kernel(const float* __restrict__ x,
                                                      const float* __restrict__ w,
                                                      ushort* __restrict__ out) {
  int row = blockIdx.x;
  int tid = threadIdx.x;
  const float* xr = x + (size_t)row * DIM;
  float vals[16];
  float s = 0.f;
#pragma unroll
  for (int c = 0; c < 4; c++) {
    float4 v = *(const float4*)&xr[(tid + c * 256) * 4];
    vals[c * 4 + 0] = v.x; vals[c * 4 + 1] = v.y;
    vals[c * 4 + 2] = v.z; vals[c * 4 + 3] = v.w;
    s += v.x * v.x + v.y * v.y + v.z * v.z + v.w * v.w;
  }
#pragma unroll
  for (int off = 32; off >= 1; off >>= 1) s += __shfl_down(s, off);
  __shared__ float wsum[4];
  __shared__ float scale_s;
  int lane = tid & 63, wv = tid >> 6;
  if (lane == 0) wsum[wv] = s;
  __syncthreads();
  if (tid == 0) {
    float t = wsum[0] + wsum[1] + wsum[2] + wsum[3];
    scale_s = rsqrtf(t / (float)DIM + 1e-5f);
  }
  __syncthreads();
  float scale = scale_s;
  ushort* orow = out + (size_t)row * DIM;
#pragma unroll
  for (int c = 0; c < 4; c++) {
    int base = (tid + c * 256) * 4;
    float4 wv4 = *(const float4*)&w[base];
    ushort4v ov;
    ov.x = f2bf(vals[c * 4 + 0] * scale * wv4.x);
    ov.y = f2bf(vals[c * 4 + 1] * scale * wv4.y);
    ov.z = f2bf(vals[c * 4 + 2] * scale * wv4.z);
    ov.w = f2bf(vals[c * 4 + 3] * scale * wv4.w);
    *(ushort4v*)&orow[base] = ov;
  }
}

// ---------------- LoRA A: tbf[M][16] = A(bf16 M x K) @ la(K x 16), bf16 out ----------------
__global__ __launch_bounds__(256) void lora_a_kernel(const ushort* __restrict__ A,
                                                     const float* __restrict__ la,
                                                     ushort* __restrict__ tbf, int K) {
  int m = blockIdx.x, i = threadIdx.x;
  float acc[16];
#pragma unroll
  for (int n = 0; n < 16; n++) acc[n] = 0.f;
  for (int base = i * 16; base < K; base += 256 * 16) {
    bf16x8 a0 = *(const bf16x8*)&A[(size_t)m * K + base];
    bf16x8 a1 = *(const bf16x8*)&A[(size_t)m * K + base + 8];
    const float* lp = la + (size_t)base * LR;
#pragma unroll
    for (int kk = 0; kk < 16; kk++) {
      float av = bf2f((ushort)(kk < 8 ? a0[kk] : a1[kk - 8]));
#pragma unroll
      for (int n = 0; n < 16; n += 4) {
        float4 l = *(const float4*)&lp[kk * LR + n];
        acc[n] += av * l.x; acc[n + 1] += av * l.y;
        acc[n + 2] += av * l.z; acc[n + 3] += av * l.w;
      }
    }
  }
  __shared__ float red[256][16];
  __shared__ float red2[16][16];
#pragma unroll
  for (int n = 0; n < 16; n++) red[i][n] = acc[n];
  __syncthreads();
  {
    int g = i >> 4, n = i & 15;
    float s = 0.f;
#pragma unroll
    for (int j = 0; j < 16; j++) s += red[g * 16 + j][n];
    red2[g][n] = s;
  }
  __syncthreads();
  if (i < 16) {
    float s = 0.f;
#pragma unroll
    for (int g = 0; g < 16; g++) s += red2[g][i];
    tbf[(size_t)m * LR + i] = f2bf(s);
  }
}

// ================= 256x256 GEMM, 8 waves, 4-phase T3 schedule, fused f32->bf16 dequant =================
// out = A(M x K, bf16) @ W(N x K, f32)^T  [+ lora K-ext when z==0]
// A staged via global_load_lds; W reg-staged (f32 loads issued tile-early, cvt+swizzled
// ds_write after phases). Counted vmcnt 12/4 — mid-loop never drains to 0.
// Per K-tile: 4 phases {ds_read quad | barrier | lgkmcnt(0) | 16 MFMA | barrier}.
// WM 0: bf16 direct [M][N];  WM 3: f32 partial slice [z][M][N]
template <int WM>
__global__ __launch_bounds__(512) void gemm256_kernel(
    const ushort* __restrict__ A,
    const float* __restrict__ W0, const float* __restrict__ W1, const float* __restrict__ W2,
    const float* __restrict__ lb0, const float* __restrict__ lb1, const float* __restrict__ lb2,
    const ushort* __restrict__ t0, const ushort* __restrict__ t1, const ushort* __restrict__ t2,
    int c1, int c2, void* __restrict__ outp, int M, int N, int K, int nkp) {
  __shared__ __align__(16) ushort As[2][256 * 64];
  __shared__ __align__(16) ushort Bs[2][256 * 64];
  int tid = threadIdx.x;
  int lane = tid & 63, wave = tid >> 6;
  int wm = wave >> 2, wn = wave & 3;

  // ---- T1: bijective XCD swizzle of flattened block index ----
  int gx = gridDim.x, gy = gridDim.y;
  int flat = blockIdx.x + gx * (blockIdx.y + gy * blockIdx.z);
  int nwg = gx * gy * gridDim.z;
  int q = nwg >> 3, r = nwg & 7;
  int xcd = flat & 7;
  int wgid = (xcd < r ? xcd * (q + 1) : r * (q + 1) + (xcd - r) * q) + (flat >> 3);
  int bx = wgid % gx;
  int tmp = wgid / gx;
  int by = tmp % gy;
  int z = tmp / gy;

  int n0 = bx * 256, m0 = by * 256;
  int k0 = z * nkp;

  // segment select for weight / lora
  const float* Wp; const float* lbp; const ushort* tp; int nseg, wseg;
  if (n0 < c1)      { Wp = W0; lbp = lb0; tp = t0; nseg = n0;      wseg = c1; }
  else if (n0 < c2) { Wp = W1; lbp = lb1; tp = t1; nseg = n0 - c1; wseg = c2 - c1; }
  else              { Wp = W2; lbp = lb2; tp = t2; nseg = n0 - c2; wseg = N - c2; }

  // A staging (global_load_lds, linear dest, source pre-swizzled)
  int srow = tid >> 3;                     // 0..63
  int sswz = ((tid & 7) ^ (srow & 7)) * 8; // inverse-swizzled source col
  const ushort* Ab = A + (size_t)(m0 + srow) * K + sswz;
  // B reg-staging source (no pre-swizzle; swizzle applied at ds_write)
  int cg = tid & 7;                        // 8-f32 col group
  const float* Wb = Wp + (size_t)(nseg + srow) * K + cg * 8;
  int phys = (tid & 7) ^ (srow & 7);       // swizzled write slot (same for all i)

  f32x4 acc[8][4] = {};
  float4 breg[4][2];

#define ISSUE_B(kt)                                                           \
  _Pragma("unroll") for (int i = 0; i < 4; i++) {                             \
    const float* gp = Wb + (size_t)(i * 64) * K + (size_t)(kt) * 64;          \
    breg[i][0] = *(const float4*)gp;                                          \
    breg[i][1] = *(const float4*)(gp + 4);                                    \
  }
#define ISSUE_A(kt, b)                                                        \
  _Pragma("unroll") for (int i = 0; i < 4; i++) {                             \
    gload_lds16(Ab + (size_t)(i * 64) * K + (size_t)(kt) * 64,                \
                &As[b][wave * 512 + i * 4096]);                               \
  }
#define WRITE_B(b)                                                            \
  _Pragma("unroll") for (int i = 0; i < 4; i++) {                             \
    bf16x8 v;                                                                 \
    v[0] = (short)f2bf(breg[i][0].x); v[1] = (short)f2bf(breg[i][0].y);       \
    v[2] = (short)f2bf(breg[i][0].z); v[3] = (short)f2bf(breg[i][0].w);       \
    v[4] = (short)f2bf(breg[i][1].x); v[5] = (short)f2bf(breg[i][1].y);       \
    v[6] = (short)f2bf(breg[i][1].z); v[7] = (short)f2bf(breg[i][1].w);       \
    *(bf16x8*)&Bs[b][(i * 64 + srow) * 64 + phys * 8] = v;                    \
  }
#define LDFRAG(buf, rr, ks) \
  (*(const bf16x8*)&(buf)[(rr) * 64 + (((ks) * 4 + (lane >> 4)) ^ ((rr) & 7)) * 8])

  // ---- prologue: tile k0 into buf 0 ----
  ISSUE_B(k0);
  asm volatile("" ::: "memory");  // pin order: B loads before A gloads
  ISSUE_A(k0, 0);
  asm volatile("s_waitcnt vmcnt(4)" ::: "memory");  // B(k0) regs ready, A(k0) in flight
  WRITE_B(0);
  asm volatile("s_waitcnt lgkmcnt(0)" ::: "memory");

  for (int t = 0; t < nkp; t++) {
    int cur = t & 1;
    if (t + 1 < nkp) {
      ISSUE_B(k0 + t + 1);
      asm volatile("" ::: "memory");
      ISSUE_A(k0 + t + 1, cur ^ 1);
      asm volatile("s_waitcnt vmcnt(12)" ::: "memory");  // drain A(t); keep B/A(t+1) in flight
    } else {
      asm volatile("s_waitcnt vmcnt(0)" ::: "memory");
    }
    __builtin_amdgcn_s_barrier();
    __builtin_amdgcn_sched_barrier(0);
    const ushort* as = As[cur];
    const ushort* bs = Bs[cur];
    bf16x8 bfr[4][2];
    // ---- 4 phases: quadrant ds_read | barrier | lgkm | 16 MFMA | barrier ----
#pragma unroll
    for (int p = 0; p < 4; p++) {
      bf16x8 af[2][2];
#pragma unroll
      for (int qq = 0; qq < 2; qq++) {
        int ra = wm * 128 + (p * 2 + qq) * 16 + (lane & 15);
#pragma unroll
        for (int ks = 0; ks < 2; ks++) af[qq][ks] = LDFRAG(as, ra, ks);
      }
      if (p == 0) {
#pragma unroll
        for (int f = 0; f < 4; f++) {
          int rb = wn * 64 + f * 16 + (lane & 15);
#pragma unroll
          for (int ks = 0; ks < 2; ks++) bfr[f][ks] = LDFRAG(bs, rb, ks);
        }
      }
      __builtin_amdgcn_sched_barrier(0);
      __builtin_amdgcn_s_barrier();
      asm volatile("s_waitcnt lgkmcnt(0)" ::: "memory");
      __builtin_amdgcn_sched_barrier(0);
      __builtin_amdgcn_s_setprio(1);
#pragma unroll
      for (int qq = 0; qq < 2; qq++)
#pragma unroll
        for (int fn = 0; fn < 4; fn++)
#pragma unroll
          for (int ks = 0; ks < 2; ks++)
            acc[p * 2 + qq][fn] = __builtin_amdgcn_mfma_f32_16x16x32_bf16(
                af[qq][ks], bfr[fn][ks], acc[p * 2 + qq][fn], 0, 0, 0);
      __builtin_amdgcn_s_setprio(0);
      __builtin_amdgcn_sched_barrier(0);
      __builtin_amdgcn_s_barrier();
    }
    // ---- tile end: land B(t+1) regs, cvt + swizzled ds_write ----
    if (t + 1 < nkp) {
      asm volatile("s_waitcnt vmcnt(4)" ::: "memory");  // B(t+1) done; A(t+1) still in flight
      WRITE_B(cur ^ 1);
      asm volatile("s_waitcnt lgkmcnt(0)" ::: "memory");
    }
    __builtin_amdgcn_sched_barrier(0);
    __builtin_amdgcn_s_barrier();
  }
#undef ISSUE_B
#undef ISSUE_A
#undef WRITE_B

  // ---- LoRA K-extension (split 0 only): K=32 slice, A=[t|0], B=[lb^T|0] ----
  if (z == 0) {
#pragma unroll
    for (int it = 0; it < 2; it++) {
      int task = tid + it * 512;  // 256 rows x 4 slots
      int rr = task >> 2, ls = task & 3;
      int ph = ls ^ (rr & 7);
      bf16x8 avv = {};
      bf16x8 bvv = {};
      if (ls < 2) {
        avv = *(const bf16x8*)&tp[(size_t)(m0 + rr) * LR + ls * 8];
#pragma unroll
        for (int j = 0; j < 8; j++)
          bvv[j] = (short)f2bf(lbp[(size_t)(ls * 8 + j) * wseg + nseg + rr]);
      }
      *(bf16x8*)&As[0][rr * 64 + ph * 8] = avv;
      *(bf16x8*)&Bs[0][rr * 64 + ph * 8] = bvv;
    }
    __syncthreads();
    bf16x8 af[8], bfr[4];
#pragma unroll
    for (int f = 0; f < 8; f++) {
      int ra = wm * 128 + f * 16 + (lane & 15);
      af[f] = LDFRAG(As[0], ra, 0);
    }
#pragma unroll
    for (int f = 0; f < 4; f++) {
      int rb = wn * 64 + f * 16 + (lane & 15);
      bfr[f] = LDFRAG(Bs[0], rb, 0);
    }
#pragma unroll
    for (int fm = 0; fm < 8; fm++)
#pragma unroll
      for (int fn = 0; fn < 4; fn++)
        acc[fm][fn] = __builtin_amdgcn_mfma_f32_16x16x32_bf16(af[fm], bfr[fn], acc[fm][fn], 0, 0, 0);
  }
#undef LDFRAG

  // ---- write ----
#pragma unroll
  for (int fm = 0; fm < 8; fm++) {
#pragma unroll
    for (int j = 0; j < 4; j++) {
      int mg = m0 + wm * 128 + fm * 16 + (lane >> 4) * 4 + j;
#pragma unroll
      for (int fn = 0; fn < 4; fn++) {
        int ng = n0 + wn * 64 + fn * 16 + (lane & 15);
        float v = acc[fm][fn][j];
        if (WM == 0) {
          ((ushort*)outp)[(size_t)mg * N + ng] = f2bf(v);
        } else {
          ((float*)outp)[((size_t)z * M + mg) * (size_t)N + ng] = v;
        }
      }
    }
  }
}

// ---------------- split-K reduces ----------------
// QKV fused: p has 2 slices of [M][6144]; route cols to qb / kb / vt(transposed)
__global__ __launch_bounds__(256) void reduce2_qkv_kernel(const float* __restrict__ p,
                                                          ushort* __restrict__ qb,
                                                          ushort* __restrict__ kb,
                                                          ushort* __restrict__ vtb) {
  size_t i4 = ((size_t)blockIdx.x * 256 + threadIdx.x) * 4;
  size_t sstride = (size_t)SEQ * 6144;
  int m = (int)(i4 / 6144);
  int c = (int)(i4 % 6144);
  float4 a = *(const float4*)&p[i4];
  float4 b = *(const float4*)&p[i4 + sstride];
  float4 s;
  s.x = a.x + b.x; s.y = a.y + b.y; s.z = a.z + b.z; s.w = a.w + b.w;
  if (c < DIM) {
    ushort4v o;
    o.x = f2bf(s.x); o.y = f2bf(s.y); o.z = f2bf(s.z); o.w = f2bf(s.w);
    *(ushort4v*)&qb[(size_t)m * DIM + c] = o;
  } else if (c < DIM + 1024) {
    ushort4v o;
    o.x = f2bf(s.x); o.y = f2bf(s.y); o.z = f2bf(s.z); o.w = f2bf(s.w);
    *(ushort4v*)&kb[(size_t)m * 1024 + (c - DIM)] = o;
  } else {
    int n = c - DIM - 1024;
    vtb[(size_t)(n + 0) * SEQ + m] = f2bf(s.x);
    vtb[(size_t)(n + 1) * SEQ + m] = f2bf(s.y);
    vtb[(size_t)(n + 2) * SEQ + m] = f2bf(s.z);
    vtb[(size_t)(n + 3) * SEQ + m] = f2bf(s.w);
  }
}

__global__ __launch_bounds__(256) void reduce4_res_kernel(const float* __restrict__ p,
                                                          const float* __restrict__ res,
                                                          float* __restrict__ out,
                                                          size_t sstride) {
  size_t i = ((size_t)blockIdx.x * 256 + threadIdx.x) * 4;
  float4 a = *(const float4*)&p[i];
  float4 b = *(const float4*)&p[i + sstride];
  float4 c = *(const float4*)&p[i + 2 * sstride];
  float4 d = *(const float4*)&p[i + 3 * sstride];
  float4 r = *(const float4*)&res[i];
  float4 o;
  o.x = a.x + b.x + c.x + d.x + r.x;
  o.y = a.y + b.y + c.y + d.y + r.y;
  o.z = a.z + b.z + c.z + d.z + r.z;
  o.w = a.w + b.w + c.w + d.w + r.w;
  *(float4*)&out[i] = o;
}

// ---------------- RoPE (in-place, bf16), rotate_half, optional scale ----------------
__global__ __launch_bounds__(256) void rope_kernel(ushort* __restrict__ x,
                                                   const float* __restrict__ ct,
                                                   const float* __restrict__ st,
                                                   int nheads, float scale) {
  int idx = blockIdx.x * 256 + threadIdx.x;
  int d = idx & 63;
  int hh = (idx >> 6) % nheads;
  int s = idx / (64 * nheads);
  ushort* p = x + (size_t)s * (nheads * HD) + hh * HD + d;
  float x1 = bf2f(p[0]), x2 = bf2f(p[64]);
  float c = ct[s * HD + d], sn = st[s * HD + d];
  p[0] = f2bf((x1 * c - x2 * sn) * scale);
  p[64] = f2bf((x2 * c + x1 * sn) * scale);
}

// ---------------- Flash attention (causal, GQA 4:1) ----------------
__global__ __launch_bounds__(256) void attn_kernel(const ushort* __restrict__ q,
                                                   const ushort* __restrict__ k,
                                                   const ushort* __restrict__ vt,
                                                   ushort* __restrict__ o) {
  int qb = blockIdx.x, h = blockIdx.y, kvh = h >> 2;
  int tid = threadIdx.x, lane = tid & 63, wave = tid >> 6;
  __shared__ ushort Ks[64][136];
  __shared__ ushort Vs[128][72];
  __shared__ ushort Ps[4][16][72];

  bf16x8 qf[4];
  int qrow = qb * 64 + wave * 16 + (lane & 15);
#pragma unroll
  for (int kk = 0; kk < 4; kk++)
    qf[kk] = *(const bf16x8*)&q[(size_t)qrow * DIM + h * HD + kk * 32 + (lane >> 4) * 8];

  f32x4 oacc[8] = {};
  float mrow[4], lrow[4];
  int qr[4];
#pragma unroll
  for (int j = 0; j < 4; j++) {
    mrow[j] = -INFINITY; lrow[j] = 0.f;
    qr[j] = qb * 64 + wave * 16 + (lane >> 4) * 4 + j;
  }

  for (int kt = 0; kt <= qb; kt++) {
    int key0 = kt * 64;
#pragma unroll
    for (int c = 0; c < 4; c++) {
      int e = tid * 32 + c * 8;
      int r = e >> 7, cc = e & 127;
      *(bf16x8*)&Ks[r][cc] =
          *(const bf16x8*)&k[(size_t)(key0 + r) * (NKVH * HD) + kvh * HD + cc];
      int r2 = e >> 6, cc2 = e & 63;
      *(bf16x8*)&Vs[r2][cc2] =
          *(const bf16x8*)&vt[(size_t)(kvh * HD + r2) * SEQ + key0 + cc2];
    }
    __syncthreads();

    f32x4 sf[4] = {};
#pragma unroll
    for (int fn = 0; fn < 4; fn++)
#pragma unroll
      for (int kk = 0; kk < 4; kk++) {
        bf16x8 kf = *(const bf16x8*)&Ks[fn * 16 + (lane & 15)][kk * 32 + (lane >> 4) * 8];
        sf[fn] = __builtin_amdgcn_mfma_f32_16x16x32_bf16(qf[kk], kf, sf[fn], 0, 0, 0);
      }

#pragma unroll
    for (int fn = 0; fn < 4; fn++) {
      int key = key0 + fn * 16 + (lane & 15);
#pragma unroll
      for (int j = 0; j < 4; j++)
        if (key > qr[j]) sf[fn][j] = -INFINITY;
    }

#pragma unroll
    for (int j = 0; j < 4; j++) {
      float mx = fmaxf(fmaxf(sf[0][j], sf[1][j]), fmaxf(sf[2][j], sf[3][j]));
#pragma unroll
      for (int off = 1; off < 16; off <<= 1) mx = fmaxf(mx, __shfl_xor(mx, off));
      float mnew = fmaxf(mrow[j], mx);
      float sc = __expf(mrow[j] - mnew);
      mrow[j] = mnew;
      float rs = 0.f;
#pragma unroll
      for (int fn = 0; fn < 4; fn++) {
        float p = __expf(sf[fn][j] - mnew);
        sf[fn][j] = p;
        rs += p;
      }
#pragma unroll
      for (int off = 1; off < 16; off <<= 1) rs += __shfl_xor(rs, off);
      lrow[j] = lrow[j] * sc + rs;
#pragma unroll
      for (int f2 = 0; f2 < 8; f2++) oacc[f2][j] *= sc;
    }

#pragma unroll
    for (int fn = 0; fn < 4; fn++)
#pragma unroll
      for (int j = 0; j < 4; j++)
        Ps[wave][(lane >> 4) * 4 + j][fn * 16 + (lane & 15)] = f2bf(sf[fn][j]);

#pragma unroll
    for (int kk = 0; kk < 2; kk++) {
      bf16x8 pf = *(const bf16x8*)&Ps[wave][lane & 15][kk * 32 + (lane >> 4) * 8];
#pragma unroll
      for (int f2 = 0; f2 < 8; f2++) {
        bf16x8 vf = *(const bf16x8*)&Vs[f2 * 16 + (lane & 15)][kk * 32 + (lane >> 4) * 8];
        oacc[f2] = __builtin_amdgcn_mfma_f32_16x16x32_bf16(pf, vf, oacc[f2], 0, 0, 0);
      }
    }
    __syncthreads();
  }

#pragma unroll
  for (int j = 0; j < 4; j++) {
    float inv = 1.f / lrow[j];
#pragma unroll
    for (int f2 = 0; f2 < 8; f2++)
      o[(size_t)qr[j] * DIM + h * HD + f2 * 16 + (lane & 15)] = f2bf(oacc[f2][j] * inv);
  }
}

// ---------------- h = silu(gate) * up ----------------
__global__ __launch_bounds__(256) void silu_mul_kernel(const ushort* __restrict__ g,
                                                       const ushort* __restrict__ u,
                                                       ushort* __restrict__ h) {
  size_t idx = (size_t)(blockIdx.x * 256 + threadIdx.x) * 8;
  bf16x8 gv = *(const bf16x8*)&g[idx];
  bf16x8 uv = *(const bf16x8*)&u[idx];
  bf16x8 hv;
#pragma unroll
  for (int i = 0; i < 8; i++) {
    float gf = bf2f((ushort)gv[i]);
    float uf = bf2f((ushort)uv[i]);
    float sv = gf / (1.f + __expf(-gf));
    hv[i] = (short)f2bf(sv * uf);
  }
  *(bf16x8*)&h[idx] = hv;
}

extern "C" void kernel_launch(void* const* d_in, const int* in_sizes, int n_in,
                              void* d_out, int out_size, void* d_ws, size_t ws_size,
                              hipStream_t stream) {
  const float* x    = (const float*)d_in[0];
  const float* w1   = (const float*)d_in[1];
  const float* w2   = (const float*)d_in[2];
  const float* cosT = (const float*)d_in[3];
  const float* sinT = (const float*)d_in[4];
  const float* wq = (const float*)d_in[6];
  const float* la_q = (const float*)d_in[7];
  const float* lb_q = (const float*)d_in[8];
  const float* wk = (const float*)d_in[9];
  const float* la_k = (const float*)d_in[10];
  const float* lb_k = (const float*)d_in[11];
  const float* wv = (const float*)d_in[12];
  const float* la_v = (const float*)d_in[13];
  const float* lb_v = (const float*)d_in[14];
  const float* wo = (const float*)d_in[15];
  const float* la_o = (const float*)d_in[16];
  const float* lb_o = (const float*)d_in[17];
  const float* wg = (const float*)d_in[18];
  const float* la_g = (const float*)d_in[19];
  const float* lb_g = (const float*)d_in[20];
  const float* wu = (const float*)d_in[21];
  const float* la_u = (const float*)d_in[22];
  const float* lb_u = (const float*)d_in[23];
  const float* wd = (const float*)d_in[24];
  const float* la_d = (const float*)d_in[25];
  const float* lb_d = (const float*)d_in[26];
  float* out = (float*)d_out;

  char* ws = (char*)d_ws;
  ushort* xn1 = (ushort*)ws;  ws += (size_t)SEQ * DIM * 2;   // 8 MB
  ushort* qb  = (ushort*)ws;  ws += (size_t)SEQ * DIM * 2;   // 8 MB
  ushort* kb  = (ushort*)ws;  ws += (size_t)SEQ * NKVH * HD * 2;
  ushort* vtb = (ushort*)ws;  ws += (size_t)SEQ * NKVH * HD * 2;
  ushort* ob  = (ushort*)ws;  ws += (size_t)SEQ * DIM * 2;
  float*  xmed= (float*)ws;   ws += (size_t)SEQ * DIM * 4;   // 16 MB
  ushort* xn2 = (ushort*)ws;  ws += (size_t)SEQ * DIM * 2;   // 8 MB
  ushort* gate= (ushort*)ws;  ws += (size_t)SEQ * FF * 2;    // 28 MB
  ushort* up  = (ushort*)ws;  ws += (size_t)SEQ * FF * 2;    // 28 MB
  ushort* hb  = (ushort*)ws;  ws += (size_t)SEQ * FF * 2;    // 28 MB
  ushort* t_q = (ushort*)ws; ws += SEQ * LR * 2;
  ushort* t_k = (ushort*)ws; ws += SEQ * LR * 2;
  ushort* t_v = (ushort*)ws; ws += SEQ * LR * 2;
  ushort* t_o = (ushort*)ws; ws += SEQ * LR * 2;
  ushort* t_g = (ushort*)ws; ws += SEQ * LR * 2;
  ushort* t_u = (ushort*)ws; ws += SEQ * LR * 2;
  ushort* t_d = (ushort*)ws; ws += SEQ * LR * 2;

  // split-K partial buffers aliased onto dead regions:
  float* pbuf1 = (float*)gate;  // QKV (50 MB) / wo (64 MB): gate..hb dead then
  float* pbuf2 = (float*)xn2;   // wd (64 MB): xn2+gate+up dead then, ends at hb

  size_t snd = (size_t)SEQ * DIM;

  // 1) norm + lora-A
  rmsnorm_kernel<<<SEQ, 256, 0, stream>>>(x, w1, xn1);
  lora_a_kernel<<<SEQ, 256, 0, stream>>>(xn1, la_q, t_q, DIM);
  lora_a_kernel<<<SEQ, 256, 0, stream>>>(xn1, la_k, t_k, DIM);
  lora_a_kernel<<<SEQ, 256, 0, stream>>>(xn1, la_v, t_v, DIM);

  // 2) fused QKV GEMM (N=6144, split-K2, fused dequant) -> routed reduce
  gemm256_kernel<3><<<dim3((DIM + 2048) / 256, SEQ / 256, 2), 512, 0, stream>>>(
      xn1, wq, wk, wv, lb_q, lb_k, lb_v, t_q, t_k, t_v, DIM, DIM + 1024,
      pbuf1, SEQ, DIM + 2048, DIM, 32);
  reduce2_qkv_kernel<<<SEQ * (DIM + 2048) / 1024, 256, 0, stream>>>(pbuf1, qb, kb, vtb);

  // 3) RoPE (q pre-scaled by 1/sqrt(HD)) + attention
  rope_kernel<<<SEQ * NH * 64 / 256, 256, 0, stream>>>(qb, cosT, sinT, NH, 0.08838834764831845f);
  rope_kernel<<<SEQ * NKVH * 64 / 256, 256, 0, stream>>>(kb, cosT, sinT, NKVH, 1.0f);
  attn_kernel<<<dim3(SEQ / 64, NH), 256, 0, stream>>>(qb, kb, vtb, ob);

  // 4) WO (split-K4) + residual -> xmed
  lora_a_kernel<<<SEQ, 256, 0, stream>>>(ob, la_o, t_o, DIM);
  gemm256_kernel<3><<<dim3(DIM / 256, SEQ / 256, 4), 512, 0, stream>>>(
      ob, wo, wo, wo, lb_o, lb_o, lb_o, t_o, t_o, t_o, DIM, DIM,
      pbuf1, SEQ, DIM, DIM, 16);
  reduce4_res_kernel<<<snd / 1024, 256, 0, stream>>>(pbuf1, x, xmed, snd);

  // 5) FFN
  rmsnorm_kernel<<<SEQ, 256, 0, stream>>>(xmed, w2, xn2);
  lora_a_kernel<<<SEQ, 256, 0, stream>>>(xn2, la_g, t_g, DIM);
  lora_a_kernel<<<SEQ, 256, 0, stream>>>(xn2, la_u, t_u, DIM);
  gemm256_kernel<0><<<dim3(FF / 256, SEQ / 256, 1), 512, 0, stream>>>(
      xn2, wg, wg, wg, lb_g, lb_g, lb_g, t_g, t_g, t_g, FF, FF,
      gate, SEQ, FF, DIM, DIM / 64);
  gemm256_kernel<0><<<dim3(FF / 256, SEQ / 256, 1), 512, 0, stream>>>(
      xn2, wu, wu, wu, lb_u, lb_u, lb_u, t_u, t_u, t_u, FF, FF,
      up, SEQ, FF, DIM, DIM / 64);
  silu_mul_kernel<<<SEQ * FF / 8 / 256, 256, 0, stream>>>(gate, up, hb);
  lora_a_kernel<<<SEQ, 256, 0, stream>>>(hb, la_d, t_d, FF);
  gemm256_kernel<3><<<dim3(DIM / 256, SEQ / 256, 4), 512, 0, stream>>>(
      hb, wd, wd, wd, lb_d, lb_d, lb_d, t_d, t_d, t_d, DIM, DIM,
      pbuf2, SEQ, DIM, FF, FF / 4 / 64);
  reduce4_res_kernel<<<snd / 1024, 256, 0, stream>>>(pbuf2, xmed, out, snd);
}

// Round 8
// 1282.295 us; speedup vs baseline: 1.1285x; 1.1285x over previous
//
#include <hip/hip_runtime.h>
#include <hip/hip_bf16.h>
#include <math.h>

#define SEQ 1024
#define DIM 4096
#define NH 32
#define HD 128
#define NKVH 8
#define FF 14336
#define LR 16

typedef __attribute__((ext_vector_type(8))) short bf16x8;
typedef __attribute__((ext_vector_type(4))) float f32x4;
typedef __attribute__((ext_vector_type(4))) ushort ushort4v;

__device__ __forceinline__ ushort f2bf(float f) {
  union { float f; unsigned u; } v; v.f = f;
  unsigned r = (v.u + 0x7FFFu + ((v.u >> 16) & 1u)) >> 16;
  return (ushort)r;
}
__device__ __forceinline__ float bf2f(ushort h) {
  union { unsigned u; float f; } v; v.u = ((unsigned)h) << 16;
  return v.f;
}

__device__ __forceinline__ void gload_lds16(const void* g, void* l) {
  __builtin_amdgcn_global_load_lds(
      (const __attribute__((address_space(1))) void*)g,
      (__attribute__((address_space(3))) void*)l, 16, 0, 0);
}

// ---------------- weight f32 -> bf16 convert (grid-stride) ----------------
__global__ __launch_bounds__(256) void w_convert_kernel(const float* __restrict__ in,
                                                        ushort* __restrict__ out,
                                                        size_t n8) {
  size_t stride = (size_t)gridDim.x * 256;
  for (size_t i = (size_t)blockIdx.x * 256 + threadIdx.x; i < n8; i += stride) {
    size_t b = i * 8;
    float4 a = *(const float4*)&in[b];
    float4 c = *(const float4*)&in[b + 4];
    bf16x8 o;
    o[0] = (short)f2bf(a.x); o[1] = (short)f2bf(a.y);
    o[2] = (short)f2bf(a.z); o[3] = (short)f2bf(a.w);
    o[4] = (short)f2bf(c.x); o[5] = (short)f2bf(c.y);
    o[6] = (short)f2bf(c.z); o[7] = (short)f2bf(c.w);
    *(bf16x8*)&out[b] = o;
  }
}

// ---------------- RMSNorm: f32 in -> bf16 out ----------------
__global__ __launch_bounds__(256) void rmsnorm_kernel(const float* __restrict__ x,
                                                      const float* __restrict__ w,
                                                      ushort* __restrict__ out) {
  int row = blockIdx.x;
  int tid = threadIdx.x;
  const float* xr = x + (size_t)row * DIM;
  float vals[16];
  float s = 0.f;
#pragma unroll
  for (int c = 0; c < 4; c++) {
    float4 v = *(const float4*)&xr[(tid + c * 256) * 4];
    vals[c * 4 + 0] = v.x; vals[c * 4 + 1] = v.y;
    vals[c * 4 + 2] = v.z; vals[c * 4 + 3] = v.w;
    s += v.x * v.x + v.y * v.y + v.z * v.z + v.w * v.w;
  }
#pragma unroll
  for (int off = 32; off >= 1; off >>= 1) s += __shfl_down(s, off);
  __shared__ float wsum[4];
  __shared__ float scale_s;
  int lane = tid & 63, wv = tid >> 6;
  if (lane == 0) wsum[wv] = s;
  __syncthreads();
  if (tid == 0) {
    float t = wsum[0] + wsum[1] + wsum[2] + wsum[3];
    scale_s = rsqrtf(t / (float)DIM + 1e-5f);
  }
  __syncthreads();
  float scale = scale_s;
  ushort* orow = out + (size_t)row * DIM;
#pragma unroll
  for (int c = 0; c < 4; c++) {
    int base = (tid + c * 256) * 4;
    float4 wv4 = *(const float4*)&w[base];
    ushort4v ov;
    ov.x = f2bf(vals[c * 4 + 0] * scale * wv4.x);
    ov.y = f2bf(vals[c * 4 + 1] * scale * wv4.y);
    ov.z = f2bf(vals[c * 4 + 2] * scale * wv4.z);
    ov.w = f2bf(vals[c * 4 + 3] * scale * wv4.w);
    *(ushort4v*)&orow[base] = ov;
  }
}

// ---------------- LoRA A: tbf[M][16] = A(bf16 M x K) @ la(K x 16), bf16 out ----------------
__global__ __launch_bounds__(256) void lora_a_kernel(const ushort* __restrict__ A,
                                                     const float* __restrict__ la,
                                                     ushort* __restrict__ tbf, int K) {
  int m = blockIdx.x, i = threadIdx.x;
  float acc[16];
#pragma unroll
  for (int n = 0; n < 16; n++) acc[n] = 0.f;
  for (int base = i * 16; base < K; base += 256 * 16) {
    bf16x8 a0 = *(const bf16x8*)&A[(size_t)m * K + base];
    bf16x8 a1 = *(const bf16x8*)&A[(size_t)m * K + base + 8];
    const float* lp = la + (size_t)base * LR;
#pragma unroll
    for (int kk = 0; kk < 16; kk++) {
      float av = bf2f((ushort)(kk < 8 ? a0[kk] : a1[kk - 8]));
#pragma unroll
      for (int n = 0; n < 16; n += 4) {
        float4 l = *(const float4*)&lp[kk * LR + n];
        acc[n] += av * l.x; acc[n + 1] += av * l.y;
        acc[n + 2] += av * l.z; acc[n + 3] += av * l.w;
      }
    }
  }
  __shared__ float red[256][16];
  __shared__ float red2[16][16];
#pragma unroll
  for (int n = 0; n < 16; n++) red[i][n] = acc[n];
  __syncthreads();
  {
    int g = i >> 4, n = i & 15;
    float s = 0.f;
#pragma unroll
    for (int j = 0; j < 16; j++) s += red[g * 16 + j][n];
    red2[g][n] = s;
  }
  __syncthreads();
  if (i < 16) {
    float s = 0.f;
#pragma unroll
    for (int g = 0; g < 16; g++) s += red2[g][i];
    tbf[(size_t)m * LR + i] = f2bf(s);
  }
}

// ================= 256x256 GEMM, 8 waves, m201 8-phase/2-tile schedule =================
// out = A(M x K, bf16) @ W(N x K, bf16)^T  [+ lora K-ext when z==0]
// Per phase: ds_read one C-quadrant (+bfr at quad0) || stage ONE matrix-half (2 gload_lds)
//            -> barrier -> lgkmcnt(0) -> setprio(1) 16 MFMA setprio(0) -> barrier.
// Staging schedule per 8-phase iter (tiles 2t buf0, 2t+1 buf1):
//   p0/p1: A(2t+1)->buf1   p2/p3: B(2t+2)->buf0 (B of buf0 consumed at p0)
//   p4/p5: A(2t+2)->buf0   p6/p7: B(2t+3)->buf1 (B of buf1 consumed at p4)
// vmcnt(4) only at end of p3 and p7 (leaves next-next B pair in flight).
// WM 0: bf16 direct [M][N];  WM 3: f32 partial slice [z][M][N]
template <int WM>
__global__ __launch_bounds__(512) void gemm256_kernel(
    const ushort* __restrict__ A, const ushort* __restrict__ Wbf,
    const float* __restrict__ lb0, const float* __restrict__ lb1, const float* __restrict__ lb2,
    const ushort* __restrict__ t0, const ushort* __restrict__ t1, const ushort* __restrict__ t2,
    int c1, int c2, void* __restrict__ outp, int M, int N, int K, int nkp) {
  __shared__ __align__(16) ushort As[2][256 * 64];
  __shared__ __align__(16) ushort Bs[2][256 * 64];
  int tid = threadIdx.x;
  int lane = tid & 63, wave = tid >> 6;
  int wm = wave >> 2, wn = wave & 3;

  // ---- T1: bijective XCD swizzle of flattened block index ----
  int gx = gridDim.x, gy = gridDim.y;
  int flat = blockIdx.x + gx * (blockIdx.y + gy * blockIdx.z);
  int nwg = gx * gy * gridDim.z;
  int q = nwg >> 3, r = nwg & 7;
  int xcd = flat & 7;
  int wgid = (xcd < r ? xcd * (q + 1) : r * (q + 1) + (xcd - r) * q) + (flat >> 3);
  int bx = wgid % gx;
  int tmp = wgid / gx;
  int by = tmp % gy;
  int z = tmp / gy;

  int n0 = bx * 256, m0 = by * 256;
  int k0 = z * nkp;

  // lora segment select
  const float* lbp; const ushort* tp; int nseg, wseg;
  if (n0 < c1)      { lbp = lb0; tp = t0; nseg = n0;      wseg = c1; }
  else if (n0 < c2) { lbp = lb1; tp = t1; nseg = n0 - c1; wseg = c2 - c1; }
  else              { lbp = lb2; tp = t2; nseg = n0 - c2; wseg = N - c2; }

  // staging pointers: issue i covers rows [i*64,+64); thread -> row i*64+(tid>>3), slot tid&7
  int srow = tid >> 3;
  int sswz = ((tid & 7) ^ (srow & 7)) * 8;  // inverse-swizzled source col
  const ushort* Ab = A + (size_t)(m0 + srow) * K + sswz;
  const ushort* Wb = Wbf + (size_t)(n0 + srow) * K + sswz;

  f32x4 acc[8][4] = {};

#define SHALF(PTR, DST, kt, b, h)                                             \
  _Pragma("unroll") for (int i = 2 * (h); i < 2 * (h) + 2; i++) {             \
    gload_lds16(PTR + (size_t)(i * 64) * K + (size_t)(kt) * 64,               \
                &DST[b][wave * 512 + i * 4096]);                              \
  }
#define LDFRAG(buf, rr, ks) \
  (*(const bf16x8*)&(buf)[(rr) * 64 + (((ks) * 4 + (lane >> 4)) ^ ((rr) & 7)) * 8])

  // ---- prologue: B(0), A(0) -> buf0; B(1) -> buf1 ----
  SHALF(Wb, Bs, k0, 0, 0); SHALF(Wb, Bs, k0, 0, 1);
  SHALF(Ab, As, k0, 0, 0); SHALF(Ab, As, k0, 0, 1);
  SHALF(Wb, Bs, k0 + 1, 1, 0); SHALF(Wb, Bs, k0 + 1, 1, 1);
  asm volatile("s_waitcnt vmcnt(4)" ::: "memory");  // tile0 landed; B(1) in flight
  __builtin_amdgcn_s_barrier();
  __builtin_amdgcn_sched_barrier(0);

  int nkp2 = nkp >> 1;
  for (int t2 = 0; t2 < nkp2; t2++) {
    int tau0 = 2 * t2, tau1 = 2 * t2 + 1;
    bool pre0 = (tau0 + 2 < nkp);   // stage B/A of tile tau0+2
    bool pre1 = (tau1 + 2 < nkp);   // stage B of tile tau1+2
    // ---- half-iteration 0: compute tile tau0 (buf0) ----
    {
      bf16x8 bfr[4][2];
#pragma unroll
      for (int p = 0; p < 4; p++) {
        bf16x8 af[2][2];
#pragma unroll
        for (int qq = 0; qq < 2; qq++) {
          int ra = wm * 128 + (p * 2 + qq) * 16 + (lane & 15);
#pragma unroll
          for (int ks = 0; ks < 2; ks++) af[qq][ks] = LDFRAG(As[0], ra, ks);
        }
        if (p == 0) {
#pragma unroll
          for (int f = 0; f < 4; f++) {
            int rb = wn * 64 + f * 16 + (lane & 15);
#pragma unroll
            for (int ks = 0; ks < 2; ks++) bfr[f][ks] = LDFRAG(Bs[0], rb, ks);
          }
        }
        // stage one half-unit
        if (p == 0) { SHALF(Ab, As, k0 + tau1, 1, 0); }
        if (p == 1) { SHALF(Ab, As, k0 + tau1, 1, 1); }
        if (p == 2 && pre0) { SHALF(Wb, Bs, k0 + tau0 + 2, 0, 0); }
        if (p == 3 && pre0) { SHALF(Wb, Bs, k0 + tau0 + 2, 0, 1); }
        __builtin_amdgcn_sched_barrier(0);
        __builtin_amdgcn_s_barrier();
        asm volatile("s_waitcnt lgkmcnt(0)" ::: "memory");
        __builtin_amdgcn_sched_barrier(0);
        __builtin_amdgcn_s_setprio(1);
#pragma unroll
        for (int qq = 0; qq < 2; qq++)
#pragma unroll
          for (int fn = 0; fn < 4; fn++)
#pragma unroll
            for (int ks = 0; ks < 2; ks++)
              acc[p * 2 + qq][fn] = __builtin_amdgcn_mfma_f32_16x16x32_bf16(
                  af[qq][ks], bfr[fn][ks], acc[p * 2 + qq][fn], 0, 0, 0);
        __builtin_amdgcn_s_setprio(0);
        __builtin_amdgcn_sched_barrier(0);
        if (p == 3) {
          if (pre0) asm volatile("s_waitcnt vmcnt(4)" ::: "memory");
          else      asm volatile("s_waitcnt vmcnt(0)" ::: "memory");
        }
        __builtin_amdgcn_s_barrier();
        __builtin_amdgcn_sched_barrier(0);
      }
    }
    // ---- half-iteration 1: compute tile tau1 (buf1) ----
    {
      bf16x8 bfr[4][2];
#pragma unroll
      for (int p = 0; p < 4; p++) {
        bf16x8 af[2][2];
#pragma unroll
        for (int qq = 0; qq < 2; qq++) {
          int ra = wm * 128 + (p * 2 + qq) * 16 + (lane & 15);
#pragma unroll
          for (int ks = 0; ks < 2; ks++) af[qq][ks] = LDFRAG(As[1], ra, ks);
        }
        if (p == 0) {
#pragma unroll
          for (int f = 0; f < 4; f++) {
            int rb = wn * 64 + f * 16 + (lane & 15);
#pragma unroll
            for (int ks = 0; ks < 2; ks++) bfr[f][ks] = LDFRAG(Bs[1], rb, ks);
          }
        }
        if (p == 0 && pre0) { SHALF(Ab, As, k0 + tau0 + 2, 0, 0); }
        if (p == 1 && pre0) { SHALF(Ab, As, k0 + tau0 + 2, 0, 1); }
        if (p == 2 && pre1) { SHALF(Wb, Bs, k0 + tau1 + 2, 1, 0); }
        if (p == 3 && pre1) { SHALF(Wb, Bs, k0 + tau1 + 2, 1, 1); }
        __builtin_amdgcn_sched_barrier(0);
        __builtin_amdgcn_s_barrier();
        asm volatile("s_waitcnt lgkmcnt(0)" ::: "memory");
        __builtin_amdgcn_sched_barrier(0);
        __builtin_amdgcn_s_setprio(1);
#pragma unroll
        for (int qq = 0; qq < 2; qq++)
#pragma unroll
          for (int fn = 0; fn < 4; fn++)
#pragma unroll
            for (int ks = 0; ks < 2; ks++)
              acc[p * 2 + qq][fn] = __builtin_amdgcn_mfma_f32_16x16x32_bf16(
                  af[qq][ks], bfr[fn][ks], acc[p * 2 + qq][fn], 0, 0, 0);
        __builtin_amdgcn_s_setprio(0);
        __builtin_amdgcn_sched_barrier(0);
        if (p == 3) {
          if (pre1) asm volatile("s_waitcnt vmcnt(4)" ::: "memory");
          else      asm volatile("s_waitcnt vmcnt(0)" ::: "memory");
        }
        __builtin_amdgcn_s_barrier();
        __builtin_amdgcn_sched_barrier(0);
      }
    }
  }
#undef SHALF

  // ---- LoRA K-extension (split 0 only): K=32 slice, A=[t|0], B=[lb^T|0] ----
  if (z == 0) {
#pragma unroll
    for (int it = 0; it < 2; it++) {
      int task = tid + it * 512;  // 256 rows x 4 slots
      int rr = task >> 2, ls = task & 3;
      int ph = ls ^ (rr & 7);
      bf16x8 avv = {};
      bf16x8 bvv = {};
      if (ls < 2) {
        avv = *(const bf16x8*)&tp[(size_t)(m0 + rr) * LR + ls * 8];
#pragma unroll
        for (int j = 0; j < 8; j++)
          bvv[j] = (short)f2bf(lbp[(size_t)(ls * 8 + j) * wseg + nseg + rr]);
      }
      *(bf16x8*)&As[0][rr * 64 + ph * 8] = avv;
      *(bf16x8*)&Bs[0][rr * 64 + ph * 8] = bvv;
    }
    __syncthreads();
    bf16x8 af[8], bfr[4];
#pragma unroll
    for (int f = 0; f < 8; f++) {
      int ra = wm * 128 + f * 16 + (lane & 15);
      af[f] = LDFRAG(As[0], ra, 0);
    }
#pragma unroll
    for (int f = 0; f < 4; f++) {
      int rb = wn * 64 + f * 16 + (lane & 15);
      bfr[f] = LDFRAG(Bs[0], rb, 0);
    }
#pragma unroll
    for (int fm = 0; fm < 8; fm++)
#pragma unroll
      for (int fn = 0; fn < 4; fn++)
        acc[fm][fn] = __builtin_amdgcn_mfma_f32_16x16x32_bf16(af[fm], bfr[fn], acc[fm][fn], 0, 0, 0);
  }
#undef LDFRAG

  // ---- write ----
#pragma unroll
  for (int fm = 0; fm < 8; fm++) {
#pragma unroll
    for (int j = 0; j < 4; j++) {
      int mg = m0 + wm * 128 + fm * 16 + (lane >> 4) * 4 + j;
#pragma unroll
      for (int fn = 0; fn < 4; fn++) {
        int ng = n0 + wn * 64 + fn * 16 + (lane & 15);
        float v = acc[fm][fn][j];
        if (WM == 0) {
          ((ushort*)outp)[(size_t)mg * N + ng] = f2bf(v);
        } else {
          ((float*)outp)[((size_t)z * M + mg) * (size_t)N + ng] = v;
        }
      }
    }
  }
}

// ---------------- split-K reduces ----------------
__global__ __launch_bounds__(256) void reduce2_qkv_kernel(const float* __restrict__ p,
                                                          ushort* __restrict__ qb,
                                                          ushort* __restrict__ kb,
                                                          ushort* __restrict__ vtb) {
  size_t i4 = ((size_t)blockIdx.x * 256 + threadIdx.x) * 4;
  size_t sstride = (size_t)SEQ * 6144;
  int m = (int)(i4 / 6144);
  int c = (int)(i4 % 6144);
  float4 a = *(const float4*)&p[i4];
  float4 b = *(const float4*)&p[i4 + sstride];
  float4 s;
  s.x = a.x + b.x; s.y = a.y + b.y; s.z = a.z + b.z; s.w = a.w + b.w;
  if (c < DIM) {
    ushort4v o;
    o.x = f2bf(s.x); o.y = f2bf(s.y); o.z = f2bf(s.z); o.w = f2bf(s.w);
    *(ushort4v*)&qb[(size_t)m * DIM + c] = o;
  } else if (c < DIM + 1024) {
    ushort4v o;
    o.x = f2bf(s.x); o.y = f2bf(s.y); o.z = f2bf(s.z); o.w = f2bf(s.w);
    *(ushort4v*)&kb[(size_t)m * 1024 + (c - DIM)] = o;
  } else {
    int n = c - DIM - 1024;
    vtb[(size_t)(n + 0) * SEQ + m] = f2bf(s.x);
    vtb[(size_t)(n + 1) * SEQ + m] = f2bf(s.y);
    vtb[(size_t)(n + 2) * SEQ + m] = f2bf(s.z);
    vtb[(size_t)(n + 3) * SEQ + m] = f2bf(s.w);
  }
}

__global__ __launch_bounds__(256) void reduce4_res_kernel(const float* __restrict__ p,
                                                          const float* __restrict__ res,
                                                          float* __restrict__ out,
                                                          size_t sstride) {
  size_t i = ((size_t)blockIdx.x * 256 + threadIdx.x) * 4;
  float4 a = *(const float4*)&p[i];
  float4 b = *(const float4*)&p[i + sstride];
  float4 c = *(const float4*)&p[i + 2 * sstride];
  float4 d = *(const float4*)&p[i + 3 * sstride];
  float4 r = *(const float4*)&res[i];
  float4 o;
  o.x = a.x + b.x + c.x + d.x + r.x;
  o.y = a.y + b.y + c.y + d.y + r.y;
  o.z = a.z + b.z + c.z + d.z + r.z;
  o.w = a.w + b.w + c.w + d.w + r.w;
  *(float4*)&out[i] = o;
}

// ---------------- RoPE (in-place, bf16), rotate_half, optional scale ----------------
__global__ __launch_bounds__(256) void rope_kernel(ushort* __restrict__ x,
                                                   const float* __restrict__ ct,
                                                   const float* __restrict__ st,
                                                   int nheads, float scale) {
  int idx = blockIdx.x * 256 + threadIdx.x;
  int d = idx & 63;
  int hh = (idx >> 6) % nheads;
  int s = idx / (64 * nheads);
  ushort* p = x + (size_t)s * (nheads * HD) + hh * HD + d;
  float x1 = bf2f(p[0]), x2 = bf2f(p[64]);
  float c = ct[s * HD + d], sn = st[s * HD + d];
  p[0] = f2bf((x1 * c - x2 * sn) * scale);
  p[64] = f2bf((x2 * c + x1 * sn) * scale);
}

// ---------------- Flash attention (causal, GQA 4:1) ----------------
__global__ __launch_bounds__(256) void attn_kernel(const ushort* __restrict__ q,
                                                   const ushort* __restrict__ k,
                                                   const ushort* __restrict__ vt,
                                                   ushort* __restrict__ o) {
  int qb = blockIdx.x, h = blockIdx.y, kvh = h >> 2;
  int tid = threadIdx.x, lane = tid & 63, wave = tid >> 6;
  __shared__ ushort Ks[64][136];
  __shared__ ushort Vs[128][72];
  __shared__ ushort Ps[4][16][72];

  bf16x8 qf[4];
  int qrow = qb * 64 + wave * 16 + (lane & 15);
#pragma unroll
  for (int kk = 0; kk < 4; kk++)
    qf[kk] = *(const bf16x8*)&q[(size_t)qrow * DIM + h * HD + kk * 32 + (lane >> 4) * 8];

  f32x4 oacc[8] = {};
  float mrow[4], lrow[4];
  int qr[4];
#pragma unroll
  for (int j = 0; j < 4; j++) {
    mrow[j] = -INFINITY; lrow[j] = 0.f;
    qr[j] = qb * 64 + wave * 16 + (lane >> 4) * 4 + j;
  }

  for (int kt = 0; kt <= qb; kt++) {
    int key0 = kt * 64;
#pragma unroll
    for (int c = 0; c < 4; c++) {
      int e = tid * 32 + c * 8;
      int r = e >> 7, cc = e & 127;
      *(bf16x8*)&Ks[r][cc] =
          *(const bf16x8*)&k[(size_t)(key0 + r) * (NKVH * HD) + kvh * HD + cc];
      int r2 = e >> 6, cc2 = e & 63;
      *(bf16x8*)&Vs[r2][cc2] =
          *(const bf16x8*)&vt[(size_t)(kvh * HD + r2) * SEQ + key0 + cc2];
    }
    __syncthreads();

    f32x4 sf[4] = {};
#pragma unroll
    for (int fn = 0; fn < 4; fn++)
#pragma unroll
      for (int kk = 0; kk < 4; kk++) {
        bf16x8 kf = *(const bf16x8*)&Ks[fn * 16 + (lane & 15)][kk * 32 + (lane >> 4) * 8];
        sf[fn] = __builtin_amdgcn_mfma_f32_16x16x32_bf16(qf[kk], kf, sf[fn], 0, 0, 0);
      }

#pragma unroll
    for (int fn = 0; fn < 4; fn++) {
      int key = key0 + fn * 16 + (lane & 15);
#pragma unroll
      for (int j = 0; j < 4; j++)
        if (key > qr[j]) sf[fn][j] = -INFINITY;
    }

#pragma unroll
    for (int j = 0; j < 4; j++) {
      float mx = fmaxf(fmaxf(sf[0][j], sf[1][j]), fmaxf(sf[2][j], sf[3][j]));
#pragma unroll
      for (int off = 1; off < 16; off <<= 1) mx = fmaxf(mx, __shfl_xor(mx, off));
      float mnew = fmaxf(mrow[j], mx);
      float sc = __expf(mrow[j] - mnew);
      mrow[j] = mnew;
      float rs = 0.f;
#pragma unroll
      for (int fn = 0; fn < 4; fn++) {
        float p = __expf(sf[fn][j] - mnew);
        sf[fn][j] = p;
        rs += p;
      }
#pragma unroll
      for (int off = 1; off < 16; off <<= 1) rs += __shfl_xor(rs, off);
      lrow[j] = lrow[j] * sc + rs;
#pragma unroll
      for (int f2 = 0; f2 < 8; f2++) oacc[f2][j] *= sc;
    }

#pragma unroll
    for (int fn = 0; fn < 4; fn++)
#pragma unroll
      for (int j = 0; j < 4; j++)
        Ps[wave][(lane >> 4) * 4 + j][fn * 16 + (lane & 15)] = f2bf(sf[fn][j]);

#pragma unroll
    for (int kk = 0; kk < 2; kk++) {
      bf16x8 pf = *(const bf16x8*)&Ps[wave][lane & 15][kk * 32 + (lane >> 4) * 8];
#pragma unroll
      for (int f2 = 0; f2 < 8; f2++) {
        bf16x8 vf = *(const bf16x8*)&Vs[f2 * 16 + (lane & 15)][kk * 32 + (lane >> 4) * 8];
        oacc[f2] = __builtin_amdgcn_mfma_f32_16x16x32_bf16(pf, vf, oacc[f2], 0, 0, 0);
      }
    }
    __syncthreads();
  }

#pragma unroll
  for (int j = 0; j < 4; j++) {
    float inv = 1.f / lrow[j];
#pragma unroll
    for (int f2 = 0; f2 < 8; f2++)
      o[(size_t)qr[j] * DIM + h * HD + f2 * 16 + (lane & 15)] = f2bf(oacc[f2][j] * inv);
  }
}

// ---------------- h = silu(gate) * up ----------------
__global__ __launch_bounds__(256) void silu_mul_kernel(const ushort* __restrict__ g,
                                                       const ushort* __restrict__ u,
                                                       ushort* __restrict__ h) {
  size_t idx = (size_t)(blockIdx.x * 256 + threadIdx.x) * 8;
  bf16x8 gv = *(const bf16x8*)&g[idx];
  bf16x8 uv = *(const bf16x8*)&u[idx];
  bf16x8 hv;
#pragma unroll
  for (int i = 0; i < 8; i++) {
    float gf = bf2f((ushort)gv[i]);
    float uf = bf2f((ushort)uv[i]);
    float sv = gf / (1.f + __expf(-gf));
    hv[i] = (short)f2bf(sv * uf);
  }
  *(bf16x8*)&h[idx] = hv;
}

extern "C" void kernel_launch(void* const* d_in, const int* in_sizes, int n_in,
                              void* d_out, int out_size, void* d_ws, size_t ws_size,
                              hipStream_t stream) {
  const float* x    = (const float*)d_in[0];
  const float* w1   = (const float*)d_in[1];
  const float* w2   = (const float*)d_in[2];
  const float* cosT = (const float*)d_in[3];
  const float* sinT = (const float*)d_in[4];
  const float* wq = (const float*)d_in[6];
  const float* la_q = (const float*)d_in[7];
  const float* lb_q = (const float*)d_in[8];
  const float* wk = (const float*)d_in[9];
  const float* la_k = (const float*)d_in[10];
  const float* lb_k = (const float*)d_in[11];
  const float* wv = (const float*)d_in[12];
  const float* la_v = (const float*)d_in[13];
  const float* lb_v = (const float*)d_in[14];
  const float* wo = (const float*)d_in[15];
  const float* la_o = (const float*)d_in[16];
  const float* lb_o = (const float*)d_in[17];
  const float* wg = (const float*)d_in[18];
  const float* la_g = (const float*)d_in[19];
  const float* lb_g = (const float*)d_in[20];
  const float* wu = (const float*)d_in[21];
  const float* la_u = (const float*)d_in[22];
  const float* lb_u = (const float*)d_in[23];
  const float* wd = (const float*)d_in[24];
  const float* la_d = (const float*)d_in[25];
  const float* lb_d = (const float*)d_in[26];
  float* out = (float*)d_out;

  char* ws = (char*)d_ws;
  ushort* xn1 = (ushort*)ws;  ws += (size_t)SEQ * DIM * 2;   // 8 MB
  ushort* qb  = (ushort*)ws;  ws += (size_t)SEQ * DIM * 2;   // 8 MB
  ushort* kb  = (ushort*)ws;  ws += (size_t)SEQ * NKVH * HD * 2;
  ushort* vtb = (ushort*)ws;  ws += (size_t)SEQ * NKVH * HD * 2;
  ushort* ob  = (ushort*)ws;  ws += (size_t)SEQ * DIM * 2;
  float*  xmed= (float*)ws;   ws += (size_t)SEQ * DIM * 4;   // 16 MB
  ushort* xn2 = (ushort*)ws;  ws += (size_t)SEQ * DIM * 2;   // 8 MB
  ushort* gate= (ushort*)ws;  ws += (size_t)SEQ * FF * 2;    // 28 MB
  ushort* up  = (ushort*)ws;  ws += (size_t)SEQ * FF * 2;    // 28 MB
  ushort* hb  = (ushort*)ws;  ws += (size_t)SEQ * FF * 2;    // 28 MB
  ushort* t_q = (ushort*)ws; ws += SEQ * LR * 2;
  ushort* t_k = (ushort*)ws; ws += SEQ * LR * 2;
  ushort* t_v = (ushort*)ws; ws += SEQ * LR * 2;
  ushort* t_o = (ushort*)ws; ws += SEQ * LR * 2;
  ushort* t_g = (ushort*)ws; ws += SEQ * LR * 2;
  ushort* t_u = (ushort*)ws; ws += SEQ * LR * 2;
  ushort* t_d = (ushort*)ws; ws += SEQ * LR * 2;
  ushort* wbf = (ushort*)ws; ws += (size_t)FF * DIM * 2;     // 112 MB rotating bf16 weights

  // split-K partial buffers aliased onto dead regions:
  float* pbuf1 = (float*)gate;  // QKV (50 MB) / wo (64 MB): gate..hb dead then
  float* pbuf2 = (float*)xn2;   // wd (64 MB): xn2+gate+up dead then, ends at hb

  size_t snd = (size_t)SEQ * DIM;

  auto cvt = [&](const float* w, ushort* dst, size_t n) {
    w_convert_kernel<<<2048, 256, 0, stream>>>(w, dst, n / 8);
  };

  // 1) norm + lora-A
  rmsnorm_kernel<<<SEQ, 256, 0, stream>>>(x, w1, xn1);
  lora_a_kernel<<<SEQ, 256, 0, stream>>>(xn1, la_q, t_q, DIM);
  lora_a_kernel<<<SEQ, 256, 0, stream>>>(xn1, la_k, t_k, DIM);
  lora_a_kernel<<<SEQ, 256, 0, stream>>>(xn1, la_v, t_v, DIM);

  // 2) fused QKV GEMM (N=6144, split-K2) -> routed reduce
  cvt(wq, wbf, (size_t)DIM * DIM);
  cvt(wk, wbf + (size_t)DIM * DIM, (size_t)1024 * DIM);
  cvt(wv, wbf + (size_t)(DIM + 1024) * DIM, (size_t)1024 * DIM);
  gemm256_kernel<3><<<dim3((DIM + 2048) / 256, SEQ / 256, 2), 512, 0, stream>>>(
      xn1, wbf, lb_q, lb_k, lb_v, t_q, t_k, t_v, DIM, DIM + 1024,
      pbuf1, SEQ, DIM + 2048, DIM, 32);
  reduce2_qkv_kernel<<<SEQ * (DIM + 2048) / 1024, 256, 0, stream>>>(pbuf1, qb, kb, vtb);

  // 3) RoPE (q pre-scaled by 1/sqrt(HD)) + attention
  rope_kernel<<<SEQ * NH * 64 / 256, 256, 0, stream>>>(qb, cosT, sinT, NH, 0.08838834764831845f);
  rope_kernel<<<SEQ * NKVH * 64 / 256, 256, 0, stream>>>(kb, cosT, sinT, NKVH, 1.0f);
  attn_kernel<<<dim3(SEQ / 64, NH), 256, 0, stream>>>(qb, kb, vtb, ob);

  // 4) WO (split-K4) + residual -> xmed
  lora_a_kernel<<<SEQ, 256, 0, stream>>>(ob, la_o, t_o, DIM);
  cvt(wo, wbf, (size_t)DIM * DIM);
  gemm256_kernel<3><<<dim3(DIM / 256, SEQ / 256, 4), 512, 0, stream>>>(
      ob, wbf, lb_o, lb_o, lb_o, t_o, t_o, t_o, DIM, DIM,
      pbuf1, SEQ, DIM, DIM, 16);
  reduce4_res_kernel<<<snd / 1024, 256, 0, stream>>>(pbuf1, x, xmed, snd);

  // 5) FFN
  rmsnorm_kernel<<<SEQ, 256, 0, stream>>>(xmed, w2, xn2);
  lora_a_kernel<<<SEQ, 256, 0, stream>>>(xn2, la_g, t_g, DIM);
  lora_a_kernel<<<SEQ, 256, 0, stream>>>(xn2, la_u, t_u, DIM);
  cvt(wg, wbf, (size_t)FF * DIM);
  gemm256_kernel<0><<<dim3(FF / 256, SEQ / 256, 1), 512, 0, stream>>>(
      xn2, wbf, lb_g, lb_g, lb_g, t_g, t_g, t_g, FF, FF,
      gate, SEQ, FF, DIM, DIM / 64);
  cvt(wu, wbf, (size_t)FF * DIM);
  gemm256_kernel<0><<<dim3(FF / 256, SEQ / 256, 1), 512, 0, stream>>>(
      xn2, wbf, lb_u, lb_u, lb_u, t_u, t_u, t_u, FF, FF,
      up, SEQ, FF, DIM, DIM / 64);
  silu_mul_kernel<<<SEQ * FF / 8 / 256, 256, 0, stream>>>(gate, up, hb);
  lora_a_kernel<<<SEQ, 256, 0, stream>>>(hb, la_d, t_d, FF);
  cvt(wd, wbf, (size_t)DIM * FF);
  gemm256_kernel<3><<<dim3(DIM / 256, SEQ / 256, 4), 512, 0, stream>>>(
      hb, wbf, lb_d, lb_d, lb_d, t_d, t_d, t_d, DIM, DIM,
      pbuf2, SEQ, DIM, FF, FF / 4 / 64);
  reduce4_res_kernel<<<snd / 1024, 256, 0, stream>>>(pbuf2, xmed, out, snd);
}

// Round 9
// 1214.806 us; speedup vs baseline: 1.1912x; 1.0556x over previous
//
#include <hip/hip_runtime.h>
#include <hip/hip_bf16.h>
#include <math.h>

#define SEQ 1024
#define DIM 4096
#define NH 32
#define HD 128
#define NKVH 8
#define FF 14336
#define LR 16

typedef __attribute__((ext_vector_type(8))) short bf16x8;
typedef __attribute__((ext_vector_type(4))) float f32x4;
typedef __attribute__((ext_vector_type(4))) ushort ushort4v;

__device__ __forceinline__ ushort f2bf(float f) {
  union { float f; unsigned u; } v; v.f = f;
  unsigned r = (v.u + 0x7FFFu + ((v.u >> 16) & 1u)) >> 16;
  return (ushort)r;
}
__device__ __forceinline__ float bf2f(ushort h) {
  union { unsigned u; float f; } v; v.u = ((unsigned)h) << 16;
  return v.f;
}

__device__ __forceinline__ void gload_lds16(const void* g, void* l) {
  __builtin_amdgcn_global_load_lds(
      (const __attribute__((address_space(1))) void*)g,
      (__attribute__((address_space(3))) void*)l, 16, 0, 0);
}

// ---------------- weight f32 -> bf16 convert (grid-stride) ----------------
__global__ __launch_bounds__(256) void w_convert_kernel(const float* __restrict__ in,
                                                        ushort* __restrict__ out,
                                                        size_t n8) {
  size_t stride = (size_t)gridDim.x * 256;
  for (size_t i = (size_t)blockIdx.x * 256 + threadIdx.x; i < n8; i += stride) {
    size_t b = i * 8;
    float4 a = *(const float4*)&in[b];
    float4 c = *(const float4*)&in[b + 4];
    bf16x8 o;
    o[0] = (short)f2bf(a.x); o[1] = (short)f2bf(a.y);
    o[2] = (short)f2bf(a.z); o[3] = (short)f2bf(a.w);
    o[4] = (short)f2bf(c.x); o[5] = (short)f2bf(c.y);
    o[6] = (short)f2bf(c.z); o[7] = (short)f2bf(c.w);
    *(bf16x8*)&out[b] = o;
  }
}

// ---------------- RMSNorm: f32 in -> bf16 out ----------------
__global__ __launch_bounds__(256) void rmsnorm_kernel(const float* __restrict__ x,
                                                      const float* __restrict__ w,
                                                      ushort* __restrict__ out) {
  int row = blockIdx.x;
  int tid = threadIdx.x;
  const float* xr = x + (size_t)row * DIM;
  float vals[16];
  float s = 0.f;
#pragma unroll
  for (int c = 0; c < 4; c++) {
    float4 v = *(const float4*)&xr[(tid + c * 256) * 4];
    vals[c * 4 + 0] = v.x; vals[c * 4 + 1] = v.y;
    vals[c * 4 + 2] = v.z; vals[c * 4 + 3] = v.w;
    s += v.x * v.x + v.y * v.y + v.z * v.z + v.w * v.w;
  }
#pragma unroll
  for (int off = 32; off >= 1; off >>= 1) s += __shfl_down(s, off);
  __shared__ float wsum[4];
  __shared__ float scale_s;
  int lane = tid & 63, wv = tid >> 6;
  if (lane == 0) wsum[wv] = s;
  __syncthreads();
  if (tid == 0) {
    float t = wsum[0] + wsum[1] + wsum[2] + wsum[3];
    scale_s = rsqrtf(t / (float)DIM + 1e-5f);
  }
  __syncthreads();
  float scale = scale_s;
  ushort* orow = out + (size_t)row * DIM;
#pragma unroll
  for (int c = 0; c < 4; c++) {
    int base = (tid + c * 256) * 4;
    float4 wv4 = *(const float4*)&w[base];
    ushort4v ov;
    ov.x = f2bf(vals[c * 4 + 0] * scale * wv4.x);
    ov.y = f2bf(vals[c * 4 + 1] * scale * wv4.y);
    ov.z = f2bf(vals[c * 4 + 2] * scale * wv4.z);
    ov.w = f2bf(vals[c * 4 + 3] * scale * wv4.w);
    *(ushort4v*)&orow[base] = ov;
  }
}

// ---------------- LoRA A (fused, staged): t_l[M][16] = A @ la_l, l < NL ----------------
// 4 rows/block (1 wave per row); la chunk [256][16] staged in LDS coalesced;
// lane i covers k = i + 64j (coalesced A reads, conflict-free LDS reads);
// wave shfl_xor reduce; bf16 out.
template <int NL>
__global__ __launch_bounds__(256) void lora_a_kernel(
    const ushort* __restrict__ A,
    const float* __restrict__ la0, const float* __restrict__ la1,
    const float* __restrict__ la2,
    ushort* __restrict__ t0, ushort* __restrict__ t1, ushort* __restrict__ t2,
    int K) {
  __shared__ float laS[NL][256][17];
  int tid = threadIdx.x;
  int r = tid >> 6;          // row within block (wave id)
  int i = tid & 63;          // lane
  int m = blockIdx.x * 4 + r;
  float acc[NL][16];
#pragma unroll
  for (int l = 0; l < NL; l++)
#pragma unroll
    for (int n = 0; n < 16; n++) acc[l][n] = 0.f;

  const ushort* Arow = A + (size_t)m * K;

  for (int kc = 0; kc < K; kc += 256) {
    __syncthreads();
    // stage la chunks: 4096 f32 per l = 1024 float4, 256 threads x 4, coalesced
#pragma unroll
    for (int l = 0; l < NL; l++) {
      const float* lap = (l == 0 ? la0 : (l == 1 ? la1 : la2));
#pragma unroll
      for (int c = 0; c < 4; c++) {
        int f4 = c * 256 + tid;              // flat float4 index
        float4 v = *(const float4*)&lap[(size_t)kc * 16 + (size_t)f4 * 4];
        *(float4*)&laS[l][c * 64 + (tid >> 2)][(tid & 3) * 4] = v;
      }
    }
    __syncthreads();
#pragma unroll
    for (int j = 0; j < 4; j++) {
      int k = i + j * 64;
      float a = bf2f(Arow[kc + k]);
#pragma unroll
      for (int l = 0; l < NL; l++) {
#pragma unroll
        for (int n = 0; n < 16; n += 4) {
          float4 lv = *(const float4*)&laS[l][k][n];
          acc[l][n + 0] += a * lv.x;
          acc[l][n + 1] += a * lv.y;
          acc[l][n + 2] += a * lv.z;
          acc[l][n + 3] += a * lv.w;
        }
      }
    }
  }
  // wave butterfly reduce over 64 lanes
#pragma unroll
  for (int l = 0; l < NL; l++)
#pragma unroll
    for (int n = 0; n < 16; n++) {
#pragma unroll
      for (int off = 32; off >= 1; off >>= 1)
        acc[l][n] += __shfl_xor(acc[l][n], off);
    }
  if (i == 0) {
#pragma unroll
    for (int l = 0; l < NL; l++) {
      ushort* tp = (l == 0 ? t0 : (l == 1 ? t1 : t2));
#pragma unroll
      for (int c = 0; c < 4; c++) {
        ushort4v o;
        o.x = f2bf(acc[l][c * 4 + 0]); o.y = f2bf(acc[l][c * 4 + 1]);
        o.z = f2bf(acc[l][c * 4 + 2]); o.w = f2bf(acc[l][c * 4 + 3]);
        *(ushort4v*)&tp[(size_t)m * LR + c * 4] = o;
      }
    }
  }
}

// ================= 256x256 GEMM, 8 waves, m201 8-phase/2-tile schedule =================
// out = A(M x K, bf16) @ W(N x K, bf16)^T  [+ lora K-ext when z==0]
// Per phase: ds_read one C-quadrant (+bfr at quad0) || stage ONE matrix-half (2 gload_lds)
//            -> barrier -> lgkmcnt(0) -> setprio(1) 16 MFMA setprio(0) -> barrier.
// Staging per 8-phase iter: p0/p1 A(2t+1), p2/p3 B(2t+2), p4/p5 A(2t+2), p6/p7 B(2t+3).
// vmcnt(4) only at end of p3 and p7.
// WM 0: bf16 direct [M][N];  WM 3: f32 partial slice [z][M][N]
template <int WM>
__global__ __launch_bounds__(512) void gemm256_kernel(
    const ushort* __restrict__ A, const ushort* __restrict__ Wbf,
    const float* __restrict__ lb0, const float* __restrict__ lb1, const float* __restrict__ lb2,
    const ushort* __restrict__ t0, const ushort* __restrict__ t1, const ushort* __restrict__ t2,
    int c1, int c2, void* __restrict__ outp, int M, int N, int K, int nkp) {
  __shared__ __align__(16) ushort As[2][256 * 64];
  __shared__ __align__(16) ushort Bs[2][256 * 64];
  int tid = threadIdx.x;
  int lane = tid & 63, wave = tid >> 6;
  int wm = wave >> 2, wn = wave & 3;

  // ---- T1: bijective XCD swizzle of flattened block index ----
  int gx = gridDim.x, gy = gridDim.y;
  int flat = blockIdx.x + gx * (blockIdx.y + gy * blockIdx.z);
  int nwg = gx * gy * gridDim.z;
  int q = nwg >> 3, r = nwg & 7;
  int xcd = flat & 7;
  int wgid = (xcd < r ? xcd * (q + 1) : r * (q + 1) + (xcd - r) * q) + (flat >> 3);
  int bx = wgid % gx;
  int tmp = wgid / gx;
  int by = tmp % gy;
  int z = tmp / gy;

  int n0 = bx * 256, m0 = by * 256;
  int k0 = z * nkp;

  // lora segment select
  const float* lbp; const ushort* tp; int nseg, wseg;
  if (n0 < c1)      { lbp = lb0; tp = t0; nseg = n0;      wseg = c1; }
  else if (n0 < c2) { lbp = lb1; tp = t1; nseg = n0 - c1; wseg = c2 - c1; }
  else              { lbp = lb2; tp = t2; nseg = n0 - c2; wseg = N - c2; }

  // staging pointers: issue i covers rows [i*64,+64); thread -> row i*64+(tid>>3), slot tid&7
  int srow = tid >> 3;
  int sswz = ((tid & 7) ^ (srow & 7)) * 8;  // inverse-swizzled source col
  const ushort* Ab = A + (size_t)(m0 + srow) * K + sswz;
  const ushort* Wb = Wbf + (size_t)(n0 + srow) * K + sswz;

  f32x4 acc[8][4] = {};

#define SHALF(PTR, DST, kt, b, h)                                             \
  _Pragma("unroll") for (int i = 2 * (h); i < 2 * (h) + 2; i++) {             \
    gload_lds16(PTR + (size_t)(i * 64) * K + (size_t)(kt) * 64,               \
                &DST[b][wave * 512 + i * 4096]);                              \
  }
#define LDFRAG(buf, rr, ks) \
  (*(const bf16x8*)&(buf)[(rr) * 64 + (((ks) * 4 + (lane >> 4)) ^ ((rr) & 7)) * 8])

  // ---- prologue: B(0), A(0) -> buf0; B(1) -> buf1 ----
  SHALF(Wb, Bs, k0, 0, 0); SHALF(Wb, Bs, k0, 0, 1);
  SHALF(Ab, As, k0, 0, 0); SHALF(Ab, As, k0, 0, 1);
  SHALF(Wb, Bs, k0 + 1, 1, 0); SHALF(Wb, Bs, k0 + 1, 1, 1);
  asm volatile("s_waitcnt vmcnt(4)" ::: "memory");  // tile0 landed; B(1) in flight
  __builtin_amdgcn_s_barrier();
  __builtin_amdgcn_sched_barrier(0);

  int nkp2 = nkp >> 1;
  for (int t2 = 0; t2 < nkp2; t2++) {
    int tau0 = 2 * t2, tau1 = 2 * t2 + 1;
    bool pre0 = (tau0 + 2 < nkp);
    bool pre1 = (tau1 + 2 < nkp);
    // ---- half-iteration 0: compute tile tau0 (buf0) ----
    {
      bf16x8 bfr[4][2];
#pragma unroll
      for (int p = 0; p < 4; p++) {
        bf16x8 af[2][2];
#pragma unroll
        for (int qq = 0; qq < 2; qq++) {
          int ra = wm * 128 + (p * 2 + qq) * 16 + (lane & 15);
#pragma unroll
          for (int ks = 0; ks < 2; ks++) af[qq][ks] = LDFRAG(As[0], ra, ks);
        }
        if (p == 0) {
#pragma unroll
          for (int f = 0; f < 4; f++) {
            int rb = wn * 64 + f * 16 + (lane & 15);
#pragma unroll
            for (int ks = 0; ks < 2; ks++) bfr[f][ks] = LDFRAG(Bs[0], rb, ks);
          }
        }
        if (p == 0) { SHALF(Ab, As, k0 + tau1, 1, 0); }
        if (p == 1) { SHALF(Ab, As, k0 + tau1, 1, 1); }
        if (p == 2 && pre0) { SHALF(Wb, Bs, k0 + tau0 + 2, 0, 0); }
        if (p == 3 && pre0) { SHALF(Wb, Bs, k0 + tau0 + 2, 0, 1); }
        __builtin_amdgcn_sched_barrier(0);
        __builtin_amdgcn_s_barrier();
        asm volatile("s_waitcnt lgkmcnt(0)" ::: "memory");
        __builtin_amdgcn_sched_barrier(0);
        __builtin_amdgcn_s_setprio(1);
#pragma unroll
        for (int qq = 0; qq < 2; qq++)
#pragma unroll
          for (int fn = 0; fn < 4; fn++)
#pragma unroll
            for (int ks = 0; ks < 2; ks++)
              acc[p * 2 + qq][fn] = __builtin_amdgcn_mfma_f32_16x16x32_bf16(
                  af[qq][ks], bfr[fn][ks], acc[p * 2 + qq][fn], 0, 0, 0);
        __builtin_amdgcn_s_setprio(0);
        __builtin_amdgcn_sched_barrier(0);
        if (p == 3) {
          if (pre0) asm volatile("s_waitcnt vmcnt(4)" ::: "memory");
          else      asm volatile("s_waitcnt vmcnt(0)" ::: "memory");
        }
        __builtin_amdgcn_s_barrier();
        __builtin_amdgcn_sched_barrier(0);
      }
    }
    // ---- half-iteration 1: compute tile tau1 (buf1) ----
    {
      bf16x8 bfr[4][2];
#pragma unroll
      for (int p = 0; p < 4; p++) {
        bf16x8 af[2][2];
#pragma unroll
        for (int qq = 0; qq < 2; qq++) {
          int ra = wm * 128 + (p * 2 + qq) * 16 + (lane & 15);
#pragma unroll
          for (int ks = 0; ks < 2; ks++) af[qq][ks] = LDFRAG(As[1], ra, ks);
        }
        if (p == 0) {
#pragma unroll
          for (int f = 0; f < 4; f++) {
            int rb = wn * 64 + f * 16 + (lane & 15);
#pragma unroll
            for (int ks = 0; ks < 2; ks++) bfr[f][ks] = LDFRAG(Bs[1], rb, ks);
          }
        }
        if (p == 0 && pre0) { SHALF(Ab, As, k0 + tau0 + 2, 0, 0); }
        if (p == 1 && pre0) { SHALF(Ab, As, k0 + tau0 + 2, 0, 1); }
        if (p == 2 && pre1) { SHALF(Wb, Bs, k0 + tau1 + 2, 1, 0); }
        if (p == 3 && pre1) { SHALF(Wb, Bs, k0 + tau1 + 2, 1, 1); }
        __builtin_amdgcn_sched_barrier(0);
        __builtin_amdgcn_s_barrier();
        asm volatile("s_waitcnt lgkmcnt(0)" ::: "memory");
        __builtin_amdgcn_sched_barrier(0);
        __builtin_amdgcn_s_setprio(1);
#pragma unroll
        for (int qq = 0; qq < 2; qq++)
#pragma unroll
          for (int fn = 0; fn < 4; fn++)
#pragma unroll
            for (int ks = 0; ks < 2; ks++)
              acc[p * 2 + qq][fn] = __builtin_amdgcn_mfma_f32_16x16x32_bf16(
                  af[qq][ks], bfr[fn][ks], acc[p * 2 + qq][fn], 0, 0, 0);
        __builtin_amdgcn_s_setprio(0);
        __builtin_amdgcn_sched_barrier(0);
        if (p == 3) {
          if (pre1) asm volatile("s_waitcnt vmcnt(4)" ::: "memory");
          else      asm volatile("s_waitcnt vmcnt(0)" ::: "memory");
        }
        __builtin_amdgcn_s_barrier();
        __builtin_amdgcn_sched_barrier(0);
      }
    }
  }
#undef SHALF

  // ---- LoRA K-extension (split 0 only): K=32 slice, A=[t|0], B=[lb^T|0] ----
  if (z == 0) {
#pragma unroll
    for (int it = 0; it < 2; it++) {
      int task = tid + it * 512;  // 256 rows x 4 slots
      int rr = task >> 2, ls = task & 3;
      int ph = ls ^ (rr & 7);
      bf16x8 avv = {};
      bf16x8 bvv = {};
      if (ls < 2) {
        avv = *(const bf16x8*)&tp[(size_t)(m0 + rr) * LR + ls * 8];
#pragma unroll
        for (int j = 0; j < 8; j++)
          bvv[j] = (short)f2bf(lbp[(size_t)(ls * 8 + j) * wseg + nseg + rr]);
      }
      *(bf16x8*)&As[0][rr * 64 + ph * 8] = avv;
      *(bf16x8*)&Bs[0][rr * 64 + ph * 8] = bvv;
    }
    __syncthreads();
    bf16x8 af[8], bfr[4];
#pragma unroll
    for (int f = 0; f < 8; f++) {
      int ra = wm * 128 + f * 16 + (lane & 15);
      af[f] = LDFRAG(As[0], ra, 0);
    }
#pragma unroll
    for (int f = 0; f < 4; f++) {
      int rb = wn * 64 + f * 16 + (lane & 15);
      bfr[f] = LDFRAG(Bs[0], rb, 0);
    }
#pragma unroll
    for (int fm = 0; fm < 8; fm++)
#pragma unroll
      for (int fn = 0; fn < 4; fn++)
        acc[fm][fn] = __builtin_amdgcn_mfma_f32_16x16x32_bf16(af[fm], bfr[fn], acc[fm][fn], 0, 0, 0);
  }
#undef LDFRAG

  // ---- write ----
#pragma unroll
  for (int fm = 0; fm < 8; fm++) {
#pragma unroll
    for (int j = 0; j < 4; j++) {
      int mg = m0 + wm * 128 + fm * 16 + (lane >> 4) * 4 + j;
#pragma unroll
      for (int fn = 0; fn < 4; fn++) {
        int ng = n0 + wn * 64 + fn * 16 + (lane & 15);
        float v = acc[fm][fn][j];
        if (WM == 0) {
          ((ushort*)outp)[(size_t)mg * N + ng] = f2bf(v);
        } else {
          ((float*)outp)[((size_t)z * M + mg) * (size_t)N + ng] = v;
        }
      }
    }
  }
}

// ---------------- split-K reduces ----------------
__global__ __launch_bounds__(256) void reduce2_qkv_kernel(const float* __restrict__ p,
                                                          ushort* __restrict__ qb,
                                                          ushort* __restrict__ kb,
                                                          ushort* __restrict__ vtb) {
  size_t i4 = ((size_t)blockIdx.x * 256 + threadIdx.x) * 4;
  size_t sstride = (size_t)SEQ * 6144;
  int m = (int)(i4 / 6144);
  int c = (int)(i4 % 6144);
  float4 a = *(const float4*)&p[i4];
  float4 b = *(const float4*)&p[i4 + sstride];
  float4 s;
  s.x = a.x + b.x; s.y = a.y + b.y; s.z = a.z + b.z; s.w = a.w + b.w;
  if (c < DIM) {
    ushort4v o;
    o.x = f2bf(s.x); o.y = f2bf(s.y); o.z = f2bf(s.z); o.w = f2bf(s.w);
    *(ushort4v*)&qb[(size_t)m * DIM + c] = o;
  } else if (c < DIM + 1024) {
    ushort4v o;
    o.x = f2bf(s.x); o.y = f2bf(s.y); o.z = f2bf(s.z); o.w = f2bf(s.w);
    *(ushort4v*)&kb[(size_t)m * 1024 + (c - DIM)] = o;
  } else {
    int n = c - DIM - 1024;
    vtb[(size_t)(n + 0) * SEQ + m] = f2bf(s.x);
    vtb[(size_t)(n + 1) * SEQ + m] = f2bf(s.y);
    vtb[(size_t)(n + 2) * SEQ + m] = f2bf(s.z);
    vtb[(size_t)(n + 3) * SEQ + m] = f2bf(s.w);
  }
}

__global__ __launch_bounds__(256) void reduce4_res_kernel(const float* __restrict__ p,
                                                          const float* __restrict__ res,
                                                          float* __restrict__ out,
                                                          size_t sstride) {
  size_t i = ((size_t)blockIdx.x * 256 + threadIdx.x) * 4;
  float4 a = *(const float4*)&p[i];
  float4 b = *(const float4*)&p[i + sstride];
  float4 c = *(const float4*)&p[i + 2 * sstride];
  float4 d = *(const float4*)&p[i + 3 * sstride];
  float4 r = *(const float4*)&res[i];
  float4 o;
  o.x = a.x + b.x + c.x + d.x + r.x;
  o.y = a.y + b.y + c.y + d.y + r.y;
  o.z = a.z + b.z + c.z + d.z + r.z;
  o.w = a.w + b.w + c.w + d.w + r.w;
  *(float4*)&out[i] = o;
}

// ---------------- RoPE (in-place, bf16), rotate_half, optional scale ----------------
__global__ __launch_bounds__(256) void rope_kernel(ushort* __restrict__ x,
                                                   const float* __restrict__ ct,
                                                   const float* __restrict__ st,
                                                   int nheads, float scale) {
  int idx = blockIdx.x * 256 + threadIdx.x;
  int d = idx & 63;
  int hh = (idx >> 6) % nheads;
  int s = idx / (64 * nheads);
  ushort* p = x + (size_t)s * (nheads * HD) + hh * HD + d;
  float x1 = bf2f(p[0]), x2 = bf2f(p[64]);
  float c = ct[s * HD + d], sn = st[s * HD + d];
  p[0] = f2bf((x1 * c - x2 * sn) * scale);
  p[64] = f2bf((x2 * c + x1 * sn) * scale);
}

// ---------------- Flash attention (causal, GQA 4:1) ----------------
__global__ __launch_bounds__(256) void attn_kernel(const ushort* __restrict__ q,
                                                   const ushort* __restrict__ k,
                                                   const ushort* __restrict__ vt,
                                                   ushort* __restrict__ o) {
  int qb = blockIdx.x, h = blockIdx.y, kvh = h >> 2;
  int tid = threadIdx.x, lane = tid & 63, wave = tid >> 6;
  __shared__ ushort Ks[64][136];
  __shared__ ushort Vs[128][72];
  __shared__ ushort Ps[4][16][72];

  bf16x8 qf[4];
  int qrow = qb * 64 + wave * 16 + (lane & 15);
#pragma unroll
  for (int kk = 0; kk < 4; kk++)
    qf[kk] = *(const bf16x8*)&q[(size_t)qrow * DIM + h * HD + kk * 32 + (lane >> 4) * 8];

  f32x4 oacc[8] = {};
  float mrow[4], lrow[4];
  int qr[4];
#pragma unroll
  for (int j = 0; j < 4; j++) {
    mrow[j] = -INFINITY; lrow[j] = 0.f;
    qr[j] = qb * 64 + wave * 16 + (lane >> 4) * 4 + j;
  }

  for (int kt = 0; kt <= qb; kt++) {
    int key0 = kt * 64;
#pragma unroll
    for (int c = 0; c < 4; c++) {
      int e = tid * 32 + c * 8;
      int r = e >> 7, cc = e & 127;
      *(bf16x8*)&Ks[r][cc] =
          *(const bf16x8*)&k[(size_t)(key0 + r) * (NKVH * HD) + kvh * HD + cc];
      int r2 = e >> 6, cc2 = e & 63;
      *(bf16x8*)&Vs[r2][cc2] =
          *(const bf16x8*)&vt[(size_t)(kvh * HD + r2) * SEQ + key0 + cc2];
    }
    __syncthreads();

    f32x4 sf[4] = {};
#pragma unroll
    for (int fn = 0; fn < 4; fn++)
#pragma unroll
      for (int kk = 0; kk < 4; kk++) {
        bf16x8 kf = *(const bf16x8*)&Ks[fn * 16 + (lane & 15)][kk * 32 + (lane >> 4) * 8];
        sf[fn] = __builtin_amdgcn_mfma_f32_16x16x32_bf16(qf[kk], kf, sf[fn], 0, 0, 0);
      }

#pragma unroll
    for (int fn = 0; fn < 4; fn++) {
      int key = key0 + fn * 16 + (lane & 15);
#pragma unroll
      for (int j = 0; j < 4; j++)
        if (key > qr[j]) sf[fn][j] = -INFINITY;
    }

#pragma unroll
    for (int j = 0; j < 4; j++) {
      float mx = fmaxf(fmaxf(sf[0][j], sf[1][j]), fmaxf(sf[2][j], sf[3][j]));
#pragma unroll
      for (int off = 1; off < 16; off <<= 1) mx = fmaxf(mx, __shfl_xor(mx, off));
      float mnew = fmaxf(mrow[j], mx);
      float sc = __expf(mrow[j] - mnew);
      mrow[j] = mnew;
      float rs = 0.f;
#pragma unroll
      for (int fn = 0; fn < 4; fn++) {
        float p = __expf(sf[fn][j] - mnew);
        sf[fn][j] = p;
        rs += p;
      }
#pragma unroll
      for (int off = 1; off < 16; off <<= 1) rs += __shfl_xor(rs, off);
      lrow[j] = lrow[j] * sc + rs;
#pragma unroll
      for (int f2 = 0; f2 < 8; f2++) oacc[f2][j] *= sc;
    }

#pragma unroll
    for (int fn = 0; fn < 4; fn++)
#pragma unroll
      for (int j = 0; j < 4; j++)
        Ps[wave][(lane >> 4) * 4 + j][fn * 16 + (lane & 15)] = f2bf(sf[fn][j]);

#pragma unroll
    for (int kk = 0; kk < 2; kk++) {
      bf16x8 pf = *(const bf16x8*)&Ps[wave][lane & 15][kk * 32 + (lane >> 4) * 8];
#pragma unroll
      for (int f2 = 0; f2 < 8; f2++) {
        bf16x8 vf = *(const bf16x8*)&Vs[f2 * 16 + (lane & 15)][kk * 32 + (lane >> 4) * 8];
        oacc[f2] = __builtin_amdgcn_mfma_f32_16x16x32_bf16(pf, vf, oacc[f2], 0, 0, 0);
      }
    }
    __syncthreads();
  }

#pragma unroll
  for (int j = 0; j < 4; j++) {
    float inv = 1.f / lrow[j];
#pragma unroll
    for (int f2 = 0; f2 < 8; f2++)
      o[(size_t)qr[j] * DIM + h * HD + f2 * 16 + (lane & 15)] = f2bf(oacc[f2][j] * inv);
  }
}

// ---------------- h = silu(gate) * up ----------------
__global__ __launch_bounds__(256) void silu_mul_kernel(const ushort* __restrict__ g,
                                                       const ushort* __restrict__ u,
                                                       ushort* __restrict__ h) {
  size_t idx = (size_t)(blockIdx.x * 256 + threadIdx.x) * 8;
  bf16x8 gv = *(const bf16x8*)&g[idx];
  bf16x8 uv = *(const bf16x8*)&u[idx];
  bf16x8 hv;
#pragma unroll
  for (int i = 0; i < 8; i++) {
    float gf = bf2f((ushort)gv[i]);
    float uf = bf2f((ushort)uv[i]);
    float sv = gf / (1.f + __expf(-gf));
    hv[i] = (short)f2bf(sv * uf);
  }
  *(bf16x8*)&h[idx] = hv;
}

extern "C" void kernel_launch(void* const* d_in, const int* in_sizes, int n_in,
                              void* d_out, int out_size, void* d_ws, size_t ws_size,
                              hipStream_t stream) {
  const float* x    = (const float*)d_in[0];
  const float* w1   = (const float*)d_in[1];
  const float* w2   = (const float*)d_in[2];
  const float* cosT = (const float*)d_in[3];
  const float* sinT = (const float*)d_in[4];
  const float* wq = (const float*)d_in[6];
  const float* la_q = (const float*)d_in[7];
  const float* lb_q = (const float*)d_in[8];
  const float* wk = (const float*)d_in[9];
  const float* la_k = (const float*)d_in[10];
  const float* lb_k = (const float*)d_in[11];
  const float* wv = (const float*)d_in[12];
  const float* la_v = (const float*)d_in[13];
  const float* lb_v = (const float*)d_in[14];
  const float* wo = (const float*)d_in[15];
  const float* la_o = (const float*)d_in[16];
  const float* lb_o = (const float*)d_in[17];
  const float* wg = (const float*)d_in[18];
  const float* la_g = (const float*)d_in[19];
  const float* lb_g = (const float*)d_in[20];
  const float* wu = (const float*)d_in[21];
  const float* la_u = (const float*)d_in[22];
  const float* lb_u = (const float*)d_in[23];
  const float* wd = (const float*)d_in[24];
  const float* la_d = (const float*)d_in[25];
  const float* lb_d = (const float*)d_in[26];
  float* out = (float*)d_out;

  char* ws = (char*)d_ws;
  ushort* xn1 = (ushort*)ws;  ws += (size_t)SEQ * DIM * 2;   // 8 MB
  ushort* qb  = (ushort*)ws;  ws += (size_t)SEQ * DIM * 2;   // 8 MB
  ushort* kb  = (ushort*)ws;  ws += (size_t)SEQ * NKVH * HD * 2;
  ushort* vtb = (ushort*)ws;  ws += (size_t)SEQ * NKVH * HD * 2;
  ushort* ob  = (ushort*)ws;  ws += (size_t)SEQ * DIM * 2;
  float*  xmed= (float*)ws;   ws += (size_t)SEQ * DIM * 4;   // 16 MB
  ushort* xn2 = (ushort*)ws;  ws += (size_t)SEQ * DIM * 2;   // 8 MB
  ushort* gate= (ushort*)ws;  ws += (size_t)SEQ * FF * 2;    // 28 MB
  ushort* up  = (ushort*)ws;  ws += (size_t)SEQ * FF * 2;    // 28 MB
  ushort* hb  = (ushort*)ws;  ws += (size_t)SEQ * FF * 2;    // 28 MB
  ushort* t_q = (ushort*)ws; ws += SEQ * LR * 2;
  ushort* t_k = (ushort*)ws; ws += SEQ * LR * 2;
  ushort* t_v = (ushort*)ws; ws += SEQ * LR * 2;
  ushort* t_o = (ushort*)ws; ws += SEQ * LR * 2;
  ushort* t_g = (ushort*)ws; ws += SEQ * LR * 2;
  ushort* t_u = (ushort*)ws; ws += SEQ * LR * 2;
  ushort* t_d = (ushort*)ws; ws += SEQ * LR * 2;
  ushort* wbf = (ushort*)ws; ws += (size_t)FF * DIM * 2;     // 112 MB rotating bf16 weights

  // split-K partial buffers aliased onto dead regions:
  float* pbuf1 = (float*)gate;  // QKV (50 MB) / wo (64 MB): gate..hb dead then
  float* pbuf2 = (float*)xn2;   // wd (64 MB): xn2+gate+up dead then, ends at hb

  size_t snd = (size_t)SEQ * DIM;

  auto cvt = [&](const float* w, ushort* dst, size_t n) {
    w_convert_kernel<<<2048, 256, 0, stream>>>(w, dst, n / 8);
  };

  // 1) norm + fused lora-A (q,k,v share xn1)
  rmsnorm_kernel<<<SEQ, 256, 0, stream>>>(x, w1, xn1);
  lora_a_kernel<3><<<SEQ / 4, 256, 0, stream>>>(xn1, la_q, la_k, la_v, t_q, t_k, t_v, DIM);

  // 2) fused QKV GEMM (N=6144, split-K2) -> routed reduce
  cvt(wq, wbf, (size_t)DIM * DIM);
  cvt(wk, wbf + (size_t)DIM * DIM, (size_t)1024 * DIM);
  cvt(wv, wbf + (size_t)(DIM + 1024) * DIM, (size_t)1024 * DIM);
  gemm256_kernel<3><<<dim3((DIM + 2048) / 256, SEQ / 256, 2), 512, 0, stream>>>(
      xn1, wbf, lb_q, lb_k, lb_v, t_q, t_k, t_v, DIM, DIM + 1024,
      pbuf1, SEQ, DIM + 2048, DIM, 32);
  reduce2_qkv_kernel<<<SEQ * (DIM + 2048) / 1024, 256, 0, stream>>>(pbuf1, qb, kb, vtb);

  // 3) RoPE (q pre-scaled by 1/sqrt(HD)) + attention
  rope_kernel<<<SEQ * NH * 64 / 256, 256, 0, stream>>>(qb, cosT, sinT, NH, 0.08838834764831845f);
  rope_kernel<<<SEQ * NKVH * 64 / 256, 256, 0, stream>>>(kb, cosT, sinT, NKVH, 1.0f);
  attn_kernel<<<dim3(SEQ / 64, NH), 256, 0, stream>>>(qb, kb, vtb, ob);

  // 4) WO (split-K4) + residual -> xmed
  lora_a_kernel<1><<<SEQ / 4, 256, 0, stream>>>(ob, la_o, la_o, la_o, t_o, t_o, t_o, DIM);
  cvt(wo, wbf, (size_t)DIM * DIM);
  gemm256_kernel<3><<<dim3(DIM / 256, SEQ / 256, 4), 512, 0, stream>>>(
      ob, wbf, lb_o, lb_o, lb_o, t_o, t_o, t_o, DIM, DIM,
      pbuf1, SEQ, DIM, DIM, 16);
  reduce4_res_kernel<<<snd / 1024, 256, 0, stream>>>(pbuf1, x, xmed, snd);

  // 5) FFN (g,u share xn2)
  rmsnorm_kernel<<<SEQ, 256, 0, stream>>>(xmed, w2, xn2);
  lora_a_kernel<2><<<SEQ / 4, 256, 0, stream>>>(xn2, la_g, la_u, la_u, t_g, t_u, t_u, DIM);
  cvt(wg, wbf, (size_t)FF * DIM);
  gemm256_kernel<0><<<dim3(FF / 256, SEQ / 256, 1), 512, 0, stream>>>(
      xn2, wbf, lb_g, lb_g, lb_g, t_g, t_g, t_g, FF, FF,
      gate, SEQ, FF, DIM, DIM / 64);
  cvt(wu, wbf, (size_t)FF * DIM);
  gemm256_kernel<0><<<dim3(FF / 256, SEQ / 256, 1), 512, 0, stream>>>(
      xn2, wbf, lb_u, lb_u, lb_u, t_u, t_u, t_u, FF, FF,
      up, SEQ, FF, DIM, DIM / 64);
  silu_mul_kernel<<<SEQ * FF / 8 / 256, 256, 0, stream>>>(gate, up, hb);
  lora_a_kernel<1><<<SEQ / 4, 256, 0, stream>>>(hb, la_d, la_d, la_d, t_d, t_d, t_d, FF);
  cvt(wd, wbf, (size_t)DIM * FF);
  gemm256_kernel<3><<<dim3(DIM / 256, SEQ / 256, 4), 512, 0, stream>>>(
      hb, wbf, lb_d, lb_d, lb_d, t_d, t_d, t_d, DIM, DIM,
      pbuf2, SEQ, DIM, FF, FF / 4 / 64);
  reduce4_res_kernel<<<snd / 1024, 256, 0, stream>>>(pbuf2, xmed, out, snd);
}

// Round 10
// 1044.531 us; speedup vs baseline: 1.3853x; 1.1630x over previous
//
#include <hip/hip_runtime.h>
#include <hip/hip_bf16.h>
#include <math.h>

#define SEQ 1024
#define DIM 4096
#define NH 32
#define HD 128
#define NKVH 8
#define FF 14336
#define LR 16

typedef __attribute__((ext_vector_type(8))) short bf16x8;
typedef __attribute__((ext_vector_type(4))) float f32x4;
typedef __attribute__((ext_vector_type(4))) ushort ushort4v;

__device__ __forceinline__ ushort f2bf(float f) {
  union { float f; unsigned u; } v; v.f = f;
  unsigned r = (v.u + 0x7FFFu + ((v.u >> 16) & 1u)) >> 16;
  return (ushort)r;
}
__device__ __forceinline__ float bf2f(ushort h) {
  union { unsigned u; float f; } v; v.u = ((unsigned)h) << 16;
  return v.f;
}

__device__ __forceinline__ void gload_lds16(const void* g, void* l) {
  __builtin_amdgcn_global_load_lds(
      (const __attribute__((address_space(1))) void*)g,
      (__attribute__((address_space(3))) void*)l, 16, 0, 0);
}

// ---------------- weight f32 -> bf16 convert (grid-stride) ----------------
__global__ __launch_bounds__(256) void w_convert_kernel(const float* __restrict__ in,
                                                        ushort* __restrict__ out,
                                                        size_t n8) {
  size_t stride = (size_t)gridDim.x * 256;
  for (size_t i = (size_t)blockIdx.x * 256 + threadIdx.x; i < n8; i += stride) {
    size_t b = i * 8;
    float4 a = *(const float4*)&in[b];
    float4 c = *(const float4*)&in[b + 4];
    bf16x8 o;
    o[0] = (short)f2bf(a.x); o[1] = (short)f2bf(a.y);
    o[2] = (short)f2bf(a.z); o[3] = (short)f2bf(a.w);
    o[4] = (short)f2bf(c.x); o[5] = (short)f2bf(c.y);
    o[6] = (short)f2bf(c.z); o[7] = (short)f2bf(c.w);
    *(bf16x8*)&out[b] = o;
  }
}

// ---------------- RMSNorm: f32 in -> bf16 out ----------------
__global__ __launch_bounds__(256) void rmsnorm_kernel(const float* __restrict__ x,
                                                      const float* __restrict__ w,
                                                      ushort* __restrict__ out) {
  int row = blockIdx.x;
  int tid = threadIdx.x;
  const float* xr = x + (size_t)row * DIM;
  float vals[16];
  float s = 0.f;
#pragma unroll
  for (int c = 0; c < 4; c++) {
    float4 v = *(const float4*)&xr[(tid + c * 256) * 4];
    vals[c * 4 + 0] = v.x; vals[c * 4 + 1] = v.y;
    vals[c * 4 + 2] = v.z; vals[c * 4 + 3] = v.w;
    s += v.x * v.x + v.y * v.y + v.z * v.z + v.w * v.w;
  }
#pragma unroll
  for (int off = 32; off >= 1; off >>= 1) s += __shfl_down(s, off);
  __shared__ float wsum[4];
  __shared__ float scale_s;
  int lane = tid & 63, wv = tid >> 6;
  if (lane == 0) wsum[wv] = s;
  __syncthreads();
  if (tid == 0) {
    float t = wsum[0] + wsum[1] + wsum[2] + wsum[3];
    scale_s = rsqrtf(t / (float)DIM + 1e-5f);
  }
  __syncthreads();
  float scale = scale_s;
  ushort* orow = out + (size_t)row * DIM;
#pragma unroll
  for (int c = 0; c < 4; c++) {
    int base = (tid + c * 256) * 4;
    float4 wv4 = *(const float4*)&w[base];
    ushort4v ov;
    ov.x = f2bf(vals[c * 4 + 0] * scale * wv4.x);
    ov.y = f2bf(vals[c * 4 + 1] * scale * wv4.y);
    ov.z = f2bf(vals[c * 4 + 2] * scale * wv4.z);
    ov.w = f2bf(vals[c * 4 + 3] * scale * wv4.w);
    *(ushort4v*)&orow[base] = ov;
  }
}

// ---------------- LoRA A: t_l[m][16] = A[m] @ la_l, one row per block ----------------
// thread i covers k = c*256 + i: A read coalesced scalar bf16; la[k][0..15] read as
// 4 float4 (lane-adjacent k -> consecutive 64B rows; L1 absorbs the 4-pass window).
// No barriers in hot loop; two-stage LDS tree reduce in epilogue.
template <int NL>
__global__ __launch_bounds__(256) void lora_a_kernel(
    const ushort* __restrict__ A,
    const float* __restrict__ la0, const float* __restrict__ la1,
    const float* __restrict__ la2,
    ushort* __restrict__ t0, ushort* __restrict__ t1, ushort* __restrict__ t2,
    int K) {
  int m = blockIdx.x, i = threadIdx.x;
  float acc[NL][16];
#pragma unroll
  for (int l = 0; l < NL; l++)
#pragma unroll
    for (int n = 0; n < 16; n++) acc[l][n] = 0.f;

  const ushort* Arow = A + (size_t)m * K;
  int nc = K >> 8;
  for (int c = 0; c < nc; c++) {
    int k = c * 256 + i;
    float a = bf2f(Arow[k]);
#pragma unroll
    for (int l = 0; l < NL; l++) {
      const float* lap = (l == 0 ? la0 : (l == 1 ? la1 : la2)) + (size_t)k * 16;
#pragma unroll
      for (int q = 0; q < 4; q++) {
        float4 lv = *(const float4*)&lap[q * 4];
        acc[l][q * 4 + 0] += a * lv.x;
        acc[l][q * 4 + 1] += a * lv.y;
        acc[l][q * 4 + 2] += a * lv.z;
        acc[l][q * 4 + 3] += a * lv.w;
      }
    }
  }

  __shared__ float red[256][17];
  __shared__ float red2[16][17];
#pragma unroll
  for (int l = 0; l < NL; l++) {
    __syncthreads();
#pragma unroll
    for (int n = 0; n < 16; n++) red[i][n] = acc[l][n];
    __syncthreads();
    {
      int g = i >> 4, n = i & 15;
      float s = 0.f;
#pragma unroll
      for (int j = 0; j < 16; j++) s += red[g * 16 + j][n];
      red2[g][n] = s;
    }
    __syncthreads();
    if (i < 16) {
      float s2 = 0.f;
#pragma unroll
      for (int g2 = 0; g2 < 16; g2++) s2 += red2[g2][i];
      ushort* tp = (l == 0 ? t0 : (l == 1 ? t1 : t2));
      tp[(size_t)m * LR + i] = f2bf(s2);
    }
  }
}

// ================= 256x256 GEMM, 8 waves, m201 8-phase/2-tile schedule =================
// out = A(M x K, bf16) @ W(N x K, bf16)^T  [+ lora K-ext when z==0]
// Per phase: ds_read one C-quadrant (+bfr at quad0) || stage ONE matrix-half (2 gload_lds)
//            -> barrier -> lgkmcnt(0) -> setprio(1) 16 MFMA setprio(0) -> barrier.
// Staging per 8-phase iter: p0/p1 A(2t+1), p2/p3 B(2t+2), p4/p5 A(2t+2), p6/p7 B(2t+3).
// vmcnt(4) only at end of p3 and p7.
// WM 0: bf16 direct [M][N];  WM 3: f32 partial slice [z][M][N]
template <int WM>
__global__ __launch_bounds__(512) void gemm256_kernel(
    const ushort* __restrict__ A, const ushort* __restrict__ Wbf,
    const float* __restrict__ lb0, const float* __restrict__ lb1, const float* __restrict__ lb2,
    const ushort* __restrict__ t0, const ushort* __restrict__ t1, const ushort* __restrict__ t2,
    int c1, int c2, void* __restrict__ outp, int M, int N, int K, int nkp) {
  __shared__ __align__(16) ushort As[2][256 * 64];
  __shared__ __align__(16) ushort Bs[2][256 * 64];
  int tid = threadIdx.x;
  int lane = tid & 63, wave = tid >> 6;
  int wm = wave >> 2, wn = wave & 3;

  // ---- T1: bijective XCD swizzle of flattened block index ----
  int gx = gridDim.x, gy = gridDim.y;
  int flat = blockIdx.x + gx * (blockIdx.y + gy * blockIdx.z);
  int nwg = gx * gy * gridDim.z;
  int q = nwg >> 3, r = nwg & 7;
  int xcd = flat & 7;
  int wgid = (xcd < r ? xcd * (q + 1) : r * (q + 1) + (xcd - r) * q) + (flat >> 3);
  int bx = wgid % gx;
  int tmp = wgid / gx;
  int by = tmp % gy;
  int z = tmp / gy;

  int n0 = bx * 256, m0 = by * 256;
  int k0 = z * nkp;

  // lora segment select
  const float* lbp; const ushort* tp; int nseg, wseg;
  if (n0 < c1)      { lbp = lb0; tp = t0; nseg = n0;      wseg = c1; }
  else if (n0 < c2) { lbp = lb1; tp = t1; nseg = n0 - c1; wseg = c2 - c1; }
  else              { lbp = lb2; tp = t2; nseg = n0 - c2; wseg = N - c2; }

  // staging pointers: issue i covers rows [i*64,+64); thread -> row i*64+(tid>>3), slot tid&7
  int srow = tid >> 3;
  int sswz = ((tid & 7) ^ (srow & 7)) * 8;  // inverse-swizzled source col
  const ushort* Ab = A + (size_t)(m0 + srow) * K + sswz;
  const ushort* Wb = Wbf + (size_t)(n0 + srow) * K + sswz;

  f32x4 acc[8][4] = {};

#define SHALF(PTR, DST, kt, b, h)                                             \
  _Pragma("unroll") for (int i = 2 * (h); i < 2 * (h) + 2; i++) {             \
    gload_lds16(PTR + (size_t)(i * 64) * K + (size_t)(kt) * 64,               \
                &DST[b][wave * 512 + i * 4096]);                              \
  }
#define LDFRAG(buf, rr, ks) \
  (*(const bf16x8*)&(buf)[(rr) * 64 + (((ks) * 4 + (lane >> 4)) ^ ((rr) & 7)) * 8])

  // ---- prologue: B(0), A(0) -> buf0; B(1) -> buf1 ----
  SHALF(Wb, Bs, k0, 0, 0); SHALF(Wb, Bs, k0, 0, 1);
  SHALF(Ab, As, k0, 0, 0); SHALF(Ab, As, k0, 0, 1);
  SHALF(Wb, Bs, k0 + 1, 1, 0); SHALF(Wb, Bs, k0 + 1, 1, 1);
  asm volatile("s_waitcnt vmcnt(4)" ::: "memory");  // tile0 landed; B(1) in flight
  __builtin_amdgcn_s_barrier();
  __builtin_amdgcn_sched_barrier(0);

  int nkp2 = nkp >> 1;
  for (int t2 = 0; t2 < nkp2; t2++) {
    int tau0 = 2 * t2, tau1 = 2 * t2 + 1;
    bool pre0 = (tau0 + 2 < nkp);
    bool pre1 = (tau1 + 2 < nkp);
    // ---- half-iteration 0: compute tile tau0 (buf0) ----
    {
      bf16x8 bfr[4][2];
#pragma unroll
      for (int p = 0; p < 4; p++) {
        bf16x8 af[2][2];
#pragma unroll
        for (int qq = 0; qq < 2; qq++) {
          int ra = wm * 128 + (p * 2 + qq) * 16 + (lane & 15);
#pragma unroll
          for (int ks = 0; ks < 2; ks++) af[qq][ks] = LDFRAG(As[0], ra, ks);
        }
        if (p == 0) {
#pragma unroll
          for (int f = 0; f < 4; f++) {
            int rb = wn * 64 + f * 16 + (lane & 15);
#pragma unroll
            for (int ks = 0; ks < 2; ks++) bfr[f][ks] = LDFRAG(Bs[0], rb, ks);
          }
        }
        if (p == 0) { SHALF(Ab, As, k0 + tau1, 1, 0); }
        if (p == 1) { SHALF(Ab, As, k0 + tau1, 1, 1); }
        if (p == 2 && pre0) { SHALF(Wb, Bs, k0 + tau0 + 2, 0, 0); }
        if (p == 3 && pre0) { SHALF(Wb, Bs, k0 + tau0 + 2, 0, 1); }
        __builtin_amdgcn_sched_barrier(0);
        __builtin_amdgcn_s_barrier();
        asm volatile("s_waitcnt lgkmcnt(0)" ::: "memory");
        __builtin_amdgcn_sched_barrier(0);
        __builtin_amdgcn_s_setprio(1);
#pragma unroll
        for (int qq = 0; qq < 2; qq++)
#pragma unroll
          for (int fn = 0; fn < 4; fn++)
#pragma unroll
            for (int ks = 0; ks < 2; ks++)
              acc[p * 2 + qq][fn] = __builtin_amdgcn_mfma_f32_16x16x32_bf16(
                  af[qq][ks], bfr[fn][ks], acc[p * 2 + qq][fn], 0, 0, 0);
        __builtin_amdgcn_s_setprio(0);
        __builtin_amdgcn_sched_barrier(0);
        if (p == 3) {
          if (pre0) asm volatile("s_waitcnt vmcnt(4)" ::: "memory");
          else      asm volatile("s_waitcnt vmcnt(0)" ::: "memory");
        }
        __builtin_amdgcn_s_barrier();
        __builtin_amdgcn_sched_barrier(0);
      }
    }
    // ---- half-iteration 1: compute tile tau1 (buf1) ----
    {
      bf16x8 bfr[4][2];
#pragma unroll
      for (int p = 0; p < 4; p++) {
        bf16x8 af[2][2];
#pragma unroll
        for (int qq = 0; qq < 2; qq++) {
          int ra = wm * 128 + (p * 2 + qq) * 16 + (lane & 15);
#pragma unroll
          for (int ks = 0; ks < 2; ks++) af[qq][ks] = LDFRAG(As[1], ra, ks);
        }
        if (p == 0) {
#pragma unroll
          for (int f = 0; f < 4; f++) {
            int rb = wn * 64 + f * 16 + (lane & 15);
#pragma unroll
            for (int ks = 0; ks < 2; ks++) bfr[f][ks] = LDFRAG(Bs[1], rb, ks);
          }
        }
        if (p == 0 && pre0) { SHALF(Ab, As, k0 + tau0 + 2, 0, 0); }
        if (p == 1 && pre0) { SHALF(Ab, As, k0 + tau0 + 2, 0, 1); }
        if (p == 2 && pre1) { SHALF(Wb, Bs, k0 + tau1 + 2, 1, 0); }
        if (p == 3 && pre1) { SHALF(Wb, Bs, k0 + tau1 + 2, 1, 1); }
        __builtin_amdgcn_sched_barrier(0);
        __builtin_amdgcn_s_barrier();
        asm volatile("s_waitcnt lgkmcnt(0)" ::: "memory");
        __builtin_amdgcn_sched_barrier(0);
        __builtin_amdgcn_s_setprio(1);
#pragma unroll
        for (int qq = 0; qq < 2; qq++)
#pragma unroll
          for (int fn = 0; fn < 4; fn++)
#pragma unroll
            for (int ks = 0; ks < 2; ks++)
              acc[p * 2 + qq][fn] = __builtin_amdgcn_mfma_f32_16x16x32_bf16(
                  af[qq][ks], bfr[fn][ks], acc[p * 2 + qq][fn], 0, 0, 0);
        __builtin_amdgcn_s_setprio(0);
        __builtin_amdgcn_sched_barrier(0);
        if (p == 3) {
          if (pre1) asm volatile("s_waitcnt vmcnt(4)" ::: "memory");
          else      asm volatile("s_waitcnt vmcnt(0)" ::: "memory");
        }
        __builtin_amdgcn_s_barrier();
        __builtin_amdgcn_sched_barrier(0);
      }
    }
  }
#undef SHALF

  // ---- LoRA K-extension (split 0 only): K=32 slice, A=[t|0], B=[lb^T|0] ----
  if (z == 0) {
#pragma unroll
    for (int it = 0; it < 2; it++) {
      int task = tid + it * 512;  // 256 rows x 4 slots
      int rr = task >> 2, ls = task & 3;
      int ph = ls ^ (rr & 7);
      bf16x8 avv = {};
      bf16x8 bvv = {};
      if (ls < 2) {
        avv = *(const bf16x8*)&tp[(size_t)(m0 + rr) * LR + ls * 8];
#pragma unroll
        for (int j = 0; j < 8; j++)
          bvv[j] = (short)f2bf(lbp[(size_t)(ls * 8 + j) * wseg + nseg + rr]);
      }
      *(bf16x8*)&As[0][rr * 64 + ph * 8] = avv;
      *(bf16x8*)&Bs[0][rr * 64 + ph * 8] = bvv;
    }
    __syncthreads();
    bf16x8 af[8], bfr[4];
#pragma unroll
    for (int f = 0; f < 8; f++) {
      int ra = wm * 128 + f * 16 + (lane & 15);
      af[f] = LDFRAG(As[0], ra, 0);
    }
#pragma unroll
    for (int f = 0; f < 4; f++) {
      int rb = wn * 64 + f * 16 + (lane & 15);
      bfr[f] = LDFRAG(Bs[0], rb, 0);
    }
#pragma unroll
    for (int fm = 0; fm < 8; fm++)
#pragma unroll
      for (int fn = 0; fn < 4; fn++)
        acc[fm][fn] = __builtin_amdgcn_mfma_f32_16x16x32_bf16(af[fm], bfr[fn], acc[fm][fn], 0, 0, 0);
  }
#undef LDFRAG

  // ---- write ----
#pragma unroll
  for (int fm = 0; fm < 8; fm++) {
#pragma unroll
    for (int j = 0; j < 4; j++) {
      int mg = m0 + wm * 128 + fm * 16 + (lane >> 4) * 4 + j;
#pragma unroll
      for (int fn = 0; fn < 4; fn++) {
        int ng = n0 + wn * 64 + fn * 16 + (lane & 15);
        float v = acc[fm][fn][j];
        if (WM == 0) {
          ((ushort*)outp)[(size_t)mg * N + ng] = f2bf(v);
        } else {
          ((float*)outp)[((size_t)z * M + mg) * (size_t)N + ng] = v;
        }
      }
    }
  }
}

// ---------------- split-K reduces ----------------
__global__ __launch_bounds__(256) void reduce2_qkv_kernel(const float* __restrict__ p,
                                                          ushort* __restrict__ qb,
                                                          ushort* __restrict__ kb,
                                                          ushort* __restrict__ vtb) {
  size_t i4 = ((size_t)blockIdx.x * 256 + threadIdx.x) * 4;
  size_t sstride = (size_t)SEQ * 6144;
  int m = (int)(i4 / 6144);
  int c = (int)(i4 % 6144);
  float4 a = *(const float4*)&p[i4];
  float4 b = *(const float4*)&p[i4 + sstride];
  float4 s;
  s.x = a.x + b.x; s.y = a.y + b.y; s.z = a.z + b.z; s.w = a.w + b.w;
  if (c < DIM) {
    ushort4v o;
    o.x = f2bf(s.x); o.y = f2bf(s.y); o.z = f2bf(s.z); o.w = f2bf(s.w);
    *(ushort4v*)&qb[(size_t)m * DIM + c] = o;
  } else if (c < DIM + 1024) {
    ushort4v o;
    o.x = f2bf(s.x); o.y = f2bf(s.y); o.z = f2bf(s.z); o.w = f2bf(s.w);
    *(ushort4v*)&kb[(size_t)m * 1024 + (c - DIM)] = o;
  } else {
    int n = c - DIM - 1024;
    vtb[(size_t)(n + 0) * SEQ + m] = f2bf(s.x);
    vtb[(size_t)(n + 1) * SEQ + m] = f2bf(s.y);
    vtb[(size_t)(n + 2) * SEQ + m] = f2bf(s.z);
    vtb[(size_t)(n + 3) * SEQ + m] = f2bf(s.w);
  }
}

__global__ __launch_bounds__(256) void reduce4_res_kernel(const float* __restrict__ p,
                                                          const float* __restrict__ res,
                                                          float* __restrict__ out,
                                                          size_t sstride) {
  size_t i = ((size_t)blockIdx.x * 256 + threadIdx.x) * 4;
  float4 a = *(const float4*)&p[i];
  float4 b = *(const float4*)&p[i + sstride];
  float4 c = *(const float4*)&p[i + 2 * sstride];
  float4 d = *(const float4*)&p[i + 3 * sstride];
  float4 r = *(const float4*)&res[i];
  float4 o;
  o.x = a.x + b.x + c.x + d.x + r.x;
  o.y = a.y + b.y + c.y + d.y + r.y;
  o.z = a.z + b.z + c.z + d.z + r.z;
  o.w = a.w + b.w + c.w + d.w + r.w;
  *(float4*)&out[i] = o;
}

// ---------------- RoPE (in-place, bf16), rotate_half, optional scale ----------------
__global__ __launch_bounds__(256) void rope_kernel(ushort* __restrict__ x,
                                                   const float* __restrict__ ct,
                                                   const float* __restrict__ st,
                                                   int nheads, float scale) {
  int idx = blockIdx.x * 256 + threadIdx.x;
  int d = idx & 63;
  int hh = (idx >> 6) % nheads;
  int s = idx / (64 * nheads);
  ushort* p = x + (size_t)s * (nheads * HD) + hh * HD + d;
  float x1 = bf2f(p[0]), x2 = bf2f(p[64]);
  float c = ct[s * HD + d], sn = st[s * HD + d];
  p[0] = f2bf((x1 * c - x2 * sn) * scale);
  p[64] = f2bf((x2 * c + x1 * sn) * scale);
}

// ---------------- Flash attention (causal, GQA 4:1) ----------------
__global__ __launch_bounds__(256) void attn_kernel(const ushort* __restrict__ q,
                                                   const ushort* __restrict__ k,
                                                   const ushort* __restrict__ vt,
                                                   ushort* __restrict__ o) {
  int qb = blockIdx.x, h = blockIdx.y, kvh = h >> 2;
  int tid = threadIdx.x, lane = tid & 63, wave = tid >> 6;
  __shared__ ushort Ks[64][136];
  __shared__ ushort Vs[128][72];
  __shared__ ushort Ps[4][16][72];

  bf16x8 qf[4];
  int qrow = qb * 64 + wave * 16 + (lane & 15);
#pragma unroll
  for (int kk = 0; kk < 4; kk++)
    qf[kk] = *(const bf16x8*)&q[(size_t)qrow * DIM + h * HD + kk * 32 + (lane >> 4) * 8];

  f32x4 oacc[8] = {};
  float mrow[4], lrow[4];
  int qr[4];
#pragma unroll
  for (int j = 0; j < 4; j++) {
    mrow[j] = -INFINITY; lrow[j] = 0.f;
    qr[j] = qb * 64 + wave * 16 + (lane >> 4) * 4 + j;
  }

  for (int kt = 0; kt <= qb; kt++) {
    int key0 = kt * 64;
#pragma unroll
    for (int c = 0; c < 4; c++) {
      int e = tid * 32 + c * 8;
      int r = e >> 7, cc = e & 127;
      *(bf16x8*)&Ks[r][cc] =
          *(const bf16x8*)&k[(size_t)(key0 + r) * (NKVH * HD) + kvh * HD + cc];
      int r2 = e >> 6, cc2 = e & 63;
      *(bf16x8*)&Vs[r2][cc2] =
          *(const bf16x8*)&vt[(size_t)(kvh * HD + r2) * SEQ + key0 + cc2];
    }
    __syncthreads();

    f32x4 sf[4] = {};
#pragma unroll
    for (int fn = 0; fn < 4; fn++)
#pragma unroll
      for (int kk = 0; kk < 4; kk++) {
        bf16x8 kf = *(const bf16x8*)&Ks[fn * 16 + (lane & 15)][kk * 32 + (lane >> 4) * 8];
        sf[fn] = __builtin_amdgcn_mfma_f32_16x16x32_bf16(qf[kk], kf, sf[fn], 0, 0, 0);
      }

#pragma unroll
    for (int fn = 0; fn < 4; fn++) {
      int key = key0 + fn * 16 + (lane & 15);
#pragma unroll
      for (int j = 0; j < 4; j++)
        if (key > qr[j]) sf[fn][j] = -INFINITY;
    }

#pragma unroll
    for (int j = 0; j < 4; j++) {
      float mx = fmaxf(fmaxf(sf[0][j], sf[1][j]), fmaxf(sf[2][j], sf[3][j]));
#pragma unroll
      for (int off = 1; off < 16; off <<= 1) mx = fmaxf(mx, __shfl_xor(mx, off));
      float mnew = fmaxf(mrow[j], mx);
      float sc = __expf(mrow[j] - mnew);
      mrow[j] = mnew;
      float rs = 0.f;
#pragma unroll
      for (int fn = 0; fn < 4; fn++) {
        float p = __expf(sf[fn][j] - mnew);
        sf[fn][j] = p;
        rs += p;
      }
#pragma unroll
      for (int off = 1; off < 16; off <<= 1) rs += __shfl_xor(rs, off);
      lrow[j] = lrow[j] * sc + rs;
#pragma unroll
      for (int f2 = 0; f2 < 8; f2++) oacc[f2][j] *= sc;
    }

#pragma unroll
    for (int fn = 0; fn < 4; fn++)
#pragma unroll
      for (int j = 0; j < 4; j++)
        Ps[wave][(lane >> 4) * 4 + j][fn * 16 + (lane & 15)] = f2bf(sf[fn][j]);

#pragma unroll
    for (int kk = 0; kk < 2; kk++) {
      bf16x8 pf = *(const bf16x8*)&Ps[wave][lane & 15][kk * 32 + (lane >> 4) * 8];
#pragma unroll
      for (int f2 = 0; f2 < 8; f2++) {
        bf16x8 vf = *(const bf16x8*)&Vs[f2 * 16 + (lane & 15)][kk * 32 + (lane >> 4) * 8];
        oacc[f2] = __builtin_amdgcn_mfma_f32_16x16x32_bf16(pf, vf, oacc[f2], 0, 0, 0);
      }
    }
    __syncthreads();
  }

#pragma unroll
  for (int j = 0; j < 4; j++) {
    float inv = 1.f / lrow[j];
#pragma unroll
    for (int f2 = 0; f2 < 8; f2++)
      o[(size_t)qr[j] * DIM + h * HD + f2 * 16 + (lane & 15)] = f2bf(oacc[f2][j] * inv);
  }
}

// ---------------- h = silu(gate) * up ----------------
__global__ __launch_bounds__(256) void silu_mul_kernel(const ushort* __restrict__ g,
                                                       const ushort* __restrict__ u,
                                                       ushort* __restrict__ h) {
  size_t idx = (size_t)(blockIdx.x * 256 + threadIdx.x) * 8;
  bf16x8 gv = *(const bf16x8*)&g[idx];
  bf16x8 uv = *(const bf16x8*)&u[idx];
  bf16x8 hv;
#pragma unroll
  for (int i = 0; i < 8; i++) {
    float gf = bf2f((ushort)gv[i]);
    float uf = bf2f((ushort)uv[i]);
    float sv = gf / (1.f + __expf(-gf));
    hv[i] = (short)f2bf(sv * uf);
  }
  *(bf16x8*)&h[idx] = hv;
}

extern "C" void kernel_launch(void* const* d_in, const int* in_sizes, int n_in,
                              void* d_out, int out_size, void* d_ws, size_t ws_size,
                              hipStream_t stream) {
  const float* x    = (const float*)d_in[0];
  const float* w1   = (const float*)d_in[1];
  const float* w2   = (const float*)d_in[2];
  const float* cosT = (const float*)d_in[3];
  const float* sinT = (const float*)d_in[4];
  const float* wq = (const float*)d_in[6];
  const float* la_q = (const float*)d_in[7];
  const float* lb_q = (const float*)d_in[8];
  const float* wk = (const float*)d_in[9];
  const float* la_k = (const float*)d_in[10];
  const float* lb_k = (const float*)d_in[11];
  const float* wv = (const float*)d_in[12];
  const float* la_v = (const float*)d_in[13];
  const float* lb_v = (const float*)d_in[14];
  const float* wo = (const float*)d_in[15];
  const float* la_o = (const float*)d_in[16];
  const float* lb_o = (const float*)d_in[17];
  const float* wg = (const float*)d_in[18];
  const float* la_g = (const float*)d_in[19];
  const float* lb_g = (const float*)d_in[20];
  const float* wu = (const float*)d_in[21];
  const float* la_u = (const float*)d_in[22];
  const float* lb_u = (const float*)d_in[23];
  const float* wd = (const float*)d_in[24];
  const float* la_d = (const float*)d_in[25];
  const float* lb_d = (const float*)d_in[26];
  float* out = (float*)d_out;

  char* ws = (char*)d_ws;
  ushort* xn1 = (ushort*)ws;  ws += (size_t)SEQ * DIM * 2;   // 8 MB
  ushort* qb  = (ushort*)ws;  ws += (size_t)SEQ * DIM * 2;   // 8 MB
  ushort* kb  = (ushort*)ws;  ws += (size_t)SEQ * NKVH * HD * 2;
  ushort* vtb = (ushort*)ws;  ws += (size_t)SEQ * NKVH * HD * 2;
  ushort* ob  = (ushort*)ws;  ws += (size_t)SEQ * DIM * 2;
  float*  xmed= (float*)ws;   ws += (size_t)SEQ * DIM * 4;   // 16 MB
  ushort* xn2 = (ushort*)ws;  ws += (size_t)SEQ * DIM * 2;   // 8 MB
  ushort* gate= (ushort*)ws;  ws += (size_t)SEQ * FF * 2;    // 28 MB
  ushort* up  = (ushort*)ws;  ws += (size_t)SEQ * FF * 2;    // 28 MB
  ushort* hb  = (ushort*)ws;  ws += (size_t)SEQ * FF * 2;    // 28 MB
  ushort* t_q = (ushort*)ws; ws += SEQ * LR * 2;
  ushort* t_k = (ushort*)ws; ws += SEQ * LR * 2;
  ushort* t_v = (ushort*)ws; ws += SEQ * LR * 2;
  ushort* t_o = (ushort*)ws; ws += SEQ * LR * 2;
  ushort* t_g = (ushort*)ws; ws += SEQ * LR * 2;
  ushort* t_u = (ushort*)ws; ws += SEQ * LR * 2;
  ushort* t_d = (ushort*)ws; ws += SEQ * LR * 2;
  ushort* wbf = (ushort*)ws; ws += (size_t)FF * DIM * 2;     // 112 MB rotating bf16 weights

  // split-K partial buffers aliased onto dead regions:
  float* pbuf1 = (float*)gate;  // QKV (50 MB) / wo (64 MB): gate..hb dead then
  float* pbuf2 = (float*)xn2;   // wd (64 MB): xn2+gate+up dead then, ends at hb

  size_t snd = (size_t)SEQ * DIM;

  auto cvt = [&](const float* w, ushort* dst, size_t n) {
    w_convert_kernel<<<2048, 256, 0, stream>>>(w, dst, n / 8);
  };

  // 1) norm + fused lora-A (q,k,v share xn1)
  rmsnorm_kernel<<<SEQ, 256, 0, stream>>>(x, w1, xn1);
  lora_a_kernel<3><<<SEQ, 256, 0, stream>>>(xn1, la_q, la_k, la_v, t_q, t_k, t_v, DIM);

  // 2) fused QKV GEMM (N=6144, split-K2) -> routed reduce
  cvt(wq, wbf, (size_t)DIM * DIM);
  cvt(wk, wbf + (size_t)DIM * DIM, (size_t)1024 * DIM);
  cvt(wv, wbf + (size_t)(DIM + 1024) * DIM, (size_t)1024 * DIM);
  gemm256_kernel<3><<<dim3((DIM + 2048) / 256, SEQ / 256, 2), 512, 0, stream>>>(
      xn1, wbf, lb_q, lb_k, lb_v, t_q, t_k, t_v, DIM, DIM + 1024,
      pbuf1, SEQ, DIM + 2048, DIM, 32);
  reduce2_qkv_kernel<<<SEQ * (DIM + 2048) / 1024, 256, 0, stream>>>(pbuf1, qb, kb, vtb);

  // 3) RoPE (q pre-scaled by 1/sqrt(HD)) + attention
  rope_kernel<<<SEQ * NH * 64 / 256, 256, 0, stream>>>(qb, cosT, sinT, NH, 0.08838834764831845f);
  rope_kernel<<<SEQ * NKVH * 64 / 256, 256, 0, stream>>>(kb, cosT, sinT, NKVH, 1.0f);
  attn_kernel<<<dim3(SEQ / 64, NH), 256, 0, stream>>>(qb, kb, vtb, ob);

  // 4) WO (split-K4) + residual -> xmed
  lora_a_kernel<1><<<SEQ, 256, 0, stream>>>(ob, la_o, la_o, la_o, t_o, t_o, t_o, DIM);
  cvt(wo, wbf, (size_t)DIM * DIM);
  gemm256_kernel<3><<<dim3(DIM / 256, SEQ / 256, 4), 512, 0, stream>>>(
      ob, wbf, lb_o, lb_o, lb_o, t_o, t_o, t_o, DIM, DIM,
      pbuf1, SEQ, DIM, DIM, 16);
  reduce4_res_kernel<<<snd / 1024, 256, 0, stream>>>(pbuf1, x, xmed, snd);

  // 5) FFN (g,u share xn2)
  rmsnorm_kernel<<<SEQ, 256, 0, stream>>>(xmed, w2, xn2);
  lora_a_kernel<2><<<SEQ, 256, 0, stream>>>(xn2, la_g, la_u, la_u, t_g, t_u, t_u, DIM);
  cvt(wg, wbf, (size_t)FF * DIM);
  gemm256_kernel<0><<<dim3(FF / 256, SEQ / 256, 1), 512, 0, stream>>>(
      xn2, wbf, lb_g, lb_g, lb_g, t_g, t_g, t_g, FF, FF,
      gate, SEQ, FF, DIM, DIM / 64);
  cvt(wu, wbf, (size_t)FF * DIM);
  gemm256_kernel<0><<<dim3(FF / 256, SEQ / 256, 1), 512, 0, stream>>>(
      xn2, wbf, lb_u, lb_u, lb_u, t_u, t_u, t_u, FF, FF,
      up, SEQ, FF, DIM, DIM / 64);
  silu_mul_kernel<<<SEQ * FF / 8 / 256, 256, 0, stream>>>(gate, up, hb);
  lora_a_kernel<1><<<SEQ, 256, 0, stream>>>(hb, la_d, la_d, la_d, t_d, t_d, t_d, FF);
  cvt(wd, wbf, (size_t)DIM * FF);
  gemm256_kernel<3><<<dim3(DIM / 256, SEQ / 256, 4), 512, 0, stream>>>(
      hb, wbf, lb_d, lb_d, lb_d, t_d, t_d, t_d, DIM, DIM,
      pbuf2, SEQ, DIM, FF, FF / 4 / 64);
  reduce4_res_kernel<<<snd / 1024, 256, 0, stream>>>(pbuf2, xmed, out, snd);
}

// Round 11
// 1001.072 us; speedup vs baseline: 1.4455x; 1.0434x over previous
//
#include <hip/hip_runtime.h>
#include <hip/hip_bf16.h>
#include <math.h>

#define SEQ 1024
#define DIM 4096
#define NH 32
#define HD 128
#define NKVH 8
#define FF 14336
#define LR 16

typedef __attribute__((ext_vector_type(8))) short bf16x8;
typedef __attribute__((ext_vector_type(4))) float f32x4;
typedef __attribute__((ext_vector_type(4))) ushort ushort4v;

__device__ __forceinline__ ushort f2bf(float f) {
  union { float f; unsigned u; } v; v.f = f;
  unsigned r = (v.u + 0x7FFFu + ((v.u >> 16) & 1u)) >> 16;
  return (ushort)r;
}
__device__ __forceinline__ float bf2f(ushort h) {
  union { unsigned u; float f; } v; v.u = ((unsigned)h) << 16;
  return v.f;
}

__device__ __forceinline__ void gload_lds16(const void* g, void* l) {
  __builtin_amdgcn_global_load_lds(
      (const __attribute__((address_space(1))) void*)g,
      (__attribute__((address_space(3))) void*)l, 16, 0, 0);
}

// ---------------- RMSNorm: f32 in -> bf16 out ----------------
__global__ __launch_bounds__(256) void rmsnorm_kernel(const float* __restrict__ x,
                                                      const float* __restrict__ w,
                                                      ushort* __restrict__ out) {
  int row = blockIdx.x;
  int tid = threadIdx.x;
  const float* xr = x + (size_t)row * DIM;
  float vals[16];
  float s = 0.f;
#pragma unroll
  for (int c = 0; c < 4; c++) {
    float4 v = *(const float4*)&xr[(tid + c * 256) * 4];
    vals[c * 4 + 0] = v.x; vals[c * 4 + 1] = v.y;
    vals[c * 4 + 2] = v.z; vals[c * 4 + 3] = v.w;
    s += v.x * v.x + v.y * v.y + v.z * v.z + v.w * v.w;
  }
#pragma unroll
  for (int off = 32; off >= 1; off >>= 1) s += __shfl_down(s, off);
  __shared__ float wsum[4];
  __shared__ float scale_s;
  int lane = tid & 63, wv = tid >> 6;
  if (lane == 0) wsum[wv] = s;
  __syncthreads();
  if (tid == 0) {
    float t = wsum[0] + wsum[1] + wsum[2] + wsum[3];
    scale_s = rsqrtf(t / (float)DIM + 1e-5f);
  }
  __syncthreads();
  float scale = scale_s;
  ushort* orow = out + (size_t)row * DIM;
#pragma unroll
  for (int c = 0; c < 4; c++) {
    int base = (tid + c * 256) * 4;
    float4 wv4 = *(const float4*)&w[base];
    ushort4v ov;
    ov.x = f2bf(vals[c * 4 + 0] * scale * wv4.x);
    ov.y = f2bf(vals[c * 4 + 1] * scale * wv4.y);
    ov.z = f2bf(vals[c * 4 + 2] * scale * wv4.z);
    ov.w = f2bf(vals[c * 4 + 3] * scale * wv4.w);
    *(ushort4v*)&orow[base] = ov;
  }
}

// ---------------- LoRA A: t_l[m][16] = A[m] @ la_l, one row per block ----------------
template <int NL>
__global__ __launch_bounds__(256) void lora_a_kernel(
    const ushort* __restrict__ A,
    const float* __restrict__ la0, const float* __restrict__ la1,
    const float* __restrict__ la2,
    ushort* __restrict__ t0, ushort* __restrict__ t1, ushort* __restrict__ t2,
    int K) {
  int m = blockIdx.x, i = threadIdx.x;
  float acc[NL][16];
#pragma unroll
  for (int l = 0; l < NL; l++)
#pragma unroll
    for (int n = 0; n < 16; n++) acc[l][n] = 0.f;

  const ushort* Arow = A + (size_t)m * K;
  int nc = K >> 8;
  for (int c = 0; c < nc; c++) {
    int k = c * 256 + i;
    float a = bf2f(Arow[k]);
#pragma unroll
    for (int l = 0; l < NL; l++) {
      const float* lap = (l == 0 ? la0 : (l == 1 ? la1 : la2)) + (size_t)k * 16;
#pragma unroll
      for (int q = 0; q < 4; q++) {
        float4 lv = *(const float4*)&lap[q * 4];
        acc[l][q * 4 + 0] += a * lv.x;
        acc[l][q * 4 + 1] += a * lv.y;
        acc[l][q * 4 + 2] += a * lv.z;
        acc[l][q * 4 + 3] += a * lv.w;
      }
    }
  }

  __shared__ float red[256][17];
  __shared__ float red2[16][17];
#pragma unroll
  for (int l = 0; l < NL; l++) {
    __syncthreads();
#pragma unroll
    for (int n = 0; n < 16; n++) red[i][n] = acc[l][n];
    __syncthreads();
    {
      int g = i >> 4, n = i & 15;
      float s = 0.f;
#pragma unroll
      for (int j = 0; j < 16; j++) s += red[g * 16 + j][n];
      red2[g][n] = s;
    }
    __syncthreads();
    if (i < 16) {
      float s2 = 0.f;
#pragma unroll
      for (int g2 = 0; g2 < 16; g2++) s2 += red2[g2][i];
      ushort* tp = (l == 0 ? t0 : (l == 1 ? t1 : t2));
      tp[(size_t)m * LR + i] = f2bf(s2);
    }
  }
}

// ================= 256x256 GEMM, 8 waves, 8-phase schedule, FUSED f32->bf16 dequant =================
// out = A(M x K, bf16) @ W(N x K, f32)^T  [+ lora K-ext when z==0]
// A: global_load_lds, staged 1 tile ahead (p0/p1).
// B: reg-staged f32, loads issued 2 tiles ahead (p2/p3), cvt + swizzled ds_write
//    1 tile ahead at p1 (after MFMA). Counted waits: p1 vmcnt(4); p3-end vmcnt(8|0).
// WM 0: bf16 direct [M][N];  WM 3: f32 partial slice [z][M][N]
template <int WM>
__global__ __launch_bounds__(512) void gemm256_kernel(
    const ushort* __restrict__ A,
    const float* __restrict__ W0, const float* __restrict__ W1, const float* __restrict__ W2,
    const float* __restrict__ lb0, const float* __restrict__ lb1, const float* __restrict__ lb2,
    const ushort* __restrict__ t0, const ushort* __restrict__ t1, const ushort* __restrict__ t2,
    int c1, int c2, void* __restrict__ outp, int M, int N, int K, int nkp) {
  __shared__ __align__(16) ushort As[2][256 * 64];
  __shared__ __align__(16) ushort Bs[2][256 * 64];
  int tid = threadIdx.x;
  int lane = tid & 63, wave = tid >> 6;
  int wm = wave >> 2, wn = wave & 3;

  // ---- T1: bijective XCD swizzle of flattened block index ----
  int gx = gridDim.x, gy = gridDim.y;
  int flat = blockIdx.x + gx * (blockIdx.y + gy * blockIdx.z);
  int nwg = gx * gy * gridDim.z;
  int q = nwg >> 3, r = nwg & 7;
  int xcd = flat & 7;
  int wgid = (xcd < r ? xcd * (q + 1) : r * (q + 1) + (xcd - r) * q) + (flat >> 3);
  int bx = wgid % gx;
  int tmp = wgid / gx;
  int by = tmp % gy;
  int z = tmp / gy;

  int n0 = bx * 256, m0 = by * 256;
  int k0 = z * nkp;

  // segment select (weight + lora)
  const float* Wp; const float* lbp; const ushort* tp; int nseg, wseg;
  if (n0 < c1)      { Wp = W0; lbp = lb0; tp = t0; nseg = n0;      wseg = c1; }
  else if (n0 < c2) { Wp = W1; lbp = lb1; tp = t1; nseg = n0 - c1; wseg = c2 - c1; }
  else              { Wp = W2; lbp = lb2; tp = t2; nseg = n0 - c2; wseg = N - c2; }

  // A staging: issue i covers rows [i*64,+64); thread -> row i*64+(tid>>3), slot tid&7
  int srow = tid >> 3;
  int sswz = ((tid & 7) ^ (srow & 7)) * 8;  // inverse-swizzled source col (A only)
  const ushort* Ab = A + (size_t)(m0 + srow) * K + sswz;
  // B reg-staging source (linear; swizzle applied at ds_write)
  const float* Wbase = Wp + (size_t)(nseg + srow) * K + (tid & 7) * 8;
  int bphys = ((tid & 7) ^ (srow & 7)) * 8;  // swizzled write slot element offset base (row-dependent part matches srow rows)

  f32x4 acc[8][4] = {};
  float4 breg[8];

#define SHALF(kt, b, h)                                                       \
  _Pragma("unroll") for (int i = 2 * (h); i < 2 * (h) + 2; i++) {             \
    gload_lds16(Ab + (size_t)(i * 64) * K + (size_t)(kt) * 64,                \
                &As[b][wave * 512 + i * 4096]);                               \
  }
// BLOAD(kt, h): 4 float4 covering rows h*128 + [0,128)
#define BLOAD(kt, h)                                                          \
  {                                                                           \
    const float* gp = Wbase + (size_t)((h) * 128) * K + (size_t)(kt) * 64;    \
    breg[(h) * 4 + 0] = *(const float4*)gp;                                   \
    breg[(h) * 4 + 1] = *(const float4*)(gp + 4);                             \
    breg[(h) * 4 + 2] = *(const float4*)(gp + (size_t)64 * K);                \
    breg[(h) * 4 + 3] = *(const float4*)(gp + (size_t)64 * K + 4);            \
  }
// WRITE_B(b): cvt 8 float4 -> 4 bf16x8, swizzled ds_write into Bs[b]
#define WRITE_B(b)                                                            \
  _Pragma("unroll") for (int h = 0; h < 2; h++)                               \
  _Pragma("unroll") for (int j = 0; j < 2; j++) {                             \
    int rr = h * 128 + j * 64 + srow;                                         \
    float4 lo = breg[h * 4 + j * 2 + 0];                                      \
    float4 hi = breg[h * 4 + j * 2 + 1];                                      \
    bf16x8 v;                                                                 \
    v[0] = (short)f2bf(lo.x); v[1] = (short)f2bf(lo.y);                       \
    v[2] = (short)f2bf(lo.z); v[3] = (short)f2bf(lo.w);                       \
    v[4] = (short)f2bf(hi.x); v[5] = (short)f2bf(hi.y);                       \
    v[6] = (short)f2bf(hi.z); v[7] = (short)f2bf(hi.w);                       \
    *(bf16x8*)&Bs[b][rr * 64 + (((tid & 7) ^ (rr & 7))) * 8] = v;             \
  }
#define LDFRAG(buf, rr, ks) \
  (*(const bf16x8*)&(buf)[(rr) * 64 + (((ks) * 4 + (lane >> 4)) ^ ((rr) & 7)) * 8])

  // ---- prologue ----
  BLOAD(k0, 0); BLOAD(k0, 1);            // 8 B-f32 loads (tile 0)
  SHALF(k0, 0, 0); SHALF(k0, 0, 1);      // 4 A gl_lds (tile 0)
  asm volatile("s_waitcnt vmcnt(4)" ::: "memory");   // B(0) landed; A in flight
  WRITE_B(0);
  if (nkp > 1) { BLOAD(k0 + 1, 0); BLOAD(k0 + 1, 1); }  // 8 B loads (tile 1)
  if (nkp > 1) asm volatile("s_waitcnt vmcnt(8)" ::: "memory");  // A(0) landed
  else         asm volatile("s_waitcnt vmcnt(0)" ::: "memory");
  asm volatile("s_waitcnt lgkmcnt(0)" ::: "memory");
  __builtin_amdgcn_s_barrier();
  __builtin_amdgcn_sched_barrier(0);

  for (int tau = 0; tau < nkp; tau++) {
    int b = tau & 1;
    bool s1 = (tau + 1 < nkp), s2 = (tau + 2 < nkp);
    const ushort* as = As[b];
    const ushort* bs = Bs[b];
    bf16x8 bfr[4][2];
#pragma unroll
    for (int p = 0; p < 4; p++) {
      bf16x8 af[2][2];
#pragma unroll
      for (int qq = 0; qq < 2; qq++) {
        int ra = wm * 128 + (p * 2 + qq) * 16 + (lane & 15);
#pragma unroll
        for (int ks = 0; ks < 2; ks++) af[qq][ks] = LDFRAG(as, ra, ks);
      }
      if (p == 0) {
#pragma unroll
        for (int f = 0; f < 4; f++) {
          int rb = wn * 64 + f * 16 + (lane & 15);
#pragma unroll
          for (int ks = 0; ks < 2; ks++) bfr[f][ks] = LDFRAG(bs, rb, ks);
        }
      }
      // stage slot
      if (p == 0 && s1) { SHALF(k0 + tau + 1, b ^ 1, 0); }
      if (p == 1 && s1) { SHALF(k0 + tau + 1, b ^ 1, 1); }
      if (p == 2 && s2) { BLOAD(k0 + tau + 2, 0); }
      if (p == 3 && s2) { BLOAD(k0 + tau + 2, 1); }
      __builtin_amdgcn_sched_barrier(0);
      __builtin_amdgcn_s_barrier();
      asm volatile("s_waitcnt lgkmcnt(0)" ::: "memory");
      __builtin_amdgcn_sched_barrier(0);
      __builtin_amdgcn_s_setprio(1);
#pragma unroll
      for (int qq = 0; qq < 2; qq++)
#pragma unroll
        for (int fn = 0; fn < 4; fn++)
#pragma unroll
          for (int ks = 0; ks < 2; ks++)
            acc[p * 2 + qq][fn] = __builtin_amdgcn_mfma_f32_16x16x32_bf16(
                af[qq][ks], bfr[fn][ks], acc[p * 2 + qq][fn], 0, 0, 0);
      __builtin_amdgcn_s_setprio(0);
      __builtin_amdgcn_sched_barrier(0);
      if (p == 1 && s1) {
        // B(tau+1) regs landed (issued 2 phases ago); cvt + write into freed buffer
        asm volatile("s_waitcnt vmcnt(4)" ::: "memory");
        WRITE_B(b ^ 1);
        __builtin_amdgcn_sched_barrier(0);
      }
      if (p == 3) {
        if (s2) asm volatile("s_waitcnt vmcnt(8)" ::: "memory");  // A(tau+1) landed; B(tau+2) in flight
        else    asm volatile("s_waitcnt vmcnt(0)" ::: "memory");
      }
      __builtin_amdgcn_s_barrier();
      __builtin_amdgcn_sched_barrier(0);
    }
  }
#undef SHALF
#undef BLOAD
#undef WRITE_B

  // ---- LoRA K-extension (split 0 only): K=32 slice, A=[t|0], B=[lb^T|0] ----
  if (z == 0) {
#pragma unroll
    for (int it = 0; it < 2; it++) {
      int task = tid + it * 512;  // 256 rows x 4 slots
      int rr = task >> 2, ls = task & 3;
      int ph = ls ^ (rr & 7);
      bf16x8 avv = {};
      bf16x8 bvv = {};
      if (ls < 2) {
        avv = *(const bf16x8*)&tp[(size_t)(m0 + rr) * LR + ls * 8];
#pragma unroll
        for (int j = 0; j < 8; j++)
          bvv[j] = (short)f2bf(lbp[(size_t)(ls * 8 + j) * wseg + nseg + rr]);
      }
      *(bf16x8*)&As[0][rr * 64 + ph * 8] = avv;
      *(bf16x8*)&Bs[0][rr * 64 + ph * 8] = bvv;
    }
    __syncthreads();
    bf16x8 af[8], bfr[4];
#pragma unroll
    for (int f = 0; f < 8; f++) {
      int ra = wm * 128 + f * 16 + (lane & 15);
      af[f] = LDFRAG(As[0], ra, 0);
    }
#pragma unroll
    for (int f = 0; f < 4; f++) {
      int rb = wn * 64 + f * 16 + (lane & 15);
      bfr[f] = LDFRAG(Bs[0], rb, 0);
    }
#pragma unroll
    for (int fm = 0; fm < 8; fm++)
#pragma unroll
      for (int fn = 0; fn < 4; fn++)
        acc[fm][fn] = __builtin_amdgcn_mfma_f32_16x16x32_bf16(af[fm], bfr[fn], acc[fm][fn], 0, 0, 0);
  }
#undef LDFRAG

  // ---- write ----
#pragma unroll
  for (int fm = 0; fm < 8; fm++) {
#pragma unroll
    for (int j = 0; j < 4; j++) {
      int mg = m0 + wm * 128 + fm * 16 + (lane >> 4) * 4 + j;
#pragma unroll
      for (int fn = 0; fn < 4; fn++) {
        int ng = n0 + wn * 64 + fn * 16 + (lane & 15);
        float v = acc[fm][fn][j];
        if (WM == 0) {
          ((ushort*)outp)[(size_t)mg * N + ng] = f2bf(v);
        } else {
          ((float*)outp)[((size_t)z * M + mg) * (size_t)N + ng] = v;
        }
      }
    }
  }
}

// ---------------- split-K reduces ----------------
__global__ __launch_bounds__(256) void reduce2_qkv_kernel(const float* __restrict__ p,
                                                          ushort* __restrict__ qb,
                                                          ushort* __restrict__ kb,
                                                          ushort* __restrict__ vtb) {
  size_t i4 = ((size_t)blockIdx.x * 256 + threadIdx.x) * 4;
  size_t sstride = (size_t)SEQ * 6144;
  int m = (int)(i4 / 6144);
  int c = (int)(i4 % 6144);
  float4 a = *(const float4*)&p[i4];
  float4 b = *(const float4*)&p[i4 + sstride];
  float4 s;
  s.x = a.x + b.x; s.y = a.y + b.y; s.z = a.z + b.z; s.w = a.w + b.w;
  if (c < DIM) {
    ushort4v o;
    o.x = f2bf(s.x); o.y = f2bf(s.y); o.z = f2bf(s.z); o.w = f2bf(s.w);
    *(ushort4v*)&qb[(size_t)m * DIM + c] = o;
  } else if (c < DIM + 1024) {
    ushort4v o;
    o.x = f2bf(s.x); o.y = f2bf(s.y); o.z = f2bf(s.z); o.w = f2bf(s.w);
    *(ushort4v*)&kb[(size_t)m * 1024 + (c - DIM)] = o;
  } else {
    int n = c - DIM - 1024;
    vtb[(size_t)(n + 0) * SEQ + m] = f2bf(s.x);
    vtb[(size_t)(n + 1) * SEQ + m] = f2bf(s.y);
    vtb[(size_t)(n + 2) * SEQ + m] = f2bf(s.z);
    vtb[(size_t)(n + 3) * SEQ + m] = f2bf(s.w);
  }
}

__global__ __launch_bounds__(256) void reduce4_res_kernel(const float* __restrict__ p,
                                                          const float* __restrict__ res,
                                                          float* __restrict__ out,
                                                          size_t sstride) {
  size_t i = ((size_t)blockIdx.x * 256 + threadIdx.x) * 4;
  float4 a = *(const float4*)&p[i];
  float4 b = *(const float4*)&p[i + sstride];
  float4 c = *(const float4*)&p[i + 2 * sstride];
  float4 d = *(const float4*)&p[i + 3 * sstride];
  float4 r = *(const float4*)&res[i];
  float4 o;
  o.x = a.x + b.x + c.x + d.x + r.x;
  o.y = a.y + b.y + c.y + d.y + r.y;
  o.z = a.z + b.z + c.z + d.z + r.z;
  o.w = a.w + b.w + c.w + d.w + r.w;
  *(float4*)&out[i] = o;
}

// ---------------- RoPE (in-place, bf16), rotate_half, optional scale ----------------
__global__ __launch_bounds__(256) void rope_kernel(ushort* __restrict__ x,
                                                   const float* __restrict__ ct,
                                                   const float* __restrict__ st,
                                                   int nheads, float scale) {
  int idx = blockIdx.x * 256 + threadIdx.x;
  int d = idx & 63;
  int hh = (idx >> 6) % nheads;
  int s = idx / (64 * nheads);
  ushort* p = x + (size_t)s * (nheads * HD) + hh * HD + d;
  float x1 = bf2f(p[0]), x2 = bf2f(p[64]);
  float c = ct[s * HD + d], sn = st[s * HD + d];
  p[0] = f2bf((x1 * c - x2 * sn) * scale);
  p[64] = f2bf((x2 * c + x1 * sn) * scale);
}

// ---------------- Flash attention (causal, GQA 4:1) ----------------
__global__ __launch_bounds__(256) void attn_kernel(const ushort* __restrict__ q,
                                                   const ushort* __restrict__ k,
                                                   const ushort* __restrict__ vt,
                                                   ushort* __restrict__ o) {
  int qb = blockIdx.x, h = blockIdx.y, kvh = h >> 2;
  int tid = threadIdx.x, lane = tid & 63, wave = tid >> 6;
  __shared__ ushort Ks[64][136];
  __shared__ ushort Vs[128][72];
  __shared__ ushort Ps[4][16][72];

  bf16x8 qf[4];
  int qrow = qb * 64 + wave * 16 + (lane & 15);
#pragma unroll
  for (int kk = 0; kk < 4; kk++)
    qf[kk] = *(const bf16x8*)&q[(size_t)qrow * DIM + h * HD + kk * 32 + (lane >> 4) * 8];

  f32x4 oacc[8] = {};
  float mrow[4], lrow[4];
  int qr[4];
#pragma unroll
  for (int j = 0; j < 4; j++) {
    mrow[j] = -INFINITY; lrow[j] = 0.f;
    qr[j] = qb * 64 + wave * 16 + (lane >> 4) * 4 + j;
  }

  for (int kt = 0; kt <= qb; kt++) {
    int key0 = kt * 64;
#pragma unroll
    for (int c = 0; c < 4; c++) {
      int e = tid * 32 + c * 8;
      int r = e >> 7, cc = e & 127;
      *(bf16x8*)&Ks[r][cc] =
          *(const bf16x8*)&k[(size_t)(key0 + r) * (NKVH * HD) + kvh * HD + cc];
      int r2 = e >> 6, cc2 = e & 63;
      *(bf16x8*)&Vs[r2][cc2] =
          *(const bf16x8*)&vt[(size_t)(kvh * HD + r2) * SEQ + key0 + cc2];
    }
    __syncthreads();

    f32x4 sf[4] = {};
#pragma unroll
    for (int fn = 0; fn < 4; fn++)
#pragma unroll
      for (int kk = 0; kk < 4; kk++) {
        bf16x8 kf = *(const bf16x8*)&Ks[fn * 16 + (lane & 15)][kk * 32 + (lane >> 4) * 8];
        sf[fn] = __builtin_amdgcn_mfma_f32_16x16x32_bf16(qf[kk], kf, sf[fn], 0, 0, 0);
      }

#pragma unroll
    for (int fn = 0; fn < 4; fn++) {
      int key = key0 + fn * 16 + (lane & 15);
#pragma unroll
      for (int j = 0; j < 4; j++)
        if (key > qr[j]) sf[fn][j] = -INFINITY;
    }

#pragma unroll
    for (int j = 0; j < 4; j++) {
      float mx = fmaxf(fmaxf(sf[0][j], sf[1][j]), fmaxf(sf[2][j], sf[3][j]));
#pragma unroll
      for (int off = 1; off < 16; off <<= 1) mx = fmaxf(mx, __shfl_xor(mx, off));
      float mnew = fmaxf(mrow[j], mx);
      float sc = __expf(mrow[j] - mnew);
      mrow[j] = mnew;
      float rs = 0.f;
#pragma unroll
      for (int fn = 0; fn < 4; fn++) {
        float p = __expf(sf[fn][j] - mnew);
        sf[fn][j] = p;
        rs += p;
      }
#pragma unroll
      for (int off = 1; off < 16; off <<= 1) rs += __shfl_xor(rs, off);
      lrow[j] = lrow[j] * sc + rs;
#pragma unroll
      for (int f2 = 0; f2 < 8; f2++) oacc[f2][j] *= sc;
    }

#pragma unroll
    for (int fn = 0; fn < 4; fn++)
#pragma unroll
      for (int j = 0; j < 4; j++)
        Ps[wave][(lane >> 4) * 4 + j][fn * 16 + (lane & 15)] = f2bf(sf[fn][j]);

#pragma unroll
    for (int kk = 0; kk < 2; kk++) {
      bf16x8 pf = *(const bf16x8*)&Ps[wave][lane & 15][kk * 32 + (lane >> 4) * 8];
#pragma unroll
      for (int f2 = 0; f2 < 8; f2++) {
        bf16x8 vf = *(const bf16x8*)&Vs[f2 * 16 + (lane & 15)][kk * 32 + (lane >> 4) * 8];
        oacc[f2] = __builtin_amdgcn_mfma_f32_16x16x32_bf16(pf, vf, oacc[f2], 0, 0, 0);
      }
    }
    __syncthreads();
  }

#pragma unroll
  for (int j = 0; j < 4; j++) {
    float inv = 1.f / lrow[j];
#pragma unroll
    for (int f2 = 0; f2 < 8; f2++)
      o[(size_t)qr[j] * DIM + h * HD + f2 * 16 + (lane & 15)] = f2bf(oacc[f2][j] * inv);
  }
}

// ---------------- h = silu(gate) * up ----------------
__global__ __launch_bounds__(256) void silu_mul_kernel(const ushort* __restrict__ g,
                                                       const ushort* __restrict__ u,
                                                       ushort* __restrict__ h) {
  size_t idx = (size_t)(blockIdx.x * 256 + threadIdx.x) * 8;
  bf16x8 gv = *(const bf16x8*)&g[idx];
  bf16x8 uv = *(const bf16x8*)&u[idx];
  bf16x8 hv;
#pragma unroll
  for (int i = 0; i < 8; i++) {
    float gf = bf2f((ushort)gv[i]);
    float uf = bf2f((ushort)uv[i]);
    float sv = gf / (1.f + __expf(-gf));
    hv[i] = (short)f2bf(sv * uf);
  }
  *(bf16x8*)&h[idx] = hv;
}

extern "C" void kernel_launch(void* const* d_in, const int* in_sizes, int n_in,
                              void* d_out, int out_size, void* d_ws, size_t ws_size,
                              hipStream_t stream) {
  const float* x    = (const float*)d_in[0];
  const float* w1   = (const float*)d_in[1];
  const float* w2   = (const float*)d_in[2];
  const float* cosT = (const float*)d_in[3];
  const float* sinT = (const float*)d_in[4];
  const float* wq = (const float*)d_in[6];
  const float* la_q = (const float*)d_in[7];
  const float* lb_q = (const float*)d_in[8];
  const float* wk = (const float*)d_in[9];
  const float* la_k = (const float*)d_in[10];
  const float* lb_k = (const float*)d_in[11];
  const float* wv = (const float*)d_in[12];
  const float* la_v = (const float*)d_in[13];
  const float* lb_v = (const float*)d_in[14];
  const float* wo = (const float*)d_in[15];
  const float* la_o = (const float*)d_in[16];
  const float* lb_o = (const float*)d_in[17];
  const float* wg = (const float*)d_in[18];
  const float* la_g = (const float*)d_in[19];
  const float* lb_g = (const float*)d_in[20];
  const float* wu = (const float*)d_in[21];
  const float* la_u = (const float*)d_in[22];
  const float* lb_u = (const float*)d_in[23];
  const float* wd = (const float*)d_in[24];
  const float* la_d = (const float*)d_in[25];
  const float* lb_d = (const float*)d_in[26];
  float* out = (float*)d_out;

  char* ws = (char*)d_ws;
  ushort* xn1 = (ushort*)ws;  ws += (size_t)SEQ * DIM * 2;   // 8 MB
  ushort* qb  = (ushort*)ws;  ws += (size_t)SEQ * DIM * 2;   // 8 MB
  ushort* kb  = (ushort*)ws;  ws += (size_t)SEQ * NKVH * HD * 2;
  ushort* vtb = (ushort*)ws;  ws += (size_t)SEQ * NKVH * HD * 2;
  ushort* ob  = (ushort*)ws;  ws += (size_t)SEQ * DIM * 2;
  float*  xmed= (float*)ws;   ws += (size_t)SEQ * DIM * 4;   // 16 MB
  ushort* xn2 = (ushort*)ws;  ws += (size_t)SEQ * DIM * 2;   // 8 MB
  ushort* gate= (ushort*)ws;  ws += (size_t)SEQ * FF * 2;    // 28 MB
  ushort* up  = (ushort*)ws;  ws += (size_t)SEQ * FF * 2;    // 28 MB
  ushort* hb  = (ushort*)ws;  ws += (size_t)SEQ * FF * 2;    // 28 MB
  ushort* t_q = (ushort*)ws; ws += SEQ * LR * 2;
  ushort* t_k = (ushort*)ws; ws += SEQ * LR * 2;
  ushort* t_v = (ushort*)ws; ws += SEQ * LR * 2;
  ushort* t_o = (ushort*)ws; ws += SEQ * LR * 2;
  ushort* t_g = (ushort*)ws; ws += SEQ * LR * 2;
  ushort* t_u = (ushort*)ws; ws += SEQ * LR * 2;
  ushort* t_d = (ushort*)ws; ws += SEQ * LR * 2;

  // split-K partial buffers aliased onto dead regions:
  float* pbuf1 = (float*)gate;  // QKV (50 MB) / wo (64 MB): gate..hb dead then
  float* pbuf2 = (float*)xn2;   // wd (64 MB): xn2+gate+up dead then, ends at hb

  size_t snd = (size_t)SEQ * DIM;

  // 1) norm + fused lora-A (q,k,v share xn1)
  rmsnorm_kernel<<<SEQ, 256, 0, stream>>>(x, w1, xn1);
  lora_a_kernel<3><<<SEQ, 256, 0, stream>>>(xn1, la_q, la_k, la_v, t_q, t_k, t_v, DIM);

  // 2) fused QKV GEMM (N=6144, split-K2, fused dequant) -> routed reduce
  gemm256_kernel<3><<<dim3((DIM + 2048) / 256, SEQ / 256, 2), 512, 0, stream>>>(
      xn1, wq, wk, wv, lb_q, lb_k, lb_v, t_q, t_k, t_v, DIM, DIM + 1024,
      pbuf1, SEQ, DIM + 2048, DIM, 32);
  reduce2_qkv_kernel<<<SEQ * (DIM + 2048) / 1024, 256, 0, stream>>>(pbuf1, qb, kb, vtb);

  // 3) RoPE (q pre-scaled by 1/sqrt(HD)) + attention
  rope_kernel<<<SEQ * NH * 64 / 256, 256, 0, stream>>>(qb, cosT, sinT, NH, 0.08838834764831845f);
  rope_kernel<<<SEQ * NKVH * 64 / 256, 256, 0, stream>>>(kb, cosT, sinT, NKVH, 1.0f);
  attn_kernel<<<dim3(SEQ / 64, NH), 256, 0, stream>>>(qb, kb, vtb, ob);

  // 4) WO (split-K4, fused dequant) + residual -> xmed
  lora_a_kernel<1><<<SEQ, 256, 0, stream>>>(ob, la_o, la_o, la_o, t_o, t_o, t_o, DIM);
  gemm256_kernel<3><<<dim3(DIM / 256, SEQ / 256, 4), 512, 0, stream>>>(
      ob, wo, wo, wo, lb_o, lb_o, lb_o, t_o, t_o, t_o, DIM, DIM,
      pbuf1, SEQ, DIM, DIM, 16);
  reduce4_res_kernel<<<snd / 1024, 256, 0, stream>>>(pbuf1, x, xmed, snd);

  // 5) FFN (g,u share xn2)
  rmsnorm_kernel<<<SEQ, 256, 0, stream>>>(xmed, w2, xn2);
  lora_a_kernel<2><<<SEQ, 256, 0, stream>>>(xn2, la_g, la_u, la_u, t_g, t_u, t_u, DIM);
  gemm256_kernel<0><<<dim3(FF / 256, SEQ / 256, 1), 512, 0, stream>>>(
      xn2, wg, wg, wg, lb_g, lb_g, lb_g, t_g, t_g, t_g, FF, FF,
      gate, SEQ, FF, DIM, DIM / 64);
  gemm256_kernel<0><<<dim3(FF / 256, SEQ / 256, 1), 512, 0, stream>>>(
      xn2, wu, wu, wu, lb_u, lb_u, lb_u, t_u, t_u, t_u, FF, FF,
      up, SEQ, FF, DIM, DIM / 64);
  silu_mul_kernel<<<SEQ * FF / 8 / 256, 256, 0, stream>>>(gate, up, hb);
  lora_a_kernel<1><<<SEQ, 256, 0, stream>>>(hb, la_d, la_d, la_d, t_d, t_d, t_d, FF);
  gemm256_kernel<3><<<dim3(DIM / 256, SEQ / 256, 4), 512, 0, stream>>>(
      hb, wd, wd, wd, lb_d, lb_d, lb_d, t_d, t_d, t_d, DIM, DIM,
      pbuf2, SEQ, DIM, FF, FF / 4 / 64);
  reduce4_res_kernel<<<snd / 1024, 256, 0, stream>>>(pbuf2, xmed, out, snd);
}

// Round 12
// 912.347 us; speedup vs baseline: 1.5861x; 1.0972x over previous
//
#include <hip/hip_runtime.h>
#include <hip/hip_bf16.h>
#include <math.h>

#define SEQ 1024
#define DIM 4096
#define NH 32
#define HD 128
#define NKVH 8
#define FF 14336
#define LR 16

typedef __attribute__((ext_vector_type(8))) short bf16x8;
typedef __attribute__((ext_vector_type(4))) float f32x4;
typedef __attribute__((ext_vector_type(4))) ushort ushort4v;

__device__ __forceinline__ ushort f2bf(float f) {
  union { float f; unsigned u; } v; v.f = f;
  unsigned r = (v.u + 0x7FFFu + ((v.u >> 16) & 1u)) >> 16;
  return (ushort)r;
}
__device__ __forceinline__ float bf2f(ushort h) {
  union { unsigned u; float f; } v; v.u = ((unsigned)h) << 16;
  return v.f;
}

__device__ __forceinline__ void gload_lds16(const void* g, void* l) {
  __builtin_amdgcn_global_load_lds(
      (const __attribute__((address_space(1))) void*)g,
      (__attribute__((address_space(3))) void*)l, 16, 0, 0);
}

// ---------------- RMSNorm: f32 in -> bf16 out ----------------
__global__ __launch_bounds__(256) void rmsnorm_kernel(const float* __restrict__ x,
                                                      const float* __restrict__ w,
                                                      ushort* __restrict__ out) {
  int row = blockIdx.x;
  int tid = threadIdx.x;
  const float* xr = x + (size_t)row * DIM;
  float vals[16];
  float s = 0.f;
#pragma unroll
  for (int c = 0; c < 4; c++) {
    float4 v = *(const float4*)&xr[(tid + c * 256) * 4];
    vals[c * 4 + 0] = v.x; vals[c * 4 + 1] = v.y;
    vals[c * 4 + 2] = v.z; vals[c * 4 + 3] = v.w;
    s += v.x * v.x + v.y * v.y + v.z * v.z + v.w * v.w;
  }
#pragma unroll
  for (int off = 32; off >= 1; off >>= 1) s += __shfl_down(s, off);
  __shared__ float wsum[4];
  __shared__ float scale_s;
  int lane = tid & 63, wv = tid >> 6;
  if (lane == 0) wsum[wv] = s;
  __syncthreads();
  if (tid == 0) {
    float t = wsum[0] + wsum[1] + wsum[2] + wsum[3];
    scale_s = rsqrtf(t / (float)DIM + 1e-5f);
  }
  __syncthreads();
  float scale = scale_s;
  ushort* orow = out + (size_t)row * DIM;
#pragma unroll
  for (int c = 0; c < 4; c++) {
    int base = (tid + c * 256) * 4;
    float4 wv4 = *(const float4*)&w[base];
    ushort4v ov;
    ov.x = f2bf(vals[c * 4 + 0] * scale * wv4.x);
    ov.y = f2bf(vals[c * 4 + 1] * scale * wv4.y);
    ov.z = f2bf(vals[c * 4 + 2] * scale * wv4.z);
    ov.w = f2bf(vals[c * 4 + 3] * scale * wv4.w);
    *(ushort4v*)&orow[base] = ov;
  }
}

// ---------------- LoRA A: t_l[m][16] = A[m] @ la_l, one row per block ----------------
template <int NL>
__global__ __launch_bounds__(256) void lora_a_kernel(
    const ushort* __restrict__ A,
    const float* __restrict__ la0, const float* __restrict__ la1,
    const float* __restrict__ la2,
    ushort* __restrict__ t0, ushort* __restrict__ t1, ushort* __restrict__ t2,
    int K) {
  int m = blockIdx.x, i = threadIdx.x;
  float acc[NL][16];
#pragma unroll
  for (int l = 0; l < NL; l++)
#pragma unroll
    for (int n = 0; n < 16; n++) acc[l][n] = 0.f;

  const ushort* Arow = A + (size_t)m * K;
  int nc = K >> 8;
  for (int c = 0; c < nc; c++) {
    int k = c * 256 + i;
    float a = bf2f(Arow[k]);
#pragma unroll
    for (int l = 0; l < NL; l++) {
      const float* lap = (l == 0 ? la0 : (l == 1 ? la1 : la2)) + (size_t)k * 16;
#pragma unroll
      for (int q = 0; q < 4; q++) {
        float4 lv = *(const float4*)&lap[q * 4];
        acc[l][q * 4 + 0] += a * lv.x;
        acc[l][q * 4 + 1] += a * lv.y;
        acc[l][q * 4 + 2] += a * lv.z;
        acc[l][q * 4 + 3] += a * lv.w;
      }
    }
  }

  __shared__ float red[256][17];
  __shared__ float red2[16][17];
#pragma unroll
  for (int l = 0; l < NL; l++) {
    __syncthreads();
#pragma unroll
    for (int n = 0; n < 16; n++) red[i][n] = acc[l][n];
    __syncthreads();
    {
      int g = i >> 4, n = i & 15;
      float s = 0.f;
#pragma unroll
      for (int j = 0; j < 16; j++) s += red[g * 16 + j][n];
      red2[g][n] = s;
    }
    __syncthreads();
    if (i < 16) {
      float s2 = 0.f;
#pragma unroll
      for (int g2 = 0; g2 < 16; g2++) s2 += red2[g2][i];
      ushort* tp = (l == 0 ? t0 : (l == 1 ? t1 : t2));
      tp[(size_t)m * LR + i] = f2bf(s2);
    }
  }
}

// ================= 256x256 GEMM, 8 waves, 8-phase schedule, FUSED f32->bf16 dequant =================
// Panel-sharer co-location: wgid decodes bx OUTER, (by,z) inner, so the gy blocks
// sharing one weight panel+K-range are adjacent wgid -> same XCD L2.
// WM 0: bf16 [M][N]; WM 3: f32 partial [z][M][N]; WM 4: bf16 silu(gate)*v
template <int WM>
__global__ __launch_bounds__(512) void gemm256_kernel(
    const ushort* __restrict__ A,
    const float* __restrict__ W0, const float* __restrict__ W1, const float* __restrict__ W2,
    const float* __restrict__ lb0, const float* __restrict__ lb1, const float* __restrict__ lb2,
    const ushort* __restrict__ t0, const ushort* __restrict__ t1, const ushort* __restrict__ t2,
    const ushort* __restrict__ gatep,
    int c1, int c2, void* __restrict__ outp, int M, int N, int K, int nkp) {
  __shared__ __align__(16) ushort As[2][256 * 64];
  __shared__ __align__(16) ushort Bs[2][256 * 64];
  int tid = threadIdx.x;
  int lane = tid & 63, wave = tid >> 6;
  int wm = wave >> 2, wn = wave & 3;

  // ---- T1 XCD swizzle + panel-sharer-adjacent decode ----
  int gx = gridDim.x, gy = gridDim.y, gz = gridDim.z;
  int flat = blockIdx.x + gx * (blockIdx.y + gy * blockIdx.z);
  int nwg = gx * gy * gz;
  int q = nwg >> 3, r = nwg & 7;
  int xcd = flat & 7;
  int wgid = (xcd < r ? xcd * (q + 1) : r * (q + 1) + (xcd - r) * q) + (flat >> 3);
  int sh = gy * gz;
  int bx = wgid / sh;
  int rem = wgid - bx * sh;
  int z = rem / gy;
  int by = rem - z * gy;

  int n0 = bx * 256, m0 = by * 256;
  int k0 = z * nkp;

  // segment select (weight + lora)
  const float* Wp; const float* lbp; const ushort* tp; int nseg, wseg;
  if (n0 < c1)      { Wp = W0; lbp = lb0; tp = t0; nseg = n0;      wseg = c1; }
  else if (n0 < c2) { Wp = W1; lbp = lb1; tp = t1; nseg = n0 - c1; wseg = c2 - c1; }
  else              { Wp = W2; lbp = lb2; tp = t2; nseg = n0 - c2; wseg = N - c2; }

  // A staging
  int srow = tid >> 3;
  int sswz = ((tid & 7) ^ (srow & 7)) * 8;
  const ushort* Ab = A + (size_t)(m0 + srow) * K + sswz;
  // B reg-staging source (linear; swizzle at ds_write)
  const float* Wbase = Wp + (size_t)(nseg + srow) * K + (tid & 7) * 8;

  f32x4 acc[8][4] = {};
  float4 breg[8];

#define SHALF(kt, b, h)                                                       \
  _Pragma("unroll") for (int i = 2 * (h); i < 2 * (h) + 2; i++) {             \
    gload_lds16(Ab + (size_t)(i * 64) * K + (size_t)(kt) * 64,                \
                &As[b][wave * 512 + i * 4096]);                               \
  }
#define BLOAD(kt, h)                                                          \
  {                                                                           \
    const float* gp = Wbase + (size_t)((h) * 128) * K + (size_t)(kt) * 64;    \
    breg[(h) * 4 + 0] = *(const float4*)gp;                                   \
    breg[(h) * 4 + 1] = *(const float4*)(gp + 4);                             \
    breg[(h) * 4 + 2] = *(const float4*)(gp + (size_t)64 * K);                \
    breg[(h) * 4 + 3] = *(const float4*)(gp + (size_t)64 * K + 4);            \
  }
#define WRITE_B(b)                                                            \
  _Pragma("unroll") for (int h = 0; h < 2; h++)                               \
  _Pragma("unroll") for (int j = 0; j < 2; j++) {                             \
    int rr = h * 128 + j * 64 + srow;                                         \
    float4 lo = breg[h * 4 + j * 2 + 0];                                      \
    float4 hi = breg[h * 4 + j * 2 + 1];                                      \
    bf16x8 v;                                                                 \
    v[0] = (short)f2bf(lo.x); v[1] = (short)f2bf(lo.y);                       \
    v[2] = (short)f2bf(lo.z); v[3] = (short)f2bf(lo.w);                       \
    v[4] = (short)f2bf(hi.x); v[5] = (short)f2bf(hi.y);                       \
    v[6] = (short)f2bf(hi.z); v[7] = (short)f2bf(hi.w);                       \
    *(bf16x8*)&Bs[b][rr * 64 + (((tid & 7) ^ (rr & 7))) * 8] = v;             \
  }
#define LDFRAG(buf, rr, ks) \
  (*(const bf16x8*)&(buf)[(rr) * 64 + (((ks) * 4 + (lane >> 4)) ^ ((rr) & 7)) * 8])

  // ---- prologue ----
  BLOAD(k0, 0); BLOAD(k0, 1);
  SHALF(k0, 0, 0); SHALF(k0, 0, 1);
  asm volatile("s_waitcnt vmcnt(4)" ::: "memory");
  WRITE_B(0);
  if (nkp > 1) { BLOAD(k0 + 1, 0); BLOAD(k0 + 1, 1); }
  if (nkp > 1) asm volatile("s_waitcnt vmcnt(8)" ::: "memory");
  else         asm volatile("s_waitcnt vmcnt(0)" ::: "memory");
  asm volatile("s_waitcnt lgkmcnt(0)" ::: "memory");
  __builtin_amdgcn_s_barrier();
  __builtin_amdgcn_sched_barrier(0);

  for (int tau = 0; tau < nkp; tau++) {
    int b = tau & 1;
    bool s1 = (tau + 1 < nkp), s2 = (tau + 2 < nkp);
    const ushort* as = As[b];
    const ushort* bs = Bs[b];
    bf16x8 bfr[4][2];
#pragma unroll
    for (int p = 0; p < 4; p++) {
      bf16x8 af[2][2];
#pragma unroll
      for (int qq = 0; qq < 2; qq++) {
        int ra = wm * 128 + (p * 2 + qq) * 16 + (lane & 15);
#pragma unroll
        for (int ks = 0; ks < 2; ks++) af[qq][ks] = LDFRAG(as, ra, ks);
      }
      if (p == 0) {
#pragma unroll
        for (int f = 0; f < 4; f++) {
          int rb = wn * 64 + f * 16 + (lane & 15);
#pragma unroll
          for (int ks = 0; ks < 2; ks++) bfr[f][ks] = LDFRAG(bs, rb, ks);
        }
      }
      if (p == 0 && s1) { SHALF(k0 + tau + 1, b ^ 1, 0); }
      if (p == 1 && s1) { SHALF(k0 + tau + 1, b ^ 1, 1); }
      if (p == 2 && s2) { BLOAD(k0 + tau + 2, 0); }
      if (p == 3 && s2) { BLOAD(k0 + tau + 2, 1); }
      __builtin_amdgcn_sched_barrier(0);
      __builtin_amdgcn_s_barrier();
      asm volatile("s_waitcnt lgkmcnt(0)" ::: "memory");
      __builtin_amdgcn_sched_barrier(0);
      __builtin_amdgcn_s_setprio(1);
#pragma unroll
      for (int qq = 0; qq < 2; qq++)
#pragma unroll
        for (int fn = 0; fn < 4; fn++)
#pragma unroll
          for (int ks = 0; ks < 2; ks++)
            acc[p * 2 + qq][fn] = __builtin_amdgcn_mfma_f32_16x16x32_bf16(
                af[qq][ks], bfr[fn][ks], acc[p * 2 + qq][fn], 0, 0, 0);
      __builtin_amdgcn_s_setprio(0);
      __builtin_amdgcn_sched_barrier(0);
      if (p == 1 && s1) {
        asm volatile("s_waitcnt vmcnt(4)" ::: "memory");
        WRITE_B(b ^ 1);
        __builtin_amdgcn_sched_barrier(0);
      }
      if (p == 3) {
        if (s2) asm volatile("s_waitcnt vmcnt(8)" ::: "memory");
        else    asm volatile("s_waitcnt vmcnt(0)" ::: "memory");
      }
      __builtin_amdgcn_s_barrier();
      __builtin_amdgcn_sched_barrier(0);
    }
  }
#undef SHALF
#undef BLOAD
#undef WRITE_B

  // ---- LoRA K-extension (split 0 only) ----
  if (z == 0) {
#pragma unroll
    for (int it = 0; it < 2; it++) {
      int task = tid + it * 512;
      int rr = task >> 2, ls = task & 3;
      int ph = ls ^ (rr & 7);
      bf16x8 avv = {};
      bf16x8 bvv = {};
      if (ls < 2) {
        avv = *(const bf16x8*)&tp[(size_t)(m0 + rr) * LR + ls * 8];
#pragma unroll
        for (int j = 0; j < 8; j++)
          bvv[j] = (short)f2bf(lbp[(size_t)(ls * 8 + j) * wseg + nseg + rr]);
      }
      *(bf16x8*)&As[0][rr * 64 + ph * 8] = avv;
      *(bf16x8*)&Bs[0][rr * 64 + ph * 8] = bvv;
    }
    __syncthreads();
    bf16x8 af[8], bfr[4];
#pragma unroll
    for (int f = 0; f < 8; f++) {
      int ra = wm * 128 + f * 16 + (lane & 15);
      af[f] = LDFRAG(As[0], ra, 0);
    }
#pragma unroll
    for (int f = 0; f < 4; f++) {
      int rb = wn * 64 + f * 16 + (lane & 15);
      bfr[f] = LDFRAG(Bs[0], rb, 0);
    }
#pragma unroll
    for (int fm = 0; fm < 8; fm++)
#pragma unroll
      for (int fn = 0; fn < 4; fn++)
        acc[fm][fn] = __builtin_amdgcn_mfma_f32_16x16x32_bf16(af[fm], bfr[fn], acc[fm][fn], 0, 0, 0);
  }
#undef LDFRAG

  // ---- write ----
#pragma unroll
  for (int fm = 0; fm < 8; fm++) {
#pragma unroll
    for (int j = 0; j < 4; j++) {
      int mg = m0 + wm * 128 + fm * 16 + (lane >> 4) * 4 + j;
#pragma unroll
      for (int fn = 0; fn < 4; fn++) {
        int ng = n0 + wn * 64 + fn * 16 + (lane & 15);
        float v = acc[fm][fn][j];
        if (WM == 0) {
          ((ushort*)outp)[(size_t)mg * N + ng] = f2bf(v);
        } else if (WM == 4) {
          float g = bf2f(gatep[(size_t)mg * N + ng]);
          float sv = g / (1.f + __expf(-g));
          ((ushort*)outp)[(size_t)mg * N + ng] = f2bf(sv * v);
        } else {
          ((float*)outp)[((size_t)z * M + mg) * (size_t)N + ng] = v;
        }
      }
    }
  }
}

// ---------------- QKV reduce + fused RoPE (q scaled) + V transpose ----------------
// p: 2 slices of [SEQ][6144]. Per row: 512 q-pair-vecs, 128 k-pair-vecs, 256 v-vecs = 896 items.
__global__ __launch_bounds__(256) void reduce2_qkv_rope(const float* __restrict__ p,
                                                        const float* __restrict__ ct,
                                                        const float* __restrict__ st,
                                                        ushort* __restrict__ qb,
                                                        ushort* __restrict__ kb,
                                                        ushort* __restrict__ vtb) {
  int gidx = blockIdx.x * 256 + threadIdx.x;
  int r = gidx / 896, j = gidx - r * 896;
  size_t row = (size_t)r * 6144;
  size_t sstride = (size_t)SEQ * 6144;
  if (j < 640) {
    bool isq = j < 512;
    int jj = isq ? j : j - 512;
    int h = jj >> 4, d0 = (jj & 15) * 4;
    size_t base = row + (isq ? 0 : DIM) + h * 128 + d0;
    float4 a1 = *(const float4*)&p[base];
    float4 b1 = *(const float4*)&p[base + sstride];
    float4 a2 = *(const float4*)&p[base + 64];
    float4 b2 = *(const float4*)&p[base + 64 + sstride];
    float4 x1, x2;
    x1.x = a1.x + b1.x; x1.y = a1.y + b1.y; x1.z = a1.z + b1.z; x1.w = a1.w + b1.w;
    x2.x = a2.x + b2.x; x2.y = a2.y + b2.y; x2.z = a2.z + b2.z; x2.w = a2.w + b2.w;
    float4 c = *(const float4*)&ct[r * HD + d0];
    float4 s = *(const float4*)&st[r * HD + d0];
    float sc = isq ? 0.08838834764831845f : 1.0f;
    ushort4v o1, o2;
    o1.x = f2bf((x1.x * c.x - x2.x * s.x) * sc);
    o1.y = f2bf((x1.y * c.y - x2.y * s.y) * sc);
    o1.z = f2bf((x1.z * c.z - x2.z * s.z) * sc);
    o1.w = f2bf((x1.w * c.w - x2.w * s.w) * sc);
    o2.x = f2bf((x2.x * c.x + x1.x * s.x) * sc);
    o2.y = f2bf((x2.y * c.y + x1.y * s.y) * sc);
    o2.z = f2bf((x2.z * c.z + x1.z * s.z) * sc);
    o2.w = f2bf((x2.w * c.w + x1.w * s.w) * sc);
    if (isq) {
      *(ushort4v*)&qb[(size_t)r * DIM + h * 128 + d0] = o1;
      *(ushort4v*)&qb[(size_t)r * DIM + h * 128 + d0 + 64] = o2;
    } else {
      *(ushort4v*)&kb[(size_t)r * 1024 + h * 128 + d0] = o1;
      *(ushort4v*)&kb[(size_t)r * 1024 + h * 128 + d0 + 64] = o2;
    }
  } else {
    int jj = j - 640;
    int c0 = jj * 4;
    size_t base = row + DIM + 1024 + c0;
    float4 a = *(const float4*)&p[base];
    float4 b = *(const float4*)&p[base + sstride];
    vtb[(size_t)(c0 + 0) * SEQ + r] = f2bf(a.x + b.x);
    vtb[(size_t)(c0 + 1) * SEQ + r] = f2bf(a.y + b.y);
    vtb[(size_t)(c0 + 2) * SEQ + r] = f2bf(a.z + b.z);
    vtb[(size_t)(c0 + 3) * SEQ + r] = f2bf(a.w + b.w);
  }
}

// ---------------- split-K reduce + residual -> f32 out ----------------
__global__ __launch_bounds__(256) void reduce4_res_kernel(const float* __restrict__ p,
                                                          const float* __restrict__ res,
                                                          float* __restrict__ out,
                                                          size_t sstride) {
  size_t i = ((size_t)blockIdx.x * 256 + threadIdx.x) * 4;
  float4 a = *(const float4*)&p[i];
  float4 b = *(const float4*)&p[i + sstride];
  float4 c = *(const float4*)&p[i + 2 * sstride];
  float4 d = *(const float4*)&p[i + 3 * sstride];
  float4 r = *(const float4*)&res[i];
  float4 o;
  o.x = a.x + b.x + c.x + d.x + r.x;
  o.y = a.y + b.y + c.y + d.y + r.y;
  o.z = a.z + b.z + c.z + d.z + r.z;
  o.w = a.w + b.w + c.w + d.w + r.w;
  *(float4*)&out[i] = o;
}

// ---------------- split-K reduce + residual + fused RMSNorm (one row/block) ----------------
__global__ __launch_bounds__(256) void reduce4_res_rms(const float* __restrict__ p,
                                                       const float* __restrict__ res,
                                                       const float* __restrict__ w,
                                                       float* __restrict__ xmed,
                                                       ushort* __restrict__ xn2,
                                                       size_t sstride) {
  int row = blockIdx.x, tid = threadIdx.x;
  size_t base = (size_t)row * DIM;
  float vals[16];
  float sq = 0.f;
#pragma unroll
  for (int c = 0; c < 4; c++) {
    size_t i = base + (tid + c * 256) * 4;
    float4 a = *(const float4*)&p[i];
    float4 b = *(const float4*)&p[i + sstride];
    float4 cc = *(const float4*)&p[i + 2 * sstride];
    float4 d = *(const float4*)&p[i + 3 * sstride];
    float4 r = *(const float4*)&res[i];
    float4 v;
    v.x = a.x + b.x + cc.x + d.x + r.x;
    v.y = a.y + b.y + cc.y + d.y + r.y;
    v.z = a.z + b.z + cc.z + d.z + r.z;
    v.w = a.w + b.w + cc.w + d.w + r.w;
    *(float4*)&xmed[i] = v;
    vals[c * 4 + 0] = v.x; vals[c * 4 + 1] = v.y;
    vals[c * 4 + 2] = v.z; vals[c * 4 + 3] = v.w;
    sq += v.x * v.x + v.y * v.y + v.z * v.z + v.w * v.w;
  }
#pragma unroll
  for (int off = 32; off >= 1; off >>= 1) sq += __shfl_down(sq, off);
  __shared__ float wsum[4];
  __shared__ float scale_s;
  int lane = tid & 63, wv = tid >> 6;
  if (lane == 0) wsum[wv] = sq;
  __syncthreads();
  if (tid == 0) {
    float t = wsum[0] + wsum[1] + wsum[2] + wsum[3];
    scale_s = rsqrtf(t / (float)DIM + 1e-5f);
  }
  __syncthreads();
  float scale = scale_s;
#pragma unroll
  for (int c = 0; c < 4; c++) {
    int off = (tid + c * 256) * 4;
    float4 wv4 = *(const float4*)&w[off];
    ushort4v ov;
    ov.x = f2bf(vals[c * 4 + 0] * scale * wv4.x);
    ov.y = f2bf(vals[c * 4 + 1] * scale * wv4.y);
    ov.z = f2bf(vals[c * 4 + 2] * scale * wv4.z);
    ov.w = f2bf(vals[c * 4 + 3] * scale * wv4.w);
    *(ushort4v*)&xn2[base + off] = ov;
  }
}

// ---------------- Flash attention (causal, GQA 4:1) ----------------
__global__ __launch_bounds__(256) void attn_kernel(const ushort* __restrict__ q,
                                                   const ushort* __restrict__ k,
                                                   const ushort* __restrict__ vt,
                                                   ushort* __restrict__ o) {
  int qb = blockIdx.x, h = blockIdx.y, kvh = h >> 2;
  int tid = threadIdx.x, lane = tid & 63, wave = tid >> 6;
  __shared__ ushort Ks[64][136];
  __shared__ ushort Vs[128][72];
  __shared__ ushort Ps[4][16][72];

  bf16x8 qf[4];
  int qrow = qb * 64 + wave * 16 + (lane & 15);
#pragma unroll
  for (int kk = 0; kk < 4; kk++)
    qf[kk] = *(const bf16x8*)&q[(size_t)qrow * DIM + h * HD + kk * 32 + (lane >> 4) * 8];

  f32x4 oacc[8] = {};
  float mrow[4], lrow[4];
  int qr[4];
#pragma unroll
  for (int j = 0; j < 4; j++) {
    mrow[j] = -INFINITY; lrow[j] = 0.f;
    qr[j] = qb * 64 + wave * 16 + (lane >> 4) * 4 + j;
  }

  for (int kt = 0; kt <= qb; kt++) {
    int key0 = kt * 64;
#pragma unroll
    for (int c = 0; c < 4; c++) {
      int e = tid * 32 + c * 8;
      int r = e >> 7, cc = e & 127;
      *(bf16x8*)&Ks[r][cc] =
          *(const bf16x8*)&k[(size_t)(key0 + r) * (NKVH * HD) + kvh * HD + cc];
      int r2 = e >> 6, cc2 = e & 63;
      *(bf16x8*)&Vs[r2][cc2] =
          *(const bf16x8*)&vt[(size_t)(kvh * HD + r2) * SEQ + key0 + cc2];
    }
    __syncthreads();

    f32x4 sf[4] = {};
#pragma unroll
    for (int fn = 0; fn < 4; fn++)
#pragma unroll
      for (int kk = 0; kk < 4; kk++) {
        bf16x8 kf = *(const bf16x8*)&Ks[fn * 16 + (lane & 15)][kk * 32 + (lane >> 4) * 8];
        sf[fn] = __builtin_amdgcn_mfma_f32_16x16x32_bf16(qf[kk], kf, sf[fn], 0, 0, 0);
      }

#pragma unroll
    for (int fn = 0; fn < 4; fn++) {
      int key = key0 + fn * 16 + (lane & 15);
#pragma unroll
      for (int j = 0; j < 4; j++)
        if (key > qr[j]) sf[fn][j] = -INFINITY;
    }

#pragma unroll
    for (int j = 0; j < 4; j++) {
      float mx = fmaxf(fmaxf(sf[0][j], sf[1][j]), fmaxf(sf[2][j], sf[3][j]));
#pragma unroll
      for (int off = 1; off < 16; off <<= 1) mx = fmaxf(mx, __shfl_xor(mx, off));
      float mnew = fmaxf(mrow[j], mx);
      float sc = __expf(mrow[j] - mnew);
      mrow[j] = mnew;
      float rs = 0.f;
#pragma unroll
      for (int fn = 0; fn < 4; fn++) {
        float p = __expf(sf[fn][j] - mnew);
        sf[fn][j] = p;
        rs += p;
      }
#pragma unroll
      for (int off = 1; off < 16; off <<= 1) rs += __shfl_xor(rs, off);
      lrow[j] = lrow[j] * sc + rs;
#pragma unroll
      for (int f2 = 0; f2 < 8; f2++) oacc[f2][j] *= sc;
    }

#pragma unroll
    for (int fn = 0; fn < 4; fn++)
#pragma unroll
      for (int j = 0; j < 4; j++)
        Ps[wave][(lane >> 4) * 4 + j][fn * 16 + (lane & 15)] = f2bf(sf[fn][j]);

#pragma unroll
    for (int kk = 0; kk < 2; kk++) {
      bf16x8 pf = *(const bf16x8*)&Ps[wave][lane & 15][kk * 32 + (lane >> 4) * 8];
#pragma unroll
      for (int f2 = 0; f2 < 8; f2++) {
        bf16x8 vf = *(const bf16x8*)&Vs[f2 * 16 + (lane & 15)][kk * 32 + (lane >> 4) * 8];
        oacc[f2] = __builtin_amdgcn_mfma_f32_16x16x32_bf16(pf, vf, oacc[f2], 0, 0, 0);
      }
    }
    __syncthreads();
  }

#pragma unroll
  for (int j = 0; j < 4; j++) {
    float inv = 1.f / lrow[j];
#pragma unroll
    for (int f2 = 0; f2 < 8; f2++)
      o[(size_t)qr[j] * DIM + h * HD + f2 * 16 + (lane & 15)] = f2bf(oacc[f2][j] * inv);
  }
}

extern "C" void kernel_launch(void* const* d_in, const int* in_sizes, int n_in,
                              void* d_out, int out_size, void* d_ws, size_t ws_size,
                              hipStream_t stream) {
  const float* x    = (const float*)d_in[0];
  const float* w1   = (const float*)d_in[1];
  const float* w2   = (const float*)d_in[2];
  const float* cosT = (const float*)d_in[3];
  const float* sinT = (const float*)d_in[4];
  const float* wq = (const float*)d_in[6];
  const float* la_q = (const float*)d_in[7];
  const float* lb_q = (const float*)d_in[8];
  const float* wk = (const float*)d_in[9];
  const float* la_k = (const float*)d_in[10];
  const float* lb_k = (const float*)d_in[11];
  const float* wv = (const float*)d_in[12];
  const float* la_v = (const float*)d_in[13];
  const float* lb_v = (const float*)d_in[14];
  const float* wo = (const float*)d_in[15];
  const float* la_o = (const float*)d_in[16];
  const float* lb_o = (const float*)d_in[17];
  const float* wg = (const float*)d_in[18];
  const float* la_g = (const float*)d_in[19];
  const float* lb_g = (const float*)d_in[20];
  const float* wu = (const float*)d_in[21];
  const float* la_u = (const float*)d_in[22];
  const float* lb_u = (const float*)d_in[23];
  const float* wd = (const float*)d_in[24];
  const float* la_d = (const float*)d_in[25];
  const float* lb_d = (const float*)d_in[26];
  float* out = (float*)d_out;

  char* ws = (char*)d_ws;
  ushort* xn1 = (ushort*)ws;  ws += (size_t)SEQ * DIM * 2;
  ushort* qb  = (ushort*)ws;  ws += (size_t)SEQ * DIM * 2;
  ushort* kb  = (ushort*)ws;  ws += (size_t)SEQ * NKVH * HD * 2;
  ushort* vtb = (ushort*)ws;  ws += (size_t)SEQ * NKVH * HD * 2;
  ushort* ob  = (ushort*)ws;  ws += (size_t)SEQ * DIM * 2;
  float*  xmed= (float*)ws;   ws += (size_t)SEQ * DIM * 4;
  ushort* xn2 = (ushort*)ws;  ws += (size_t)SEQ * DIM * 2;
  ushort* gate= (ushort*)ws;  ws += (size_t)SEQ * FF * 2;
  ushort* up  = (ushort*)ws;  ws += (size_t)SEQ * FF * 2;   // unused (kept for layout)
  ushort* hb  = (ushort*)ws;  ws += (size_t)SEQ * FF * 2;
  ushort* t_q = (ushort*)ws; ws += SEQ * LR * 2;
  ushort* t_k = (ushort*)ws; ws += SEQ * LR * 2;
  ushort* t_v = (ushort*)ws; ws += SEQ * LR * 2;
  ushort* t_o = (ushort*)ws; ws += SEQ * LR * 2;
  ushort* t_g = (ushort*)ws; ws += SEQ * LR * 2;
  ushort* t_u = (ushort*)ws; ws += SEQ * LR * 2;
  ushort* t_d = (ushort*)ws; ws += SEQ * LR * 2;
  (void)up;

  float* pbuf1 = (float*)gate;  // QKV / wo partials: gate..hb dead then
  float* pbuf2 = (float*)xn2;   // wd partials: xn2+gate+up dead then

  size_t snd = (size_t)SEQ * DIM;

  // 1) norm + fused lora-A (q,k,v share xn1)
  rmsnorm_kernel<<<SEQ, 256, 0, stream>>>(x, w1, xn1);
  lora_a_kernel<3><<<SEQ, 256, 0, stream>>>(xn1, la_q, la_k, la_v, t_q, t_k, t_v, DIM);

  // 2) fused QKV GEMM (split-K2, fused dequant) -> reduce + fused RoPE + V-transpose
  gemm256_kernel<3><<<dim3((DIM + 2048) / 256, SEQ / 256, 2), 512, 0, stream>>>(
      xn1, wq, wk, wv, lb_q, lb_k, lb_v, t_q, t_k, t_v, nullptr, DIM, DIM + 1024,
      pbuf1, SEQ, DIM + 2048, DIM, 32);
  reduce2_qkv_rope<<<SEQ * 896 / 256, 256, 0, stream>>>(pbuf1, cosT, sinT, qb, kb, vtb);

  // 3) attention
  attn_kernel<<<dim3(SEQ / 64, NH), 256, 0, stream>>>(qb, kb, vtb, ob);

  // 4) WO (split-K4, fused dequant) + residual + fused RMSNorm -> xmed, xn2
  lora_a_kernel<1><<<SEQ, 256, 0, stream>>>(ob, la_o, la_o, la_o, t_o, t_o, t_o, DIM);
  gemm256_kernel<3><<<dim3(DIM / 256, SEQ / 256, 4), 512, 0, stream>>>(
      ob, wo, wo, wo, lb_o, lb_o, lb_o, t_o, t_o, t_o, nullptr, DIM, DIM,
      pbuf1, SEQ, DIM, DIM, 16);
  reduce4_res_rms<<<SEQ, 256, 0, stream>>>(pbuf1, x, w2, xmed, xn2, snd);

  // 5) FFN (g,u share xn2); silu fused into wu epilogue
  lora_a_kernel<2><<<SEQ, 256, 0, stream>>>(xn2, la_g, la_u, la_u, t_g, t_u, t_u, DIM);
  gemm256_kernel<0><<<dim3(FF / 256, SEQ / 256, 1), 512, 0, stream>>>(
      xn2, wg, wg, wg, lb_g, lb_g, lb_g, t_g, t_g, t_g, nullptr, FF, FF,
      gate, SEQ, FF, DIM, DIM / 64);
  gemm256_kernel<4><<<dim3(FF / 256, SEQ / 256, 1), 512, 0, stream>>>(
      xn2, wu, wu, wu, lb_u, lb_u, lb_u, t_u, t_u, t_u, gate, FF, FF,
      hb, SEQ, FF, DIM, DIM / 64);
  lora_a_kernel<1><<<SEQ, 256, 0, stream>>>(hb, la_d, la_d, la_d, t_d, t_d, t_d, FF);
  gemm256_kernel<3><<<dim3(DIM / 256, SEQ / 256, 4), 512, 0, stream>>>(
      hb, wd, wd, wd, lb_d, lb_d, lb_d, t_d, t_d, t_d, nullptr, DIM, DIM,
      pbuf2, SEQ, DIM, FF, FF / 4 / 64);
  reduce4_res_kernel<<<snd / 1024, 256, 0, stream>>>(pbuf2, xmed, out, snd);
}

// Round 13
// 872.713 us; speedup vs baseline: 1.6581x; 1.0454x over previous
//
#include <hip/hip_runtime.h>
#include <hip/hip_bf16.h>
#include <math.h>

#define SEQ 1024
#define DIM 4096
#define NH 32
#define HD 128
#define NKVH 8
#define FF 14336
#define LR 16

typedef __attribute__((ext_vector_type(8))) short bf16x8;
typedef __attribute__((ext_vector_type(4))) float f32x4;
typedef __attribute__((ext_vector_type(4))) ushort ushort4v;
typedef __attribute__((ext_vector_type(4))) unsigned int u32x4;

__device__ __forceinline__ ushort f2bf(float f) {
  union { float f; unsigned u; } v; v.f = f;
  unsigned r = (v.u + 0x7FFFu + ((v.u >> 16) & 1u)) >> 16;
  return (ushort)r;
}
__device__ __forceinline__ float bf2f(ushort h) {
  union { unsigned u; float f; } v; v.u = ((unsigned)h) << 16;
  return v.f;
}
__device__ __forceinline__ unsigned cvtpk(float a, float b) {
  unsigned r;
  asm("v_cvt_pk_bf16_f32 %0, %1, %2" : "=v"(r) : "v"(a), "v"(b));
  return r;
}

__device__ __forceinline__ void gload_lds16(const void* g, void* l) {
  __builtin_amdgcn_global_load_lds(
      (const __attribute__((address_space(1))) void*)g,
      (__attribute__((address_space(3))) void*)l, 16, 0, 0);
}

// ---------------- RMSNorm: f32 in -> bf16 out ----------------
__global__ __launch_bounds__(256) void rmsnorm_kernel(const float* __restrict__ x,
                                                      const float* __restrict__ w,
                                                      ushort* __restrict__ out) {
  int row = blockIdx.x;
  int tid = threadIdx.x;
  const float* xr = x + (size_t)row * DIM;
  float vals[16];
  float s = 0.f;
#pragma unroll
  for (int c = 0; c < 4; c++) {
    float4 v = *(const float4*)&xr[(tid + c * 256) * 4];
    vals[c * 4 + 0] = v.x; vals[c * 4 + 1] = v.y;
    vals[c * 4 + 2] = v.z; vals[c * 4 + 3] = v.w;
    s += v.x * v.x + v.y * v.y + v.z * v.z + v.w * v.w;
  }
#pragma unroll
  for (int off = 32; off >= 1; off >>= 1) s += __shfl_down(s, off);
  __shared__ float wsum[4];
  __shared__ float scale_s;
  int lane = tid & 63, wv = tid >> 6;
  if (lane == 0) wsum[wv] = s;
  __syncthreads();
  if (tid == 0) {
    float t = wsum[0] + wsum[1] + wsum[2] + wsum[3];
    scale_s = rsqrtf(t / (float)DIM + 1e-5f);
  }
  __syncthreads();
  float scale = scale_s;
  ushort* orow = out + (size_t)row * DIM;
#pragma unroll
  for (int c = 0; c < 4; c++) {
    int base = (tid + c * 256) * 4;
    float4 wv4 = *(const float4*)&w[base];
    ushort4v ov;
    ov.x = f2bf(vals[c * 4 + 0] * scale * wv4.x);
    ov.y = f2bf(vals[c * 4 + 1] * scale * wv4.y);
    ov.z = f2bf(vals[c * 4 + 2] * scale * wv4.z);
    ov.w = f2bf(vals[c * 4 + 3] * scale * wv4.w);
    *(ushort4v*)&orow[base] = ov;
  }
}

// ---------------- LoRA A: t_l[m][16] = A[m] @ la_l, one row per block ----------------
template <int NL>
__global__ __launch_bounds__(256) void lora_a_kernel(
    const ushort* __restrict__ A,
    const float* __restrict__ la0, const float* __restrict__ la1,
    const float* __restrict__ la2,
    ushort* __restrict__ t0, ushort* __restrict__ t1, ushort* __restrict__ t2,
    int K) {
  int m = blockIdx.x, i = threadIdx.x;
  float acc[NL][16];
#pragma unroll
  for (int l = 0; l < NL; l++)
#pragma unroll
    for (int n = 0; n < 16; n++) acc[l][n] = 0.f;

  const ushort* Arow = A + (size_t)m * K;
  int nc = K >> 8;
  for (int c = 0; c < nc; c++) {
    int k = c * 256 + i;
    float a = bf2f(Arow[k]);
#pragma unroll
    for (int l = 0; l < NL; l++) {
      const float* lap = (l == 0 ? la0 : (l == 1 ? la1 : la2)) + (size_t)k * 16;
#pragma unroll
      for (int q = 0; q < 4; q++) {
        float4 lv = *(const float4*)&lap[q * 4];
        acc[l][q * 4 + 0] += a * lv.x;
        acc[l][q * 4 + 1] += a * lv.y;
        acc[l][q * 4 + 2] += a * lv.z;
        acc[l][q * 4 + 3] += a * lv.w;
      }
    }
  }

  __shared__ float red[256][17];
  __shared__ float red2[16][17];
#pragma unroll
  for (int l = 0; l < NL; l++) {
    __syncthreads();
#pragma unroll
    for (int n = 0; n < 16; n++) red[i][n] = acc[l][n];
    __syncthreads();
    {
      int g = i >> 4, n = i & 15;
      float s = 0.f;
#pragma unroll
      for (int j = 0; j < 16; j++) s += red[g * 16 + j][n];
      red2[g][n] = s;
    }
    __syncthreads();
    if (i < 16) {
      float s2 = 0.f;
#pragma unroll
      for (int g2 = 0; g2 < 16; g2++) s2 += red2[g2][i];
      ushort* tp = (l == 0 ? t0 : (l == 1 ? t1 : t2));
      tp[(size_t)m * LR + i] = f2bf(s2);
    }
  }
}

// ================= 256x256 GEMM, 8 waves, 8-phase schedule, FUSED f32->bf16 dequant =================
// Panel-sharer co-location (bx outer decode); dequant via v_cvt_pk_bf16_f32.
// WM 0: bf16 [M][N]; WM 3: f32 partial [z][M][N]; WM 4: bf16 silu(gate)*v
template <int WM>
__global__ __launch_bounds__(512) void gemm256_kernel(
    const ushort* __restrict__ A,
    const float* __restrict__ W0, const float* __restrict__ W1, const float* __restrict__ W2,
    const float* __restrict__ lb0, const float* __restrict__ lb1, const float* __restrict__ lb2,
    const ushort* __restrict__ t0, const ushort* __restrict__ t1, const ushort* __restrict__ t2,
    const ushort* __restrict__ gatep,
    int c1, int c2, void* __restrict__ outp, int M, int N, int K, int nkp) {
  __shared__ __align__(16) ushort As[2][256 * 64];
  __shared__ __align__(16) ushort Bs[2][256 * 64];
  int tid = threadIdx.x;
  int lane = tid & 63, wave = tid >> 6;
  int wm = wave >> 2, wn = wave & 3;

  // ---- T1 XCD swizzle + panel-sharer-adjacent decode ----
  int gx = gridDim.x, gy = gridDim.y, gz = gridDim.z;
  int flat = blockIdx.x + gx * (blockIdx.y + gy * blockIdx.z);
  int nwg = gx * gy * gz;
  int q = nwg >> 3, r = nwg & 7;
  int xcd = flat & 7;
  int wgid = (xcd < r ? xcd * (q + 1) : r * (q + 1) + (xcd - r) * q) + (flat >> 3);
  int sh = gy * gz;
  int bx = wgid / sh;
  int rem = wgid - bx * sh;
  int z = rem / gy;
  int by = rem - z * gy;

  int n0 = bx * 256, m0 = by * 256;
  int k0 = z * nkp;

  // segment select (weight + lora)
  const float* Wp; const float* lbp; const ushort* tp; int nseg, wseg;
  if (n0 < c1)      { Wp = W0; lbp = lb0; tp = t0; nseg = n0;      wseg = c1; }
  else if (n0 < c2) { Wp = W1; lbp = lb1; tp = t1; nseg = n0 - c1; wseg = c2 - c1; }
  else              { Wp = W2; lbp = lb2; tp = t2; nseg = n0 - c2; wseg = N - c2; }

  // A staging
  int srow = tid >> 3;
  int sswz = ((tid & 7) ^ (srow & 7)) * 8;
  const ushort* Ab = A + (size_t)(m0 + srow) * K + sswz;
  // B reg-staging source (linear; swizzle at ds_write)
  const float* Wbase = Wp + (size_t)(nseg + srow) * K + (tid & 7) * 8;

  f32x4 acc[8][4] = {};
  float4 breg[8];

#define SHALF(kt, b, h)                                                       \
  _Pragma("unroll") for (int i = 2 * (h); i < 2 * (h) + 2; i++) {             \
    gload_lds16(Ab + (size_t)(i * 64) * K + (size_t)(kt) * 64,                \
                &As[b][wave * 512 + i * 4096]);                               \
  }
#define BLOAD(kt, h)                                                          \
  {                                                                           \
    const float* gp = Wbase + (size_t)((h) * 128) * K + (size_t)(kt) * 64;    \
    breg[(h) * 4 + 0] = *(const float4*)gp;                                   \
    breg[(h) * 4 + 1] = *(const float4*)(gp + 4);                             \
    breg[(h) * 4 + 2] = *(const float4*)(gp + (size_t)64 * K);                \
    breg[(h) * 4 + 3] = *(const float4*)(gp + (size_t)64 * K + 4);            \
  }
#define WRITE_B(b)                                                            \
  _Pragma("unroll") for (int h = 0; h < 2; h++)                               \
  _Pragma("unroll") for (int j = 0; j < 2; j++) {                             \
    int rr = h * 128 + j * 64 + srow;                                         \
    float4 lo = breg[h * 4 + j * 2 + 0];                                      \
    float4 hi = breg[h * 4 + j * 2 + 1];                                      \
    u32x4 v;                                                                  \
    v.x = cvtpk(lo.x, lo.y); v.y = cvtpk(lo.z, lo.w);                         \
    v.z = cvtpk(hi.x, hi.y); v.w = cvtpk(hi.z, hi.w);                         \
    *(u32x4*)&Bs[b][rr * 64 + (((tid & 7) ^ (rr & 7))) * 8] = v;              \
  }
#define LDFRAG(buf, rr, ks) \
  (*(const bf16x8*)&(buf)[(rr) * 64 + (((ks) * 4 + (lane >> 4)) ^ ((rr) & 7)) * 8])

  // ---- prologue ----
  BLOAD(k0, 0); BLOAD(k0, 1);
  SHALF(k0, 0, 0); SHALF(k0, 0, 1);
  asm volatile("s_waitcnt vmcnt(4)" ::: "memory");
  WRITE_B(0);
  if (nkp > 1) { BLOAD(k0 + 1, 0); BLOAD(k0 + 1, 1); }
  if (nkp > 1) asm volatile("s_waitcnt vmcnt(8)" ::: "memory");
  else         asm volatile("s_waitcnt vmcnt(0)" ::: "memory");
  asm volatile("s_waitcnt lgkmcnt(0)" ::: "memory");
  __builtin_amdgcn_s_barrier();
  __builtin_amdgcn_sched_barrier(0);

  for (int tau = 0; tau < nkp; tau++) {
    int b = tau & 1;
    bool s1 = (tau + 1 < nkp), s2 = (tau + 2 < nkp);
    const ushort* as = As[b];
    const ushort* bs = Bs[b];
    bf16x8 bfr[4][2];
#pragma unroll
    for (int p = 0; p < 4; p++) {
      bf16x8 af[2][2];
#pragma unroll
      for (int qq = 0; qq < 2; qq++) {
        int ra = wm * 128 + (p * 2 + qq) * 16 + (lane & 15);
#pragma unroll
        for (int ks = 0; ks < 2; ks++) af[qq][ks] = LDFRAG(as, ra, ks);
      }
      if (p == 0) {
#pragma unroll
        for (int f = 0; f < 4; f++) {
          int rb = wn * 64 + f * 16 + (lane & 15);
#pragma unroll
          for (int ks = 0; ks < 2; ks++) bfr[f][ks] = LDFRAG(bs, rb, ks);
        }
      }
      if (p == 0 && s1) { SHALF(k0 + tau + 1, b ^ 1, 0); }
      if (p == 1 && s1) { SHALF(k0 + tau + 1, b ^ 1, 1); }
      if (p == 2 && s2) { BLOAD(k0 + tau + 2, 0); }
      if (p == 3 && s2) { BLOAD(k0 + tau + 2, 1); }
      __builtin_amdgcn_sched_barrier(0);
      __builtin_amdgcn_s_barrier();
      asm volatile("s_waitcnt lgkmcnt(0)" ::: "memory");
      __builtin_amdgcn_sched_barrier(0);
      __builtin_amdgcn_s_setprio(1);
#pragma unroll
      for (int qq = 0; qq < 2; qq++)
#pragma unroll
        for (int fn = 0; fn < 4; fn++)
#pragma unroll
          for (int ks = 0; ks < 2; ks++)
            acc[p * 2 + qq][fn] = __builtin_amdgcn_mfma_f32_16x16x32_bf16(
                af[qq][ks], bfr[fn][ks], acc[p * 2 + qq][fn], 0, 0, 0);
      __builtin_amdgcn_s_setprio(0);
      __builtin_amdgcn_sched_barrier(0);
      if (p == 1 && s1) {
        asm volatile("s_waitcnt vmcnt(4)" ::: "memory");
        WRITE_B(b ^ 1);
        __builtin_amdgcn_sched_barrier(0);
      }
      if (p == 3) {
        if (s2) asm volatile("s_waitcnt vmcnt(8)" ::: "memory");
        else    asm volatile("s_waitcnt vmcnt(0)" ::: "memory");
      }
      __builtin_amdgcn_s_barrier();
      __builtin_amdgcn_sched_barrier(0);
    }
  }
#undef SHALF
#undef BLOAD
#undef WRITE_B

  // ---- LoRA K-extension (split 0 only) ----
  if (z == 0) {
#pragma unroll
    for (int it = 0; it < 2; it++) {
      int task = tid + it * 512;
      int rr = task >> 2, ls = task & 3;
      int ph = ls ^ (rr & 7);
      bf16x8 avv = {};
      bf16x8 bvv = {};
      if (ls < 2) {
        avv = *(const bf16x8*)&tp[(size_t)(m0 + rr) * LR + ls * 8];
#pragma unroll
        for (int j = 0; j < 8; j++)
          bvv[j] = (short)f2bf(lbp[(size_t)(ls * 8 + j) * wseg + nseg + rr]);
      }
      *(bf16x8*)&As[0][rr * 64 + ph * 8] = avv;
      *(bf16x8*)&Bs[0][rr * 64 + ph * 8] = bvv;
    }
    __syncthreads();
    bf16x8 af[8], bfr[4];
#pragma unroll
    for (int f = 0; f < 8; f++) {
      int ra = wm * 128 + f * 16 + (lane & 15);
      af[f] = LDFRAG(As[0], ra, 0);
    }
#pragma unroll
    for (int f = 0; f < 4; f++) {
      int rb = wn * 64 + f * 16 + (lane & 15);
      bfr[f] = LDFRAG(Bs[0], rb, 0);
    }
#pragma unroll
    for (int fm = 0; fm < 8; fm++)
#pragma unroll
      for (int fn = 0; fn < 4; fn++)
        acc[fm][fn] = __builtin_amdgcn_mfma_f32_16x16x32_bf16(af[fm], bfr[fn], acc[fm][fn], 0, 0, 0);
  }
#undef LDFRAG

  // ---- write ----
#pragma unroll
  for (int fm = 0; fm < 8; fm++) {
#pragma unroll
    for (int j = 0; j < 4; j++) {
      int mg = m0 + wm * 128 + fm * 16 + (lane >> 4) * 4 + j;
#pragma unroll
      for (int fn = 0; fn < 4; fn++) {
        int ng = n0 + wn * 64 + fn * 16 + (lane & 15);
        float v = acc[fm][fn][j];
        if (WM == 0) {
          ((ushort*)outp)[(size_t)mg * N + ng] = f2bf(v);
        } else if (WM == 4) {
          float g = bf2f(gatep[(size_t)mg * N + ng]);
          float sv = g / (1.f + __expf(-g));
          ((ushort*)outp)[(size_t)mg * N + ng] = f2bf(sv * v);
        } else {
          ((float*)outp)[((size_t)z * M + mg) * (size_t)N + ng] = v;
        }
      }
    }
  }
}

// ---------------- QKV reduce + fused RoPE (q scaled) + V transpose ----------------
__global__ __launch_bounds__(256) void reduce2_qkv_rope(const float* __restrict__ p,
                                                        const float* __restrict__ ct,
                                                        const float* __restrict__ st,
                                                        ushort* __restrict__ qb,
                                                        ushort* __restrict__ kb,
                                                        ushort* __restrict__ vtb) {
  int gidx = blockIdx.x * 256 + threadIdx.x;
  int r = gidx / 896, j = gidx - r * 896;
  size_t row = (size_t)r * 6144;
  size_t sstride = (size_t)SEQ * 6144;
  if (j < 640) {
    bool isq = j < 512;
    int jj = isq ? j : j - 512;
    int h = jj >> 4, d0 = (jj & 15) * 4;
    size_t base = row + (isq ? 0 : DIM) + h * 128 + d0;
    float4 a1 = *(const float4*)&p[base];
    float4 b1 = *(const float4*)&p[base + sstride];
    float4 a2 = *(const float4*)&p[base + 64];
    float4 b2 = *(const float4*)&p[base + 64 + sstride];
    float4 x1, x2;
    x1.x = a1.x + b1.x; x1.y = a1.y + b1.y; x1.z = a1.z + b1.z; x1.w = a1.w + b1.w;
    x2.x = a2.x + b2.x; x2.y = a2.y + b2.y; x2.z = a2.z + b2.z; x2.w = a2.w + b2.w;
    float4 c = *(const float4*)&ct[r * HD + d0];
    float4 s = *(const float4*)&st[r * HD + d0];
    float sc = isq ? 0.08838834764831845f : 1.0f;
    ushort4v o1, o2;
    o1.x = f2bf((x1.x * c.x - x2.x * s.x) * sc);
    o1.y = f2bf((x1.y * c.y - x2.y * s.y) * sc);
    o1.z = f2bf((x1.z * c.z - x2.z * s.z) * sc);
    o1.w = f2bf((x1.w * c.w - x2.w * s.w) * sc);
    o2.x = f2bf((x2.x * c.x + x1.x * s.x) * sc);
    o2.y = f2bf((x2.y * c.y + x1.y * s.y) * sc);
    o2.z = f2bf((x2.z * c.z + x1.z * s.z) * sc);
    o2.w = f2bf((x2.w * c.w + x1.w * s.w) * sc);
    if (isq) {
      *(ushort4v*)&qb[(size_t)r * DIM + h * 128 + d0] = o1;
      *(ushort4v*)&qb[(size_t)r * DIM + h * 128 + d0 + 64] = o2;
    } else {
      *(ushort4v*)&kb[(size_t)r * 1024 + h * 128 + d0] = o1;
      *(ushort4v*)&kb[(size_t)r * 1024 + h * 128 + d0 + 64] = o2;
    }
  } else {
    int jj = j - 640;
    int c0 = jj * 4;
    size_t base = row + DIM + 1024 + c0;
    float4 a = *(const float4*)&p[base];
    float4 b = *(const float4*)&p[base + sstride];
    vtb[(size_t)(c0 + 0) * SEQ + r] = f2bf(a.x + b.x);
    vtb[(size_t)(c0 + 1) * SEQ + r] = f2bf(a.y + b.y);
    vtb[(size_t)(c0 + 2) * SEQ + r] = f2bf(a.z + b.z);
    vtb[(size_t)(c0 + 3) * SEQ + r] = f2bf(a.w + b.w);
  }
}

// ---------------- split-K reduce + residual -> f32 out ----------------
__global__ __launch_bounds__(256) void reduce4_res_kernel(const float* __restrict__ p,
                                                          const float* __restrict__ res,
                                                          float* __restrict__ out,
                                                          size_t sstride) {
  size_t i = ((size_t)blockIdx.x * 256 + threadIdx.x) * 4;
  float4 a = *(const float4*)&p[i];
  float4 b = *(const float4*)&p[i + sstride];
  float4 c = *(const float4*)&p[i + 2 * sstride];
  float4 d = *(const float4*)&p[i + 3 * sstride];
  float4 r = *(const float4*)&res[i];
  float4 o;
  o.x = a.x + b.x + c.x + d.x + r.x;
  o.y = a.y + b.y + c.y + d.y + r.y;
  o.z = a.z + b.z + c.z + d.z + r.z;
  o.w = a.w + b.w + c.w + d.w + r.w;
  *(float4*)&out[i] = o;
}

// ---------------- split-K reduce + residual + fused RMSNorm (one row/block) ----------------
__global__ __launch_bounds__(256) void reduce4_res_rms(const float* __restrict__ p,
                                                       const float* __restrict__ res,
                                                       const float* __restrict__ w,
                                                       float* __restrict__ xmed,
                                                       ushort* __restrict__ xn2,
                                                       size_t sstride) {
  int row = blockIdx.x, tid = threadIdx.x;
  size_t base = (size_t)row * DIM;
  float vals[16];
  float sq = 0.f;
#pragma unroll
  for (int c = 0; c < 4; c++) {
    size_t i = base + (tid + c * 256) * 4;
    float4 a = *(const float4*)&p[i];
    float4 b = *(const float4*)&p[i + sstride];
    float4 cc = *(const float4*)&p[i + 2 * sstride];
    float4 d = *(const float4*)&p[i + 3 * sstride];
    float4 r = *(const float4*)&res[i];
    float4 v;
    v.x = a.x + b.x + cc.x + d.x + r.x;
    v.y = a.y + b.y + cc.y + d.y + r.y;
    v.z = a.z + b.z + cc.z + d.z + r.z;
    v.w = a.w + b.w + cc.w + d.w + r.w;
    *(float4*)&xmed[i] = v;
    vals[c * 4 + 0] = v.x; vals[c * 4 + 1] = v.y;
    vals[c * 4 + 2] = v.z; vals[c * 4 + 3] = v.w;
    sq += v.x * v.x + v.y * v.y + v.z * v.z + v.w * v.w;
  }
#pragma unroll
  for (int off = 32; off >= 1; off >>= 1) sq += __shfl_down(sq, off);
  __shared__ float wsum[4];
  __shared__ float scale_s;
  int lane = tid & 63, wv = tid >> 6;
  if (lane == 0) wsum[wv] = sq;
  __syncthreads();
  if (tid == 0) {
    float t = wsum[0] + wsum[1] + wsum[2] + wsum[3];
    scale_s = rsqrtf(t / (float)DIM + 1e-5f);
  }
  __syncthreads();
  float scale = scale_s;
#pragma unroll
  for (int c = 0; c < 4; c++) {
    int off = (tid + c * 256) * 4;
    float4 wv4 = *(const float4*)&w[off];
    ushort4v ov;
    ov.x = f2bf(vals[c * 4 + 0] * scale * wv4.x);
    ov.y = f2bf(vals[c * 4 + 1] * scale * wv4.y);
    ov.z = f2bf(vals[c * 4 + 2] * scale * wv4.z);
    ov.w = f2bf(vals[c * 4 + 3] * scale * wv4.w);
    *(ushort4v*)&xn2[base + off] = ov;
  }
}

// ---------------- Flash attention (causal, GQA 4:1), kvh-XCD co-located ----------------
__global__ __launch_bounds__(256) void attn_kernel(const ushort* __restrict__ q,
                                                   const ushort* __restrict__ k,
                                                   const ushort* __restrict__ vt,
                                                   ushort* __restrict__ o) {
  // relabel so all 64 blocks sharing a kvh have flat % 8 == kvh -> same XCD L2
  int flat = blockIdx.x + 16 * blockIdx.y;  // 0..511
  int kvh = flat & 7;
  int idx = flat >> 3;
  int h = kvh * 4 + (idx & 3);
  int qb = idx >> 2;
  int tid = threadIdx.x, lane = tid & 63, wave = tid >> 6;
  __shared__ ushort Ks[64][136];
  __shared__ ushort Vs[128][72];
  __shared__ ushort Ps[4][16][72];

  bf16x8 qf[4];
  int qrow = qb * 64 + wave * 16 + (lane & 15);
#pragma unroll
  for (int kk = 0; kk < 4; kk++)
    qf[kk] = *(const bf16x8*)&q[(size_t)qrow * DIM + h * HD + kk * 32 + (lane >> 4) * 8];

  f32x4 oacc[8] = {};
  float mrow[4], lrow[4];
  int qr[4];
#pragma unroll
  for (int j = 0; j < 4; j++) {
    mrow[j] = -INFINITY; lrow[j] = 0.f;
    qr[j] = qb * 64 + wave * 16 + (lane >> 4) * 4 + j;
  }

  for (int kt = 0; kt <= qb; kt++) {
    int key0 = kt * 64;
#pragma unroll
    for (int c = 0; c < 4; c++) {
      int e = tid * 32 + c * 8;
      int r = e >> 7, cc = e & 127;
      *(bf16x8*)&Ks[r][cc] =
          *(const bf16x8*)&k[(size_t)(key0 + r) * (NKVH * HD) + kvh * HD + cc];
      int r2 = e >> 6, cc2 = e & 63;
      *(bf16x8*)&Vs[r2][cc2] =
          *(const bf16x8*)&vt[(size_t)(kvh * HD + r2) * SEQ + key0 + cc2];
    }
    __syncthreads();

    f32x4 sf[4] = {};
#pragma unroll
    for (int fn = 0; fn < 4; fn++)
#pragma unroll
      for (int kk = 0; kk < 4; kk++) {
        bf16x8 kf = *(const bf16x8*)&Ks[fn * 16 + (lane & 15)][kk * 32 + (lane >> 4) * 8];
        sf[fn] = __builtin_amdgcn_mfma_f32_16x16x32_bf16(qf[kk], kf, sf[fn], 0, 0, 0);
      }

#pragma unroll
    for (int fn = 0; fn < 4; fn++) {
      int key = key0 + fn * 16 + (lane & 15);
#pragma unroll
      for (int j = 0; j < 4; j++)
        if (key > qr[j]) sf[fn][j] = -INFINITY;
    }

#pragma unroll
    for (int j = 0; j < 4; j++) {
      float mx = fmaxf(fmaxf(sf[0][j], sf[1][j]), fmaxf(sf[2][j], sf[3][j]));
#pragma unroll
      for (int off = 1; off < 16; off <<= 1) mx = fmaxf(mx, __shfl_xor(mx, off));
      float mnew = fmaxf(mrow[j], mx);
      float sc = __expf(mrow[j] - mnew);
      mrow[j] = mnew;
      float rs = 0.f;
#pragma unroll
      for (int fn = 0; fn < 4; fn++) {
        float p = __expf(sf[fn][j] - mnew);
        sf[fn][j] = p;
        rs += p;
      }
#pragma unroll
      for (int off = 1; off < 16; off <<= 1) rs += __shfl_xor(rs, off);
      lrow[j] = lrow[j] * sc + rs;
#pragma unroll
      for (int f2 = 0; f2 < 8; f2++) oacc[f2][j] *= sc;
    }

#pragma unroll
    for (int fn = 0; fn < 4; fn++)
#pragma unroll
      for (int j = 0; j < 4; j++)
        Ps[wave][(lane >> 4) * 4 + j][fn * 16 + (lane & 15)] = f2bf(sf[fn][j]);

#pragma unroll
    for (int kk = 0; kk < 2; kk++) {
      bf16x8 pf = *(const bf16x8*)&Ps[wave][lane & 15][kk * 32 + (lane >> 4) * 8];
#pragma unroll
      for (int f2 = 0; f2 < 8; f2++) {
        bf16x8 vf = *(const bf16x8*)&Vs[f2 * 16 + (lane & 15)][kk * 32 + (lane >> 4) * 8];
        oacc[f2] = __builtin_amdgcn_mfma_f32_16x16x32_bf16(pf, vf, oacc[f2], 0, 0, 0);
      }
    }
    __syncthreads();
  }

#pragma unroll
  for (int j = 0; j < 4; j++) {
    float inv = 1.f / lrow[j];
#pragma unroll
    for (int f2 = 0; f2 < 8; f2++)
      o[(size_t)qr[j] * DIM + h * HD + f2 * 16 + (lane & 15)] = f2bf(oacc[f2][j] * inv);
  }
}

extern "C" void kernel_launch(void* const* d_in, const int* in_sizes, int n_in,
                              void* d_out, int out_size, void* d_ws, size_t ws_size,
                              hipStream_t stream) {
  const float* x    = (const float*)d_in[0];
  const float* w1   = (const float*)d_in[1];
  const float* w2   = (const float*)d_in[2];
  const float* cosT = (const float*)d_in[3];
  const float* sinT = (const float*)d_in[4];
  const float* wq = (const float*)d_in[6];
  const float* la_q = (const float*)d_in[7];
  const float* lb_q = (const float*)d_in[8];
  const float* wk = (const float*)d_in[9];
  const float* la_k = (const float*)d_in[10];
  const float* lb_k = (const float*)d_in[11];
  const float* wv = (const float*)d_in[12];
  const float* la_v = (const float*)d_in[13];
  const float* lb_v = (const float*)d_in[14];
  const float* wo = (const float*)d_in[15];
  const float* la_o = (const float*)d_in[16];
  const float* lb_o = (const float*)d_in[17];
  const float* wg = (const float*)d_in[18];
  const float* la_g = (const float*)d_in[19];
  const float* lb_g = (const float*)d_in[20];
  const float* wu = (const float*)d_in[21];
  const float* la_u = (const float*)d_in[22];
  const float* lb_u = (const float*)d_in[23];
  const float* wd = (const float*)d_in[24];
  const float* la_d = (const float*)d_in[25];
  const float* lb_d = (const float*)d_in[26];
  float* out = (float*)d_out;

  char* ws = (char*)d_ws;
  ushort* xn1 = (ushort*)ws;  ws += (size_t)SEQ * DIM * 2;
  ushort* qb  = (ushort*)ws;  ws += (size_t)SEQ * DIM * 2;
  ushort* kb  = (ushort*)ws;  ws += (size_t)SEQ * NKVH * HD * 2;
  ushort* vtb = (ushort*)ws;  ws += (size_t)SEQ * NKVH * HD * 2;
  ushort* ob  = (ushort*)ws;  ws += (size_t)SEQ * DIM * 2;
  float*  xmed= (float*)ws;   ws += (size_t)SEQ * DIM * 4;
  ushort* xn2 = (ushort*)ws;  ws += (size_t)SEQ * DIM * 2;
  ushort* gate= (ushort*)ws;  ws += (size_t)SEQ * FF * 2;
  ushort* up  = (ushort*)ws;  ws += (size_t)SEQ * FF * 2;   // unused (kept for layout)
  ushort* hb  = (ushort*)ws;  ws += (size_t)SEQ * FF * 2;
  ushort* t_q = (ushort*)ws; ws += SEQ * LR * 2;
  ushort* t_k = (ushort*)ws; ws += SEQ * LR * 2;
  ushort* t_v = (ushort*)ws; ws += SEQ * LR * 2;
  ushort* t_o = (ushort*)ws; ws += SEQ * LR * 2;
  ushort* t_g = (ushort*)ws; ws += SEQ * LR * 2;
  ushort* t_u = (ushort*)ws; ws += SEQ * LR * 2;
  ushort* t_d = (ushort*)ws; ws += SEQ * LR * 2;
  (void)up;

  float* pbuf1 = (float*)gate;  // QKV / wo partials: gate..hb dead then
  float* pbuf2 = (float*)xn2;   // wd partials: xn2+gate+up dead then

  size_t snd = (size_t)SEQ * DIM;

  // 1) norm + fused lora-A (q,k,v share xn1)
  rmsnorm_kernel<<<SEQ, 256, 0, stream>>>(x, w1, xn1);
  lora_a_kernel<3><<<SEQ, 256, 0, stream>>>(xn1, la_q, la_k, la_v, t_q, t_k, t_v, DIM);

  // 2) fused QKV GEMM (split-K2, fused dequant) -> reduce + fused RoPE + V-transpose
  gemm256_kernel<3><<<dim3((DIM + 2048) / 256, SEQ / 256, 2), 512, 0, stream>>>(
      xn1, wq, wk, wv, lb_q, lb_k, lb_v, t_q, t_k, t_v, nullptr, DIM, DIM + 1024,
      pbuf1, SEQ, DIM + 2048, DIM, 32);
  reduce2_qkv_rope<<<SEQ * 896 / 256, 256, 0, stream>>>(pbuf1, cosT, sinT, qb, kb, vtb);

  // 3) attention
  attn_kernel<<<dim3(SEQ / 64, NH), 256, 0, stream>>>(qb, kb, vtb, ob);

  // 4) WO (split-K4, fused dequant) + residual + fused RMSNorm -> xmed, xn2
  lora_a_kernel<1><<<SEQ, 256, 0, stream>>>(ob, la_o, la_o, la_o, t_o, t_o, t_o, DIM);
  gemm256_kernel<3><<<dim3(DIM / 256, SEQ / 256, 4), 512, 0, stream>>>(
      ob, wo, wo, wo, lb_o, lb_o, lb_o, t_o, t_o, t_o, nullptr, DIM, DIM,
      pbuf1, SEQ, DIM, DIM, 16);
  reduce4_res_rms<<<SEQ, 256, 0, stream>>>(pbuf1, x, w2, xmed, xn2, snd);

  // 5) FFN (g,u share xn2); silu fused into wu epilogue
  lora_a_kernel<2><<<SEQ, 256, 0, stream>>>(xn2, la_g, la_u, la_u, t_g, t_u, t_u, DIM);
  gemm256_kernel<0><<<dim3(FF / 256, SEQ / 256, 1), 512, 0, stream>>>(
      xn2, wg, wg, wg, lb_g, lb_g, lb_g, t_g, t_g, t_g, nullptr, FF, FF,
      gate, SEQ, FF, DIM, DIM / 64);
  gemm256_kernel<4><<<dim3(FF / 256, SEQ / 256, 1), 512, 0, stream>>>(
      xn2, wu, wu, wu, lb_u, lb_u, lb_u, t_u, t_u, t_u, gate, FF, FF,
      hb, SEQ, FF, DIM, DIM / 64);
  lora_a_kernel<1><<<SEQ, 256, 0, stream>>>(hb, la_d, la_d, la_d, t_d, t_d, t_d, FF);
  gemm256_kernel<3><<<dim3(DIM / 256, SEQ / 256, 4), 512, 0, stream>>>(
      hb, wd, wd, wd, lb_d, lb_d, lb_d, t_d, t_d, t_d, nullptr, DIM, DIM,
      pbuf2, SEQ, DIM, FF, FF / 4 / 64);
  reduce4_res_kernel<<<snd / 1024, 256, 0, stream>>>(pbuf2, xmed, out, snd);
}